// Round 8
// baseline (397.525 us; speedup 1.0000x reference)
//
#include <hip/hip_runtime.h>
#include <hip/hip_bf16.h>

#define DIN 49
#define HIN 32
#define WIN 64
#define CIN 32
#define DOUT 193
#define HOUT 256
#define WOUT 512
#define NPIX (HOUT * WOUT)      // 131072
#define NUPS (DOUT * NPIX)      // 25296896
#define NCONV (DIN * HIN * WIN) // 100352
#define DSPLIT 97
#define NZ 2 // 97 + 96 planes (z0: 0..96, z1: 97..192) — covers DOUT=193
#define CGRP 8 // conv channel groups (4 ci each)

// LGA LDS geometry: bf16-packed, d-contiguous per pixel.
// PIXW=6 words/pixel (10 planes in 5 words + 1 pad word; 24 B, 8B-aligned
// for b64 reads). Double-buffered: 2 x 3960 words = 31.7 KB — same LDS
// footprint as the old single fp32 buffer, but ONE barrier per chunk.
#define ROWSTRIDE 33
#define PIXW 6
#define BUFW (20 * ROWSTRIDE * PIXW) // 3960 words per buffer

typedef __attribute__((ext_vector_type(2))) float v2f;

// Packed fp32 FMA (VOP3P, 3-address, register-only).
__device__ __forceinline__ v2f pk_fma(v2f a, v2f b, v2f c) {
    v2f d;
    asm("v_pk_fma_f32 %0, %1, %2, %3" : "=v"(d) : "v"(a), "v"(b), "v"(c));
    return d;
}

// ---------------------------------------------------------------------------
// Kernel 1: 3x3x3 conv, 32 -> 1 ch, zero pad 1, split 8 ways over channels.
// ---------------------------------------------------------------------------
__global__ void conv3d_kernel(const float* __restrict__ x,
                              const float* __restrict__ w,
                              float* __restrict__ partial) {
    __shared__ float ws[4 * 27];
    const int grp = blockIdx.y;
    for (int t = threadIdx.x; t < 4 * 27; t += blockDim.x)
        ws[t] = w[grp * (4 * 27) + t];
    __syncthreads();

    int idx = blockIdx.x * blockDim.x + threadIdx.x; // NCONV = 392*256 exact
    int wq = idx % WIN;
    int t2 = idx / WIN;
    int hq = t2 % HIN;
    int dq = t2 / HIN;

    float acc = 0.f;
    const float* xg = x + (size_t)grp * 4 * NCONV;
#pragma unroll
    for (int cl = 0; cl < 4; ++cl) {
        const float* xb = xg + cl * NCONV;
        const float* wb = ws + cl * 27;
#pragma unroll
        for (int kd = 0; kd < 3; ++kd) {
            int zd = dq + kd - 1;
            if (zd < 0 || zd >= DIN) continue;
#pragma unroll
            for (int kh = 0; kh < 3; ++kh) {
                int zh = hq + kh - 1;
                if (zh < 0 || zh >= HIN) continue;
#pragma unroll
                for (int kw = 0; kw < 3; ++kw) {
                    int zw = wq + kw - 1;
                    if (zw < 0 || zw >= WIN) continue;
                    acc += xb[(zd * HIN + zh) * WIN + zw] *
                           wb[(kd * 3 + kh) * 3 + kw];
                }
            }
        }
    }
    partial[(size_t)grp * NCONV + idx] = acc;
}

// ---------------------------------------------------------------------------
// Kernel 1b: fold 8 conv partials -> c.
// ---------------------------------------------------------------------------
__global__ void convfold_kernel(const float* __restrict__ partial,
                                float* __restrict__ c) {
    int idx = blockIdx.x * blockDim.x + threadIdx.x;
    float s = 0.f;
#pragma unroll
    for (int g = 0; g < CGRP; ++g) s += partial[(size_t)g * NCONV + idx];
    c[idx] = s;
}

__device__ __forceinline__ unsigned short bf16bits(float f) {
    __hip_bfloat16 h = __float2bfloat16(f);
    unsigned short b;
    __builtin_memcpy(&b, &h, 2);
    return b;
}

// weight #idx (0..74), idx compile-time
#define GW(idx)                                                  \
    __uint_as_float(((idx) & 1) ? (gp[(idx) >> 1] & 0xFFFF0000u) \
                                : (gp[(idx) >> 1] << 16))

#define LOF(u) __uint_as_float((u) << 16)
#define HIF(u) __uint_as_float((u) & 0xFFFF0000u)

// Packed-pair tap body (R7, measured iso-time at lower VGPR): 8 pk_fma +
// 8 scalar fmaf for the shift-misaligned middle term.
#define TAP_PK(A0, A1, B0, B1, C0, g0, g1, g2)   \
    do {                                         \
        v2f g1b = {g1, g1};                      \
        v2f g2b = {g2, g2};                      \
        acc01 = pk_fma(g1b, A0, acc01);          \
        acc01 = pk_fma(g2b, A1, acc01);          \
        acc23 = pk_fma(g1b, A1, acc23);          \
        acc23 = pk_fma(g2b, B0, acc23);          \
        acc45 = pk_fma(g1b, B0, acc45);          \
        acc45 = pk_fma(g2b, B1, acc45);          \
        acc67 = pk_fma(g1b, B1, acc67);          \
        acc67 = pk_fma(g2b, C0, acc67);          \
        acc01.x = fmaf(g0, A0.y, acc01.x);       \
        acc01.y = fmaf(g0, A1.x, acc01.y);       \
        acc23.x = fmaf(g0, A1.y, acc23.x);       \
        acc23.y = fmaf(g0, B0.x, acc23.y);       \
        acc45.x = fmaf(g0, B0.y, acc45.x);       \
        acc45.y = fmaf(g0, B1.x, acc45.y);       \
        acc67.x = fmaf(g0, B1.y, acc67.x);       \
        acc67.y = fmaf(g0, C0.x, acc67.y);       \
    } while (0)

// bf16-packed tap: b64+b64+b32 LDS read (20 B vs 40 B fp32), unpack pairs
// in-register (VALU has measured slack — R7), then the pk core.
#define TAP_BF(sp, g0, g1, g2)                   \
    do {                                         \
        uint2 wa = *(const uint2*)(sp);          \
        uint2 wbq = *(const uint2*)((sp) + 2);   \
        unsigned wcq = (sp)[4];                  \
        v2f A0 = {LOF(wa.x), HIF(wa.x)};         \
        v2f A1 = {LOF(wa.y), HIF(wa.y)};         \
        v2f B0 = {LOF(wbq.x), HIF(wbq.x)};       \
        v2f B1 = {LOF(wbq.y), HIF(wbq.y)};       \
        v2f C0 = {LOF(wcq), HIF(wcq)};           \
        TAP_PK(A0, A1, B0, B1, C0, g0, g1, g2);  \
    } while (0)

// ---------------------------------------------------------------------------
// lga1 staging: trilinear upsample from c (L2-hot) computed straight into
// the bf16 LDS buffer. OOB jobs write zeros (halo planes must be zero).
// ---------------------------------------------------------------------------
__device__ __forceinline__ void stage1(const float* __restrict__ cvol,
                                       __hip_bfloat16* __restrict__ sh,
                                       int tid, int h0p, int w0p, int dstart) {
#pragma unroll
    for (int k = 0; k < 4; ++k) {
        if (k < 3 || tid < 32) { // NJOBS = 800
            int jj = tid + k * 256;
            int seg = jj & 3;
            int rowjob = jj >> 2;
            int dl = rowjob / 20;
            int r = rowjob - dl * 20;
            int gh = h0p - 2 + r;
            int gwb = w0p - 8 + seg * 8;
            int gd = dstart - 1 + dl;
            float a0 = 0.f, a1 = 0.f, a2 = 0.f;
            if (gd >= 0 && gd < DOUT && gh >= 0 && gh < HOUT && gwb >= 0 &&
                (gwb + 8) <= WOUT) {
                float fd = (gd + 0.5f) * (49.0f / 193.0f) - 0.5f;
                fd = fminf(fmaxf(fd, 0.f), (float)(DIN - 1));
                int d0c = min((int)fd, DIN - 2);
                float ad = fd - (float)d0c;
                float fh = (gh + 0.5f) * 0.125f - 0.5f;
                fh = fminf(fmaxf(fh, 0.f), (float)(HIN - 1));
                int h0c = min((int)fh, HIN - 2);
                float ah = fh - (float)h0c;
                int g = gwb >> 3;
                int cm1 = max(g - 1, 0);
                int cp1 = min(g + 1, WIN - 1);
                const float* p00 = cvol + (d0c * HIN + h0c) * WIN;
                const float* p01 = p00 + WIN;
                const float* p10 = p00 + HIN * WIN;
                const float* p11 = p10 + WIN;
                float q00, q01, q10, q11;
                q00 = p00[cm1]; q01 = p01[cm1];
                q10 = p10[cm1]; q11 = p11[cm1];
                a0 = (q00 + ah * (q01 - q00)) * (1.f - ad) +
                     (q10 + ah * (q11 - q10)) * ad;
                q00 = p00[g]; q01 = p01[g];
                q10 = p10[g]; q11 = p11[g];
                a1 = (q00 + ah * (q01 - q00)) * (1.f - ad) +
                     (q10 + ah * (q11 - q10)) * ad;
                q00 = p00[cp1]; q01 = p01[cp1];
                q10 = p10[cp1]; q11 = p11[cp1];
                a2 = (q00 + ah * (q01 - q00)) * (1.f - ad) +
                     (q10 + ah * (q11 - q10)) * ad;
            }
            float d01 = a1 - a0, d12 = a2 - a1;
            int hb = (r * ROWSTRIDE + seg * 8) * (2 * PIXW) + dl;
            sh[hb + 0 * 2 * PIXW] = __float2bfloat16(a0 + 0.5625f * d01);
            sh[hb + 1 * 2 * PIXW] = __float2bfloat16(a0 + 0.6875f * d01);
            sh[hb + 2 * 2 * PIXW] = __float2bfloat16(a0 + 0.8125f * d01);
            sh[hb + 3 * 2 * PIXW] = __float2bfloat16(a0 + 0.9375f * d01);
            sh[hb + 4 * 2 * PIXW] = __float2bfloat16(a1 + 0.0625f * d12);
            sh[hb + 5 * 2 * PIXW] = __float2bfloat16(a1 + 0.1875f * d12);
            sh[hb + 6 * 2 * PIXW] = __float2bfloat16(a1 + 0.3125f * d12);
            sh[hb + 7 * 2 * PIXW] = __float2bfloat16(a1 + 0.4375f * d12);
        }
    }
}

// ---------------------------------------------------------------------------
// lga2 staging: bf16 y1 rows from HBM straight into the bf16 LDS buffer
// (no conversion — pure 16-bit scatter). OOB jobs write zeros.
// ---------------------------------------------------------------------------
__device__ __forceinline__ void stage2(const unsigned short* __restrict__ xus,
                                       unsigned short* __restrict__ sh,
                                       int tid, int h0p, int w0p, int dstart) {
#pragma unroll
    for (int k = 0; k < 4; ++k) {
        if (k < 3 || tid < 32) { // NJOBS = 800
            int jj = tid + k * 256;
            int seg = jj & 3;
            int rowjob = jj >> 2;
            int dl = rowjob / 20;
            int r = rowjob - dl * 20;
            int gh = h0p - 2 + r;
            int gwb = w0p - 8 + seg * 8;
            int gd = dstart - 1 + dl;
            uint4 v = make_uint4(0u, 0u, 0u, 0u);
            if (gd >= 0 && gd < DOUT && gh >= 0 && gh < HOUT && gwb >= 0 &&
                (gwb + 8) <= WOUT)
                v = *(const uint4*)(xus + (size_t)gd * NPIX + gh * WOUT + gwb);
            int hb = (r * ROWSTRIDE + seg * 8) * (2 * PIXW) + dl;
            sh[hb + 0 * 2 * PIXW] = (unsigned short)(v.x);
            sh[hb + 1 * 2 * PIXW] = (unsigned short)(v.x >> 16);
            sh[hb + 2 * 2 * PIXW] = (unsigned short)(v.y);
            sh[hb + 3 * 2 * PIXW] = (unsigned short)(v.y >> 16);
            sh[hb + 4 * 2 * PIXW] = (unsigned short)(v.z);
            sh[hb + 5 * 2 * PIXW] = (unsigned short)(v.z >> 16);
            sh[hb + 6 * 2 * PIXW] = (unsigned short)(v.w);
            sh[hb + 7 * 2 * PIXW] = (unsigned short)(v.w >> 16);
        }
    }
}

// ---------------------------------------------------------------------------
// LGA pass 1. Double-buffered bf16 su, ONE barrier per chunk; staging of
// chunk k+1 shares the barrier-free region with compute of chunk k so the
// global-load latency and lerp VALU hide under the FMA stream (T14).
// amdgpu_num_vgpr(128) pin (R6-proven).
// ---------------------------------------------------------------------------
__global__ __launch_bounds__(256)
__attribute__((amdgpu_num_vgpr(128))) void lga1_kernel(
    const float* __restrict__ cvol,
    const float* __restrict__ lg1,
    __hip_bfloat16* __restrict__ yout) {
    const int tid = threadIdx.x;
    const int tx = tid & 15;
    const int ty = tid >> 4;
    const int w0p = blockIdx.x * 16;
    const int h0p = blockIdx.y * 16;
    const int zb = blockIdx.z * DSPLIT;
    const int dend = min(zb + DSPLIT, DOUT);
    const int pix = (h0p + ty) * WOUT + (w0p + tx);

    __shared__ __align__(16) unsigned su[2 * BUFW];

    // prologue stage (chunk 0) issues first; guidance preamble overlaps it
    stage1(cvol, (__hip_bfloat16*)su, tid, h0p, w0p, zb);

    // ---- guidance: single pass, un-normalized, bf16 pairs (38 regs) ----
    float asum = 0.f;
    unsigned gp[38];
#pragma unroll
    for (int p = 0; p < 38; ++p) {
        int c0 = 2 * p, c1 = 2 * p + 1;
        float w0 = lg1[c0 * NPIX + pix];
        float w1 = (c1 < 75) ? lg1[c1 * NPIX + pix] : 0.f;
        unsigned b0 = bf16bits(w0), b1 = bf16bits(w1);
        asum += fabsf(__uint_as_float(b0 << 16)) +
                fabsf(__uint_as_float(b1 << 16));
        gp[p] = b0 | (b1 << 16);
    }
    const float inv = 1.f / fmaxf(asum, 1e-12f);

    const int pbase = (ty * ROWSTRIDE + tx + 6) * PIXW;
    __hip_bfloat16* ybase = yout + pix;

    __syncthreads();
    int pb = 0;
    for (int d0 = zb; d0 < dend; d0 += 8) {
        if (d0 + 8 < dend)
            stage1(cvol, (__hip_bfloat16*)(su + (pb ^ 1) * BUFW), tid, h0p,
                   w0p, d0 + 8);

        const unsigned* sw = su + pb * BUFW + pbase;
        v2f acc01 = {0.f, 0.f}, acc23 = {0.f, 0.f};
        v2f acc45 = {0.f, 0.f}, acc67 = {0.f, 0.f};
#pragma unroll
        for (int i = 0; i < 5; ++i) {
#pragma unroll
            for (int j = 0; j < 5; ++j) {
                const int t = i * 5 + j;
                const float g0 = GW(t);
                const float g1 = GW(25 + t);
                const float g2 = GW(50 + t);
                TAP_BF(sw + (i * ROWSTRIDE + j) * PIXW, g0, g1, g2);
            }
        }

        float acc[8] = {acc01.x, acc01.y, acc23.x, acc23.y,
                        acc45.x, acc45.y, acc67.x, acc67.y};
        if (d0 + 8 <= dend) {
#pragma unroll
            for (int dd = 0; dd < 8; ++dd)
                ybase[(size_t)(d0 + dd) * NPIX] =
                    __float2bfloat16(acc[dd] * inv);
        } else {
#pragma unroll
            for (int dd = 0; dd < 8; ++dd)
                if (d0 + dd < dend)
                    ybase[(size_t)(d0 + dd) * NPIX] =
                        __float2bfloat16(acc[dd] * inv);
        }
        __syncthreads();
        pb ^= 1;
    }
}

// ---------------------------------------------------------------------------
// LGA pass 2: same double-buffered one-barrier structure; staging is a pure
// bf16 scatter from HBM (latency hides under compute); fused online softmin.
// ---------------------------------------------------------------------------
__global__ __launch_bounds__(256)
__attribute__((amdgpu_num_vgpr(128))) void lga2_kernel(
    const __hip_bfloat16* __restrict__ xin,
    const float* __restrict__ lg1,
    float* __restrict__ part) {
    const int tid = threadIdx.x;
    const int tx = tid & 15;
    const int ty = tid >> 4;
    const int w0p = blockIdx.x * 16;
    const int h0p = blockIdx.y * 16;
    const int zb = blockIdx.z * DSPLIT;
    const int dend = min(zb + DSPLIT, DOUT);
    const int pix = (h0p + ty) * WOUT + (w0p + tx);
    const unsigned short* xus = (const unsigned short*)xin;

    __shared__ __align__(16) unsigned su[2 * BUFW];

    stage2(xus, (unsigned short*)su, tid, h0p, w0p, zb);

    float asum = 0.f;
    unsigned gp[38];
#pragma unroll
    for (int p = 0; p < 38; ++p) {
        int c0 = 2 * p, c1 = 2 * p + 1;
        float w0 = lg1[c0 * NPIX + pix];
        float w1 = (c1 < 75) ? lg1[c1 * NPIX + pix] : 0.f;
        unsigned b0 = bf16bits(w0), b1 = bf16bits(w1);
        asum += fabsf(__uint_as_float(b0 << 16)) +
                fabsf(__uint_as_float(b1 << 16));
        gp[p] = b0 | (b1 << 16);
    }
    const float inv = 1.f / fmaxf(asum, 1e-12f);

    const int pbase = (ty * ROWSTRIDE + tx + 6) * PIXW;

    float m = -1e30f, l = 0.f, s_acc = 0.f;

    __syncthreads();
    int pb = 0;
    for (int d0 = zb; d0 < dend; d0 += 8) {
        if (d0 + 8 < dend)
            stage2(xus, (unsigned short*)(su + (pb ^ 1) * BUFW), tid, h0p,
                   w0p, d0 + 8);

        const unsigned* sw = su + pb * BUFW + pbase;
        v2f acc01 = {0.f, 0.f}, acc23 = {0.f, 0.f};
        v2f acc45 = {0.f, 0.f}, acc67 = {0.f, 0.f};
#pragma unroll
        for (int i = 0; i < 5; ++i) {
#pragma unroll
            for (int j = 0; j < 5; ++j) {
                const int t = i * 5 + j;
                const float g0 = GW(t);
                const float g1 = GW(25 + t);
                const float g2 = GW(50 + t);
                TAP_BF(sw + (i * ROWSTRIDE + j) * PIXW, g0, g1, g2);
            }
        }

        float acc[8] = {acc01.x, acc01.y, acc23.x, acc23.y,
                        acc45.x, acc45.y, acc67.x, acc67.y};
        if (d0 + 8 <= dend) {
            float v0 = -acc[0] * inv, v1 = -acc[1] * inv;
            float v2 = -acc[2] * inv, v3 = -acc[3] * inv;
            float v4 = -acc[4] * inv, v5 = -acc[5] * inv;
            float v6 = -acc[6] * inv, v7 = -acc[7] * inv;
            float mx = fmaxf(fmaxf(fmaxf(v0, v1), fmaxf(v2, v3)),
                             fmaxf(fmaxf(v4, v5), fmaxf(v6, v7)));
            mx = fmaxf(mx, m);
            float sc = __expf(m - mx);
            float e0 = __expf(v0 - mx), e1 = __expf(v1 - mx);
            float e2 = __expf(v2 - mx), e3 = __expf(v3 - mx);
            float e4 = __expf(v4 - mx), e5 = __expf(v5 - mx);
            float e6 = __expf(v6 - mx), e7 = __expf(v7 - mx);
            l = l * sc + ((e0 + e1) + (e2 + e3)) + ((e4 + e5) + (e6 + e7));
            float fd0 = (float)d0;
            s_acc = s_acc * sc + e0 * fd0 + e1 * (fd0 + 1.f) +
                    e2 * (fd0 + 2.f) + e3 * (fd0 + 3.f) + e4 * (fd0 + 4.f) +
                    e5 * (fd0 + 5.f) + e6 * (fd0 + 6.f) + e7 * (fd0 + 7.f);
            m = mx;
        } else {
#pragma unroll
            for (int dd = 0; dd < 8; ++dd) {
                int d = d0 + dd;
                if (d < dend) {
                    float v = -acc[dd] * inv;
                    float mx = fmaxf(m, v);
                    float sc = __expf(m - mx);
                    float e = __expf(v - mx);
                    l = l * sc + e;
                    s_acc = s_acc * sc + e * (float)d;
                    m = mx;
                }
            }
        }
        __syncthreads();
        pb ^= 1;
    }

    float* pz = part + (size_t)blockIdx.z * 3 * NPIX;
    pz[pix] = m;
    pz[NPIX + pix] = l;
    pz[2 * NPIX + pix] = s_acc;
}
#undef GW

// ---------------------------------------------------------------------------
// Kernel 4: merge NZ online-softmin partials per pixel -> disparity.
// ---------------------------------------------------------------------------
__global__ void reduce2_kernel(const float* __restrict__ part,
                               float* __restrict__ out) {
    int pix = blockIdx.x * blockDim.x + threadIdx.x;
    float M = -1e30f, L = 0.f, S = 0.f;
#pragma unroll
    for (int z = 0; z < NZ; ++z) {
        const float* pz = part + (size_t)z * 3 * NPIX;
        float m = pz[pix];
        float l = pz[NPIX + pix];
        float s = pz[2 * NPIX + pix];
        float mx = fmaxf(M, m);
        float a = __expf(M - mx);
        float b = __expf(m - mx);
        L = L * a + l * b;
        S = S * a + s * b;
        M = mx;
    }
    out[pix] = S / L;
}

// ---------------------------------------------------------------------------
extern "C" void kernel_launch(void* const* d_in, const int* in_sizes, int n_in,
                              void* d_out, int out_size, void* d_ws,
                              size_t ws_size, hipStream_t stream) {
    const float* x = (const float*)d_in[0];
    const float* lg1 = (const float*)d_in[1];
    const float* cw = (const float*)d_in[2];
    float* out = (float*)d_out;

    // ws: c fp32 [100352] | region A bf16 [NUPS] | region B bf16 [NUPS].
    // conv partials [8][NCONV] overlay region B; lga1 writes y1 to region B;
    // lga2 writes (m,l,s) partials to region A.
    float* c = (float*)d_ws;
    __hip_bfloat16* regA = (__hip_bfloat16*)((char*)d_ws + (size_t)NCONV * 4);
    __hip_bfloat16* y1 = regA + (size_t)NUPS;
    float* cpart = (float*)y1;
    float* part = (float*)regA;

    dim3 cgrid(NCONV / 256, CGRP);
    conv3d_kernel<<<cgrid, 256, 0, stream>>>(x, cw, cpart);
    convfold_kernel<<<NCONV / 256, 256, 0, stream>>>(cpart, c);

    dim3 grid(WOUT / 16, HOUT / 16, NZ); // 32 x 16 x 2 = 1024 blocks
    lga1_kernel<<<grid, 256, 0, stream>>>(c, lg1, y1);
    lga2_kernel<<<grid, 256, 0, stream>>>(y1, lg1, part);

    reduce2_kernel<<<NPIX / 256, 256, 0, stream>>>(part, out);
}

// Round 9
// 361.800 us; speedup vs baseline: 1.0987x; 1.0987x over previous
//
#include <hip/hip_runtime.h>
#include <hip/hip_bf16.h>

#define DIN 49
#define HIN 32
#define WIN 64
#define CIN 32
#define DOUT 193
#define HOUT 256
#define WOUT 512
#define NPIX (HOUT * WOUT)      // 131072
#define NUPS (DOUT * NPIX)      // 25296896
#define NCONV (DIN * HIN * WIN) // 100352
#define DSPLIT 97
#define NZ 2 // 97 + 96 planes (z0: 0..96, z1: 97..192) — covers DOUT=193
#define CGRP 8 // conv channel groups (4 ci each)

// LGA LDS geometry: fp32, d-contiguous per pixel (R7 measured-best layout).
#define ROWSTRIDE 33 // pixel-row stride in pixels
#define PIXSTRIDE 12 // words per pixel (10 planes + 2 pad; 48 B, 16B-aligned)
#define SUWORDS 7920

typedef __attribute__((ext_vector_type(2))) float v2f;
typedef __attribute__((ext_vector_type(4))) float v4f;

// Packed fp32 FMA (VOP3P, 3-address, register-only).
__device__ __forceinline__ v2f pk_fma(v2f a, v2f b, v2f c) {
    v2f d;
    asm("v_pk_fma_f32 %0, %1, %2, %3" : "=v"(d) : "v"(a), "v"(b), "v"(c));
    return d;
}

// ---------------------------------------------------------------------------
// Kernel 1: 3x3x3 conv, 32 -> 1 ch, zero pad 1, split 8 ways over channels.
// ---------------------------------------------------------------------------
__global__ void conv3d_kernel(const float* __restrict__ x,
                              const float* __restrict__ w,
                              float* __restrict__ partial) {
    __shared__ float ws[4 * 27];
    const int grp = blockIdx.y;
    for (int t = threadIdx.x; t < 4 * 27; t += blockDim.x)
        ws[t] = w[grp * (4 * 27) + t];
    __syncthreads();

    int idx = blockIdx.x * blockDim.x + threadIdx.x; // NCONV = 392*256 exact
    int wq = idx % WIN;
    int t2 = idx / WIN;
    int hq = t2 % HIN;
    int dq = t2 / HIN;

    float acc = 0.f;
    const float* xg = x + (size_t)grp * 4 * NCONV;
#pragma unroll
    for (int cl = 0; cl < 4; ++cl) {
        const float* xb = xg + cl * NCONV;
        const float* wb = ws + cl * 27;
#pragma unroll
        for (int kd = 0; kd < 3; ++kd) {
            int zd = dq + kd - 1;
            if (zd < 0 || zd >= DIN) continue;
#pragma unroll
            for (int kh = 0; kh < 3; ++kh) {
                int zh = hq + kh - 1;
                if (zh < 0 || zh >= HIN) continue;
#pragma unroll
                for (int kw = 0; kw < 3; ++kw) {
                    int zw = wq + kw - 1;
                    if (zw < 0 || zw >= WIN) continue;
                    acc += xb[(zd * HIN + zh) * WIN + zw] *
                           wb[(kd * 3 + kh) * 3 + kw];
                }
            }
        }
    }
    partial[(size_t)grp * NCONV + idx] = acc;
}

// ---------------------------------------------------------------------------
// Kernel 1b: fold 8 conv partials -> c.
// ---------------------------------------------------------------------------
__global__ void convfold_kernel(const float* __restrict__ partial,
                                float* __restrict__ c) {
    int idx = blockIdx.x * blockDim.x + threadIdx.x;
    float s = 0.f;
#pragma unroll
    for (int g = 0; g < CGRP; ++g) s += partial[(size_t)g * NCONV + idx];
    c[idx] = s;
}

__device__ __forceinline__ unsigned short bf16bits(float f) {
    __hip_bfloat16 h = __float2bfloat16(f);
    unsigned short b;
    __builtin_memcpy(&b, &h, 2);
    return b;
}

// weight #idx (0..74), idx compile-time
#define GW(idx)                                                  \
    __uint_as_float(((idx) & 1) ? (gp[(idx) >> 1] & 0xFFFF0000u) \
                                : (gp[(idx) >> 1] << 16))

// Packed-pair tap body (R7 measured core): 8 pk_fma + 8 scalar fmaf.
#define TAP_PK(A0, A1, B0, B1, C0, g0, g1, g2)   \
    do {                                         \
        v2f g1b = {g1, g1};                      \
        v2f g2b = {g2, g2};                      \
        acc01 = pk_fma(g1b, A0, acc01);          \
        acc01 = pk_fma(g2b, A1, acc01);          \
        acc23 = pk_fma(g1b, A1, acc23);          \
        acc23 = pk_fma(g2b, B0, acc23);          \
        acc45 = pk_fma(g1b, B0, acc45);          \
        acc45 = pk_fma(g2b, B1, acc45);          \
        acc67 = pk_fma(g1b, B1, acc67);          \
        acc67 = pk_fma(g2b, C0, acc67);          \
        acc01.x = fmaf(g0, A0.y, acc01.x);       \
        acc01.y = fmaf(g0, A1.x, acc01.y);       \
        acc23.x = fmaf(g0, A1.y, acc23.x);       \
        acc23.y = fmaf(g0, B0.x, acc23.y);       \
        acc45.x = fmaf(g0, B0.y, acc45.x);       \
        acc45.y = fmaf(g0, B1.x, acc45.y);       \
        acc67.x = fmaf(g0, B1.y, acc67.x);       \
        acc67.y = fmaf(g0, C0.x, acc67.y);       \
    } while (0)

// ---------------------------------------------------------------------------
// lga1 staging phase A: trilinear d/h-lerp from c (L2-hot) into 6 packed
// bf16 regs per thread (R6 diet). Issued EARLY so the 12 L2 loads/job hide
// under the concurrent compute region (T14).
// ---------------------------------------------------------------------------
__device__ __forceinline__ void stageA1(const float* __restrict__ cvol,
                                        int tid, int h0p, int w0p, int dstart,
                                        unsigned (&aq0)[4], unsigned (&aq2)[2]) {
    aq2[0] = 0u;
    aq2[1] = 0u;
#pragma unroll
    for (int k = 0; k < 4; ++k) {
        const bool a = (k < 3) || (tid < 32); // NJOBS = 800
        int j = tid + k * 256;
        int seg = j & 3;
        int rowjob = j >> 2;
        int dl = rowjob / 20;
        int r = rowjob - dl * 20;
        int gh = h0p - 2 + r;
        int gwb = w0p - 8 + seg * 8;
        int gd = dstart - 1 + dl;
        if (a && gd >= 0 && gd < DOUT && gh >= 0 && gh < HOUT && gwb >= 0 &&
            (gwb + 8) <= WOUT) {
            float fd = (gd + 0.5f) * (49.0f / 193.0f) - 0.5f;
            fd = fminf(fmaxf(fd, 0.f), (float)(DIN - 1));
            int d0c = min((int)fd, DIN - 2);
            float ad = fd - (float)d0c;
            float fh = (gh + 0.5f) * 0.125f - 0.5f;
            fh = fminf(fmaxf(fh, 0.f), (float)(HIN - 1));
            int h0c = min((int)fh, HIN - 2);
            float ah = fh - (float)h0c;
            int g = gwb >> 3;
            int cm1 = max(g - 1, 0);
            int cp1 = min(g + 1, WIN - 1);
            const float* p00 = cvol + (d0c * HIN + h0c) * WIN;
            const float* p01 = p00 + WIN;
            const float* p10 = p00 + HIN * WIN;
            const float* p11 = p10 + WIN;
            float q00, q01, q10, q11, a0, a1, a2;
            q00 = p00[cm1]; q01 = p01[cm1];
            q10 = p10[cm1]; q11 = p11[cm1];
            a0 = (q00 + ah * (q01 - q00)) * (1.f - ad) +
                 (q10 + ah * (q11 - q10)) * ad;
            q00 = p00[g]; q01 = p01[g];
            q10 = p10[g]; q11 = p11[g];
            a1 = (q00 + ah * (q01 - q00)) * (1.f - ad) +
                 (q10 + ah * (q11 - q10)) * ad;
            q00 = p00[cp1]; q01 = p01[cp1];
            q10 = p10[cp1]; q11 = p11[cp1];
            a2 = (q00 + ah * (q01 - q00)) * (1.f - ad) +
                 (q10 + ah * (q11 - q10)) * ad;
            aq0[k] = (unsigned)bf16bits(a0) | ((unsigned)bf16bits(a1) << 16);
            aq2[k >> 1] |= ((unsigned)bf16bits(a2)) << ((k & 1) * 16);
        } else {
            aq0[k] = 0u;
        }
    }
}

// lga1 scatter phase B: compile-time-weight w-lerp from regs into LDS.
__device__ __forceinline__ void scat1(float* __restrict__ su, int tid,
                                      const unsigned (&aq0)[4],
                                      const unsigned (&aq2)[2]) {
#pragma unroll
    for (int k = 0; k < 4; ++k) {
        if (k < 3 || tid < 32) {
            int j = tid + k * 256;
            int seg = j & 3;
            int rowjob = j >> 2;
            int dl = rowjob / 20;
            int r = rowjob - dl * 20;
            int base = (r * ROWSTRIDE + seg * 8) * PIXSTRIDE + dl;
            float a0 = __uint_as_float(aq0[k] << 16);
            float a1 = __uint_as_float(aq0[k] & 0xFFFF0000u);
            float a2 = __uint_as_float((k & 1) ? (aq2[k >> 1] & 0xFFFF0000u)
                                               : (aq2[k >> 1] << 16));
            float d01 = a1 - a0, d12 = a2 - a1;
            su[base + 0 * PIXSTRIDE] = a0 + 0.5625f * d01;
            su[base + 1 * PIXSTRIDE] = a0 + 0.6875f * d01;
            su[base + 2 * PIXSTRIDE] = a0 + 0.8125f * d01;
            su[base + 3 * PIXSTRIDE] = a0 + 0.9375f * d01;
            su[base + 4 * PIXSTRIDE] = a1 + 0.0625f * d12;
            su[base + 5 * PIXSTRIDE] = a1 + 0.1875f * d12;
            su[base + 6 * PIXSTRIDE] = a1 + 0.3125f * d12;
            su[base + 7 * PIXSTRIDE] = a1 + 0.4375f * d12;
        }
    }
}

// lga2 staging phase A: one uint4 (8 bf16) HBM load per job into regs.
__device__ __forceinline__ void stageA2(const unsigned short* __restrict__ xus,
                                        int tid, int h0p, int w0p, int dstart,
                                        uint4 (&dat)[4]) {
#pragma unroll
    for (int k = 0; k < 4; ++k) {
        const bool a = (k < 3) || (tid < 32); // NJOBS = 800
        int j = tid + k * 256;
        int seg = j & 3;
        int rowjob = j >> 2;
        int dl = rowjob / 20;
        int r = rowjob - dl * 20;
        int gh = h0p - 2 + r;
        int gwb = w0p - 8 + seg * 8;
        int gd = dstart - 1 + dl;
        uint4 v = make_uint4(0u, 0u, 0u, 0u);
        if (a && gd >= 0 && gd < DOUT && gh >= 0 && gh < HOUT && gwb >= 0 &&
            (gwb + 8) <= WOUT)
            v = *(const uint4*)(xus + (size_t)gd * NPIX + gh * WOUT + gwb);
        dat[k] = v;
    }
}

// lga2 scatter phase B: unpack bf16 pairs from regs into LDS.
__device__ __forceinline__ void scat2(float* __restrict__ su, int tid,
                                      const uint4 (&dat)[4]) {
#pragma unroll
    for (int k = 0; k < 4; ++k) {
        if (k < 3 || tid < 32) {
            int j = tid + k * 256;
            int seg = j & 3;
            int rowjob = j >> 2;
            int dl = rowjob / 20;
            int r = rowjob - dl * 20;
            int base = (r * ROWSTRIDE + seg * 8) * PIXSTRIDE + dl;
            unsigned q;
            q = dat[k].x;
            su[base + 0 * PIXSTRIDE] = __uint_as_float(q << 16);
            su[base + 1 * PIXSTRIDE] = __uint_as_float(q & 0xFFFF0000u);
            q = dat[k].y;
            su[base + 2 * PIXSTRIDE] = __uint_as_float(q << 16);
            su[base + 3 * PIXSTRIDE] = __uint_as_float(q & 0xFFFF0000u);
            q = dat[k].z;
            su[base + 4 * PIXSTRIDE] = __uint_as_float(q << 16);
            su[base + 5 * PIXSTRIDE] = __uint_as_float(q & 0xFFFF0000u);
            q = dat[k].w;
            su[base + 6 * PIXSTRIDE] = __uint_as_float(q << 16);
            su[base + 7 * PIXSTRIDE] = __uint_as_float(q & 0xFFFF0000u);
        }
    }
}

// ---------------------------------------------------------------------------
// LGA pass 1. R7 fp32 core; phase A software-pipelined: loads+lerp for chunk
// k+1 issue in the same barrier-free region as compute of chunk k, so L2
// latency and lerp VALU hide under the FMA stream. amdgpu_num_vgpr(128) pin.
// ---------------------------------------------------------------------------
__global__ __launch_bounds__(256)
__attribute__((amdgpu_num_vgpr(128))) void lga1_kernel(
    const float* __restrict__ cvol,
    const float* __restrict__ lg1,
    __hip_bfloat16* __restrict__ yout) {
    const int tid = threadIdx.x;
    const int tx = tid & 15;
    const int ty = tid >> 4;
    const int w0p = blockIdx.x * 16;
    const int h0p = blockIdx.y * 16;
    const int zb = blockIdx.z * DSPLIT;
    const int dend = min(zb + DSPLIT, DOUT);
    const int pix = (h0p + ty) * WOUT + (w0p + tx);

    __shared__ __align__(16) float su[SUWORDS];

    // prologue phase A (chunk 0): loads land under the guidance preamble
    unsigned aq0[4], aq2[2];
    stageA1(cvol, tid, h0p, w0p, zb, aq0, aq2);

    // ---- guidance: single pass, un-normalized, bf16 pairs (38 regs) ----
    float asum = 0.f;
    unsigned gp[38];
#pragma unroll
    for (int p = 0; p < 38; ++p) {
        int c0 = 2 * p, c1 = 2 * p + 1;
        float w0 = lg1[c0 * NPIX + pix];
        float w1 = (c1 < 75) ? lg1[c1 * NPIX + pix] : 0.f;
        unsigned b0 = bf16bits(w0), b1 = bf16bits(w1);
        asum += fabsf(__uint_as_float(b0 << 16)) +
                fabsf(__uint_as_float(b1 << 16));
        gp[p] = b0 | (b1 << 16);
    }
    const float inv = 1.f / fmaxf(asum, 1e-12f);

    const int pbase = (ty * ROWSTRIDE + tx + 6) * PIXSTRIDE;
    __hip_bfloat16* ybase = yout + pix;

    for (int d0 = zb; d0 < dend; d0 += 8) {
        __syncthreads(); // previous chunk's readers done (no-op first iter)
        scat1(su, tid, aq0, aq2);
        __syncthreads();
        if (d0 + 8 < dend)
            stageA1(cvol, tid, h0p, w0p, d0 + 8, aq0, aq2); // overlaps compute

        v2f acc01 = {0.f, 0.f}, acc23 = {0.f, 0.f};
        v2f acc45 = {0.f, 0.f}, acc67 = {0.f, 0.f};
#pragma unroll
        for (int i = 0; i < 5; ++i) {
#pragma unroll
            for (int j = 0; j < 5; ++j) {
                const int t = i * 5 + j;
                const float* sp = su + pbase + (i * ROWSTRIDE + j) * PIXSTRIDE;
                v4f va = *(const v4f*)sp;
                v4f vb = *(const v4f*)(sp + 4);
                v2f vc = *(const v2f*)(sp + 8);
                v2f A0 = va.xy, A1 = va.zw, B0 = vb.xy, B1 = vb.zw;
                const float g0 = GW(t);
                const float g1 = GW(25 + t);
                const float g2 = GW(50 + t);
                TAP_PK(A0, A1, B0, B1, vc, g0, g1, g2);
            }
        }

        float acc[8] = {acc01.x, acc01.y, acc23.x, acc23.y,
                        acc45.x, acc45.y, acc67.x, acc67.y};
        if (d0 + 8 <= dend) {
#pragma unroll
            for (int dd = 0; dd < 8; ++dd)
                ybase[(size_t)(d0 + dd) * NPIX] =
                    __float2bfloat16(acc[dd] * inv);
        } else {
#pragma unroll
            for (int dd = 0; dd < 8; ++dd)
                if (d0 + dd < dend)
                    ybase[(size_t)(d0 + dd) * NPIX] =
                        __float2bfloat16(acc[dd] * inv);
        }
    }
}

// ---------------------------------------------------------------------------
// LGA pass 2: same pipelined structure; phase A is a pure uint4 HBM load
// (16 regs across compute); fused online softmin.
// ---------------------------------------------------------------------------
__global__ __launch_bounds__(256)
__attribute__((amdgpu_num_vgpr(128))) void lga2_kernel(
    const __hip_bfloat16* __restrict__ xin,
    const float* __restrict__ lg1,
    float* __restrict__ part) {
    const int tid = threadIdx.x;
    const int tx = tid & 15;
    const int ty = tid >> 4;
    const int w0p = blockIdx.x * 16;
    const int h0p = blockIdx.y * 16;
    const int zb = blockIdx.z * DSPLIT;
    const int dend = min(zb + DSPLIT, DOUT);
    const int pix = (h0p + ty) * WOUT + (w0p + tx);
    const unsigned short* xus = (const unsigned short*)xin;

    __shared__ __align__(16) float su[SUWORDS];

    uint4 dat[4];
    stageA2(xus, tid, h0p, w0p, zb, dat);

    float asum = 0.f;
    unsigned gp[38];
#pragma unroll
    for (int p = 0; p < 38; ++p) {
        int c0 = 2 * p, c1 = 2 * p + 1;
        float w0 = lg1[c0 * NPIX + pix];
        float w1 = (c1 < 75) ? lg1[c1 * NPIX + pix] : 0.f;
        unsigned b0 = bf16bits(w0), b1 = bf16bits(w1);
        asum += fabsf(__uint_as_float(b0 << 16)) +
                fabsf(__uint_as_float(b1 << 16));
        gp[p] = b0 | (b1 << 16);
    }
    const float inv = 1.f / fmaxf(asum, 1e-12f);

    const int pbase = (ty * ROWSTRIDE + tx + 6) * PIXSTRIDE;

    float m = -1e30f, l = 0.f, s_acc = 0.f;

    for (int d0 = zb; d0 < dend; d0 += 8) {
        __syncthreads();
        scat2(su, tid, dat);
        __syncthreads();
        if (d0 + 8 < dend)
            stageA2(xus, tid, h0p, w0p, d0 + 8, dat); // overlaps compute

        v2f acc01 = {0.f, 0.f}, acc23 = {0.f, 0.f};
        v2f acc45 = {0.f, 0.f}, acc67 = {0.f, 0.f};
#pragma unroll
        for (int i = 0; i < 5; ++i) {
#pragma unroll
            for (int j = 0; j < 5; ++j) {
                const int t = i * 5 + j;
                const float* sp = su + pbase + (i * ROWSTRIDE + j) * PIXSTRIDE;
                v4f va = *(const v4f*)sp;
                v4f vb = *(const v4f*)(sp + 4);
                v2f vc = *(const v2f*)(sp + 8);
                v2f A0 = va.xy, A1 = va.zw, B0 = vb.xy, B1 = vb.zw;
                const float g0 = GW(t);
                const float g1 = GW(25 + t);
                const float g2 = GW(50 + t);
                TAP_PK(A0, A1, B0, B1, vc, g0, g1, g2);
            }
        }

        float acc[8] = {acc01.x, acc01.y, acc23.x, acc23.y,
                        acc45.x, acc45.y, acc67.x, acc67.y};
        if (d0 + 8 <= dend) {
            float v0 = -acc[0] * inv, v1 = -acc[1] * inv;
            float v2 = -acc[2] * inv, v3 = -acc[3] * inv;
            float v4 = -acc[4] * inv, v5 = -acc[5] * inv;
            float v6 = -acc[6] * inv, v7 = -acc[7] * inv;
            float mx = fmaxf(fmaxf(fmaxf(v0, v1), fmaxf(v2, v3)),
                             fmaxf(fmaxf(v4, v5), fmaxf(v6, v7)));
            mx = fmaxf(mx, m);
            float sc = __expf(m - mx);
            float e0 = __expf(v0 - mx), e1 = __expf(v1 - mx);
            float e2 = __expf(v2 - mx), e3 = __expf(v3 - mx);
            float e4 = __expf(v4 - mx), e5 = __expf(v5 - mx);
            float e6 = __expf(v6 - mx), e7 = __expf(v7 - mx);
            l = l * sc + ((e0 + e1) + (e2 + e3)) + ((e4 + e5) + (e6 + e7));
            float fd0 = (float)d0;
            s_acc = s_acc * sc + e0 * fd0 + e1 * (fd0 + 1.f) +
                    e2 * (fd0 + 2.f) + e3 * (fd0 + 3.f) + e4 * (fd0 + 4.f) +
                    e5 * (fd0 + 5.f) + e6 * (fd0 + 6.f) + e7 * (fd0 + 7.f);
            m = mx;
        } else {
#pragma unroll
            for (int dd = 0; dd < 8; ++dd) {
                int d = d0 + dd;
                if (d < dend) {
                    float v = -acc[dd] * inv;
                    float mx = fmaxf(m, v);
                    float sc = __expf(m - mx);
                    float e = __expf(v - mx);
                    l = l * sc + e;
                    s_acc = s_acc * sc + e * (float)d;
                    m = mx;
                }
            }
        }
    }

    float* pz = part + (size_t)blockIdx.z * 3 * NPIX;
    pz[pix] = m;
    pz[NPIX + pix] = l;
    pz[2 * NPIX + pix] = s_acc;
}
#undef GW

// ---------------------------------------------------------------------------
// Kernel 4: merge NZ online-softmin partials per pixel -> disparity.
// ---------------------------------------------------------------------------
__global__ void reduce2_kernel(const float* __restrict__ part,
                               float* __restrict__ out) {
    int pix = blockIdx.x * blockDim.x + threadIdx.x;
    float M = -1e30f, L = 0.f, S = 0.f;
#pragma unroll
    for (int z = 0; z < NZ; ++z) {
        const float* pz = part + (size_t)z * 3 * NPIX;
        float m = pz[pix];
        float l = pz[NPIX + pix];
        float s = pz[2 * NPIX + pix];
        float mx = fmaxf(M, m);
        float a = __expf(M - mx);
        float b = __expf(m - mx);
        L = L * a + l * b;
        S = S * a + s * b;
        M = mx;
    }
    out[pix] = S / L;
}

// ---------------------------------------------------------------------------
extern "C" void kernel_launch(void* const* d_in, const int* in_sizes, int n_in,
                              void* d_out, int out_size, void* d_ws,
                              size_t ws_size, hipStream_t stream) {
    const float* x = (const float*)d_in[0];
    const float* lg1 = (const float*)d_in[1];
    const float* cw = (const float*)d_in[2];
    float* out = (float*)d_out;

    // ws: c fp32 [100352] | region A bf16 [NUPS] | region B bf16 [NUPS].
    // conv partials [8][NCONV] overlay region B; lga1 writes y1 to region B;
    // lga2 writes (m,l,s) partials to region A.
    float* c = (float*)d_ws;
    __hip_bfloat16* regA = (__hip_bfloat16*)((char*)d_ws + (size_t)NCONV * 4);
    __hip_bfloat16* y1 = regA + (size_t)NUPS;
    float* cpart = (float*)y1;
    float* part = (float*)regA;

    dim3 cgrid(NCONV / 256, CGRP);
    conv3d_kernel<<<cgrid, 256, 0, stream>>>(x, cw, cpart);
    convfold_kernel<<<NCONV / 256, 256, 0, stream>>>(cpart, c);

    dim3 grid(WOUT / 16, HOUT / 16, NZ); // 32 x 16 x 2 = 1024 blocks
    lga1_kernel<<<grid, 256, 0, stream>>>(c, lg1, y1);
    lga2_kernel<<<grid, 256, 0, stream>>>(y1, lg1, part);

    reduce2_kernel<<<NPIX / 256, 256, 0, stream>>>(part, out);
}

// Round 10
// 341.117 us; speedup vs baseline: 1.1654x; 1.0606x over previous
//
#include <hip/hip_runtime.h>
#include <hip/hip_bf16.h>

#define DIN 49
#define HIN 32
#define WIN 64
#define CIN 32
#define DOUT 193
#define HOUT 256
#define WOUT 512
#define NPIX (HOUT * WOUT)      // 131072
#define NUPS (DOUT * NPIX)      // 25296896
#define NCONV (DIN * HIN * WIN) // 100352
#define DSPLIT 97
#define NZ 2 // 97 + 96 planes (z0: 0..96, z1: 97..192) — covers DOUT=193
#define CGRP 8 // conv channel groups (4 ci each)

// LGA LDS geometry: fp32, d-contiguous per pixel (R7 measured-best layout).
#define ROWSTRIDE 33 // pixel-row stride in pixels
#define PIXSTRIDE 12 // words per pixel (10 planes + 2 pad; 48 B, 16B-aligned)
#define SUWORDS 7920

typedef __attribute__((ext_vector_type(2))) float v2f;
typedef __attribute__((ext_vector_type(4))) float v4f;

// Packed fp32 FMA (VOP3P, 3-address, register-only).
__device__ __forceinline__ v2f pk_fma(v2f a, v2f b, v2f c) {
    v2f d;
    asm("v_pk_fma_f32 %0, %1, %2, %3" : "=v"(d) : "v"(a), "v"(b), "v"(c));
    return d;
}

// ---------------------------------------------------------------------------
// Kernel 1: 3x3x3 conv, 32 -> 1 ch, zero pad 1, split 8 ways over channels.
// 4-wide w-vectorized: one aligned float4 + 2 guarded edge scalars per
// (ch, kd, kh) row feeds 12 fmaf — 4x fewer load-instructions per output
// than the scalar-per-tap form (which was issue-bound, not FLOP-bound).
// ---------------------------------------------------------------------------
__global__ void conv3d_kernel(const float* __restrict__ x,
                              const float* __restrict__ w,
                              float* __restrict__ partial) {
    __shared__ float ws[4 * 27];
    const int grp = blockIdx.y;
    for (int t = threadIdx.x; t < 4 * 27; t += blockDim.x)
        ws[t] = w[grp * (4 * 27) + t];
    __syncthreads();

    int idx4 = blockIdx.x * blockDim.x + threadIdx.x; // 25088 = 98*256 exact
    int w4 = idx4 & 15;  // WIN/4 = 16
    int t2 = idx4 >> 4;
    int hq = t2 & 31;    // HIN = 32
    int dq = t2 >> 5;    // dq in [0, 49)
    int wq0 = w4 * 4;

    float acc0 = 0.f, acc1 = 0.f, acc2 = 0.f, acc3 = 0.f;
    const float* xg = x + (size_t)grp * 4 * NCONV;
#pragma unroll
    for (int cl = 0; cl < 4; ++cl) {
        const float* xb = xg + cl * NCONV;
        const float* wb = ws + cl * 27;
#pragma unroll
        for (int kd = 0; kd < 3; ++kd) {
            int zd = dq + kd - 1;
            if (zd < 0 || zd >= DIN) continue;
#pragma unroll
            for (int kh = 0; kh < 3; ++kh) {
                int zh = hq + kh - 1;
                if (zh < 0 || zh >= HIN) continue;
                const float* row = xb + (zd * HIN + zh) * WIN;
                float4 v = *(const float4*)(row + wq0);
                float xl = (wq0 > 0) ? row[wq0 - 1] : 0.f;
                float xr = (wq0 < WIN - 4) ? row[wq0 + 4] : 0.f;
                float w0 = wb[(kd * 3 + kh) * 3 + 0];
                float w1 = wb[(kd * 3 + kh) * 3 + 1];
                float w2 = wb[(kd * 3 + kh) * 3 + 2];
                // window = [xl, v.x, v.y, v.z, v.w, xr]; out o uses
                // window[o]*w0 + window[o+1]*w1 + window[o+2]*w2
                acc0 = fmaf(w0, xl, acc0);
                acc0 = fmaf(w1, v.x, acc0);
                acc0 = fmaf(w2, v.y, acc0);
                acc1 = fmaf(w0, v.x, acc1);
                acc1 = fmaf(w1, v.y, acc1);
                acc1 = fmaf(w2, v.z, acc1);
                acc2 = fmaf(w0, v.y, acc2);
                acc2 = fmaf(w1, v.z, acc2);
                acc2 = fmaf(w2, v.w, acc2);
                acc3 = fmaf(w0, v.z, acc3);
                acc3 = fmaf(w1, v.w, acc3);
                acc3 = fmaf(w2, xr, acc3);
            }
        }
    }
    float4 o4 = make_float4(acc0, acc1, acc2, acc3);
    *(float4*)(partial + (size_t)grp * NCONV + (size_t)idx4 * 4) = o4;
}

// ---------------------------------------------------------------------------
// Kernel 1b: fold 8 conv partials -> c.
// ---------------------------------------------------------------------------
__global__ void convfold_kernel(const float* __restrict__ partial,
                                float* __restrict__ c) {
    int idx = blockIdx.x * blockDim.x + threadIdx.x;
    float s = 0.f;
#pragma unroll
    for (int g = 0; g < CGRP; ++g) s += partial[(size_t)g * NCONV + idx];
    c[idx] = s;
}

__device__ __forceinline__ unsigned short bf16bits(float f) {
    __hip_bfloat16 h = __float2bfloat16(f);
    unsigned short b;
    __builtin_memcpy(&b, &h, 2);
    return b;
}

// weight #idx (0..74), idx compile-time
#define GW(idx)                                                  \
    __uint_as_float(((idx) & 1) ? (gp[(idx) >> 1] & 0xFFFF0000u) \
                                : (gp[(idx) >> 1] << 16))

// Packed-pair tap body (R7 measured core): 8 pk_fma + 8 scalar fmaf.
#define TAP_PK(A0, A1, B0, B1, C0, g0, g1, g2)   \
    do {                                         \
        v2f g1b = {g1, g1};                      \
        v2f g2b = {g2, g2};                      \
        acc01 = pk_fma(g1b, A0, acc01);          \
        acc01 = pk_fma(g2b, A1, acc01);          \
        acc23 = pk_fma(g1b, A1, acc23);          \
        acc23 = pk_fma(g2b, B0, acc23);          \
        acc45 = pk_fma(g1b, B0, acc45);          \
        acc45 = pk_fma(g2b, B1, acc45);          \
        acc67 = pk_fma(g1b, B1, acc67);          \
        acc67 = pk_fma(g2b, C0, acc67);          \
        acc01.x = fmaf(g0, A0.y, acc01.x);       \
        acc01.y = fmaf(g0, A1.x, acc01.y);       \
        acc23.x = fmaf(g0, A1.y, acc23.x);       \
        acc23.y = fmaf(g0, B0.x, acc23.y);       \
        acc45.x = fmaf(g0, B0.y, acc45.x);       \
        acc45.y = fmaf(g0, B1.x, acc45.y);       \
        acc67.x = fmaf(g0, B1.y, acc67.x);       \
        acc67.y = fmaf(g0, C0.x, acc67.y);       \
    } while (0)

// ---------------------------------------------------------------------------
// lga1 staging phase A: trilinear d/h-lerp from c (L2-hot) into 6 packed
// bf16 regs per thread (R6 diet). Issued EARLY so the 12 L2 loads/job hide
// under the concurrent compute region (T14).
// ---------------------------------------------------------------------------
__device__ __forceinline__ void stageA1(const float* __restrict__ cvol,
                                        int tid, int h0p, int w0p, int dstart,
                                        unsigned (&aq0)[4], unsigned (&aq2)[2]) {
    aq2[0] = 0u;
    aq2[1] = 0u;
#pragma unroll
    for (int k = 0; k < 4; ++k) {
        const bool a = (k < 3) || (tid < 32); // NJOBS = 800
        int j = tid + k * 256;
        int seg = j & 3;
        int rowjob = j >> 2;
        int dl = rowjob / 20;
        int r = rowjob - dl * 20;
        int gh = h0p - 2 + r;
        int gwb = w0p - 8 + seg * 8;
        int gd = dstart - 1 + dl;
        if (a && gd >= 0 && gd < DOUT && gh >= 0 && gh < HOUT && gwb >= 0 &&
            (gwb + 8) <= WOUT) {
            float fd = (gd + 0.5f) * (49.0f / 193.0f) - 0.5f;
            fd = fminf(fmaxf(fd, 0.f), (float)(DIN - 1));
            int d0c = min((int)fd, DIN - 2);
            float ad = fd - (float)d0c;
            float fh = (gh + 0.5f) * 0.125f - 0.5f;
            fh = fminf(fmaxf(fh, 0.f), (float)(HIN - 1));
            int h0c = min((int)fh, HIN - 2);
            float ah = fh - (float)h0c;
            int g = gwb >> 3;
            int cm1 = max(g - 1, 0);
            int cp1 = min(g + 1, WIN - 1);
            const float* p00 = cvol + (d0c * HIN + h0c) * WIN;
            const float* p01 = p00 + WIN;
            const float* p10 = p00 + HIN * WIN;
            const float* p11 = p10 + WIN;
            float q00, q01, q10, q11, a0, a1, a2;
            q00 = p00[cm1]; q01 = p01[cm1];
            q10 = p10[cm1]; q11 = p11[cm1];
            a0 = (q00 + ah * (q01 - q00)) * (1.f - ad) +
                 (q10 + ah * (q11 - q10)) * ad;
            q00 = p00[g]; q01 = p01[g];
            q10 = p10[g]; q11 = p11[g];
            a1 = (q00 + ah * (q01 - q00)) * (1.f - ad) +
                 (q10 + ah * (q11 - q10)) * ad;
            q00 = p00[cp1]; q01 = p01[cp1];
            q10 = p10[cp1]; q11 = p11[cp1];
            a2 = (q00 + ah * (q01 - q00)) * (1.f - ad) +
                 (q10 + ah * (q11 - q10)) * ad;
            aq0[k] = (unsigned)bf16bits(a0) | ((unsigned)bf16bits(a1) << 16);
            aq2[k >> 1] |= ((unsigned)bf16bits(a2)) << ((k & 1) * 16);
        } else {
            aq0[k] = 0u;
        }
    }
}

// lga1 scatter phase B: compile-time-weight w-lerp from regs into LDS.
__device__ __forceinline__ void scat1(float* __restrict__ su, int tid,
                                      const unsigned (&aq0)[4],
                                      const unsigned (&aq2)[2]) {
#pragma unroll
    for (int k = 0; k < 4; ++k) {
        if (k < 3 || tid < 32) {
            int j = tid + k * 256;
            int seg = j & 3;
            int rowjob = j >> 2;
            int dl = rowjob / 20;
            int r = rowjob - dl * 20;
            int base = (r * ROWSTRIDE + seg * 8) * PIXSTRIDE + dl;
            float a0 = __uint_as_float(aq0[k] << 16);
            float a1 = __uint_as_float(aq0[k] & 0xFFFF0000u);
            float a2 = __uint_as_float((k & 1) ? (aq2[k >> 1] & 0xFFFF0000u)
                                               : (aq2[k >> 1] << 16));
            float d01 = a1 - a0, d12 = a2 - a1;
            su[base + 0 * PIXSTRIDE] = a0 + 0.5625f * d01;
            su[base + 1 * PIXSTRIDE] = a0 + 0.6875f * d01;
            su[base + 2 * PIXSTRIDE] = a0 + 0.8125f * d01;
            su[base + 3 * PIXSTRIDE] = a0 + 0.9375f * d01;
            su[base + 4 * PIXSTRIDE] = a1 + 0.0625f * d12;
            su[base + 5 * PIXSTRIDE] = a1 + 0.1875f * d12;
            su[base + 6 * PIXSTRIDE] = a1 + 0.3125f * d12;
            su[base + 7 * PIXSTRIDE] = a1 + 0.4375f * d12;
        }
    }
}

// lga2 staging phase A: one uint4 (8 bf16) HBM load per job into regs.
__device__ __forceinline__ void stageA2(const unsigned short* __restrict__ xus,
                                        int tid, int h0p, int w0p, int dstart,
                                        uint4 (&dat)[4]) {
#pragma unroll
    for (int k = 0; k < 4; ++k) {
        const bool a = (k < 3) || (tid < 32); // NJOBS = 800
        int j = tid + k * 256;
        int seg = j & 3;
        int rowjob = j >> 2;
        int dl = rowjob / 20;
        int r = rowjob - dl * 20;
        int gh = h0p - 2 + r;
        int gwb = w0p - 8 + seg * 8;
        int gd = dstart - 1 + dl;
        uint4 v = make_uint4(0u, 0u, 0u, 0u);
        if (a && gd >= 0 && gd < DOUT && gh >= 0 && gh < HOUT && gwb >= 0 &&
            (gwb + 8) <= WOUT)
            v = *(const uint4*)(xus + (size_t)gd * NPIX + gh * WOUT + gwb);
        dat[k] = v;
    }
}

// lga2 scatter phase B: unpack bf16 pairs from regs into LDS.
__device__ __forceinline__ void scat2(float* __restrict__ su, int tid,
                                      const uint4 (&dat)[4]) {
#pragma unroll
    for (int k = 0; k < 4; ++k) {
        if (k < 3 || tid < 32) {
            int j = tid + k * 256;
            int seg = j & 3;
            int rowjob = j >> 2;
            int dl = rowjob / 20;
            int r = rowjob - dl * 20;
            int base = (r * ROWSTRIDE + seg * 8) * PIXSTRIDE + dl;
            unsigned q;
            q = dat[k].x;
            su[base + 0 * PIXSTRIDE] = __uint_as_float(q << 16);
            su[base + 1 * PIXSTRIDE] = __uint_as_float(q & 0xFFFF0000u);
            q = dat[k].y;
            su[base + 2 * PIXSTRIDE] = __uint_as_float(q << 16);
            su[base + 3 * PIXSTRIDE] = __uint_as_float(q & 0xFFFF0000u);
            q = dat[k].z;
            su[base + 4 * PIXSTRIDE] = __uint_as_float(q << 16);
            su[base + 5 * PIXSTRIDE] = __uint_as_float(q & 0xFFFF0000u);
            q = dat[k].w;
            su[base + 6 * PIXSTRIDE] = __uint_as_float(q << 16);
            su[base + 7 * PIXSTRIDE] = __uint_as_float(q & 0xFFFF0000u);
        }
    }
}

// ---------------------------------------------------------------------------
// LGA pass 1. R7 fp32 core; phase A software-pipelined: loads+lerp for chunk
// k+1 issue in the same barrier-free region as compute of chunk k, so L2
// latency and lerp VALU hide under the FMA stream. amdgpu_num_vgpr(128) pin.
// ---------------------------------------------------------------------------
__global__ __launch_bounds__(256)
__attribute__((amdgpu_num_vgpr(128))) void lga1_kernel(
    const float* __restrict__ cvol,
    const float* __restrict__ lg1,
    __hip_bfloat16* __restrict__ yout) {
    const int tid = threadIdx.x;
    const int tx = tid & 15;
    const int ty = tid >> 4;
    const int w0p = blockIdx.x * 16;
    const int h0p = blockIdx.y * 16;
    const int zb = blockIdx.z * DSPLIT;
    const int dend = min(zb + DSPLIT, DOUT);
    const int pix = (h0p + ty) * WOUT + (w0p + tx);

    __shared__ __align__(16) float su[SUWORDS];

    // prologue phase A (chunk 0): loads land under the guidance preamble
    unsigned aq0[4], aq2[2];
    stageA1(cvol, tid, h0p, w0p, zb, aq0, aq2);

    // ---- guidance: single pass, un-normalized, bf16 pairs (38 regs) ----
    float asum = 0.f;
    unsigned gp[38];
#pragma unroll
    for (int p = 0; p < 38; ++p) {
        int c0 = 2 * p, c1 = 2 * p + 1;
        float w0 = lg1[c0 * NPIX + pix];
        float w1 = (c1 < 75) ? lg1[c1 * NPIX + pix] : 0.f;
        unsigned b0 = bf16bits(w0), b1 = bf16bits(w1);
        asum += fabsf(__uint_as_float(b0 << 16)) +
                fabsf(__uint_as_float(b1 << 16));
        gp[p] = b0 | (b1 << 16);
    }
    const float inv = 1.f / fmaxf(asum, 1e-12f);

    const int pbase = (ty * ROWSTRIDE + tx + 6) * PIXSTRIDE;
    __hip_bfloat16* ybase = yout + pix;

    for (int d0 = zb; d0 < dend; d0 += 8) {
        __syncthreads(); // previous chunk's readers done (no-op first iter)
        scat1(su, tid, aq0, aq2);
        __syncthreads();
        if (d0 + 8 < dend)
            stageA1(cvol, tid, h0p, w0p, d0 + 8, aq0, aq2); // overlaps compute

        v2f acc01 = {0.f, 0.f}, acc23 = {0.f, 0.f};
        v2f acc45 = {0.f, 0.f}, acc67 = {0.f, 0.f};
#pragma unroll
        for (int i = 0; i < 5; ++i) {
#pragma unroll
            for (int j = 0; j < 5; ++j) {
                const int t = i * 5 + j;
                const float* sp = su + pbase + (i * ROWSTRIDE + j) * PIXSTRIDE;
                v4f va = *(const v4f*)sp;
                v4f vb = *(const v4f*)(sp + 4);
                v2f vc = *(const v2f*)(sp + 8);
                v2f A0 = va.xy, A1 = va.zw, B0 = vb.xy, B1 = vb.zw;
                const float g0 = GW(t);
                const float g1 = GW(25 + t);
                const float g2 = GW(50 + t);
                TAP_PK(A0, A1, B0, B1, vc, g0, g1, g2);
            }
        }

        float acc[8] = {acc01.x, acc01.y, acc23.x, acc23.y,
                        acc45.x, acc45.y, acc67.x, acc67.y};
        if (d0 + 8 <= dend) {
#pragma unroll
            for (int dd = 0; dd < 8; ++dd)
                ybase[(size_t)(d0 + dd) * NPIX] =
                    __float2bfloat16(acc[dd] * inv);
        } else {
#pragma unroll
            for (int dd = 0; dd < 8; ++dd)
                if (d0 + dd < dend)
                    ybase[(size_t)(d0 + dd) * NPIX] =
                        __float2bfloat16(acc[dd] * inv);
        }
    }
}

// ---------------------------------------------------------------------------
// LGA pass 2: same pipelined structure; phase A is a pure uint4 HBM load
// (16 regs across compute); fused online softmin.
// ---------------------------------------------------------------------------
__global__ __launch_bounds__(256)
__attribute__((amdgpu_num_vgpr(128))) void lga2_kernel(
    const __hip_bfloat16* __restrict__ xin,
    const float* __restrict__ lg1,
    float* __restrict__ part) {
    const int tid = threadIdx.x;
    const int tx = tid & 15;
    const int ty = tid >> 4;
    const int w0p = blockIdx.x * 16;
    const int h0p = blockIdx.y * 16;
    const int zb = blockIdx.z * DSPLIT;
    const int dend = min(zb + DSPLIT, DOUT);
    const int pix = (h0p + ty) * WOUT + (w0p + tx);
    const unsigned short* xus = (const unsigned short*)xin;

    __shared__ __align__(16) float su[SUWORDS];

    uint4 dat[4];
    stageA2(xus, tid, h0p, w0p, zb, dat);

    float asum = 0.f;
    unsigned gp[38];
#pragma unroll
    for (int p = 0; p < 38; ++p) {
        int c0 = 2 * p, c1 = 2 * p + 1;
        float w0 = lg1[c0 * NPIX + pix];
        float w1 = (c1 < 75) ? lg1[c1 * NPIX + pix] : 0.f;
        unsigned b0 = bf16bits(w0), b1 = bf16bits(w1);
        asum += fabsf(__uint_as_float(b0 << 16)) +
                fabsf(__uint_as_float(b1 << 16));
        gp[p] = b0 | (b1 << 16);
    }
    const float inv = 1.f / fmaxf(asum, 1e-12f);

    const int pbase = (ty * ROWSTRIDE + tx + 6) * PIXSTRIDE;

    float m = -1e30f, l = 0.f, s_acc = 0.f;

    for (int d0 = zb; d0 < dend; d0 += 8) {
        __syncthreads();
        scat2(su, tid, dat);
        __syncthreads();
        if (d0 + 8 < dend)
            stageA2(xus, tid, h0p, w0p, d0 + 8, dat); // overlaps compute

        v2f acc01 = {0.f, 0.f}, acc23 = {0.f, 0.f};
        v2f acc45 = {0.f, 0.f}, acc67 = {0.f, 0.f};
#pragma unroll
        for (int i = 0; i < 5; ++i) {
#pragma unroll
            for (int j = 0; j < 5; ++j) {
                const int t = i * 5 + j;
                const float* sp = su + pbase + (i * ROWSTRIDE + j) * PIXSTRIDE;
                v4f va = *(const v4f*)sp;
                v4f vb = *(const v4f*)(sp + 4);
                v2f vc = *(const v2f*)(sp + 8);
                v2f A0 = va.xy, A1 = va.zw, B0 = vb.xy, B1 = vb.zw;
                const float g0 = GW(t);
                const float g1 = GW(25 + t);
                const float g2 = GW(50 + t);
                TAP_PK(A0, A1, B0, B1, vc, g0, g1, g2);
            }
        }

        float acc[8] = {acc01.x, acc01.y, acc23.x, acc23.y,
                        acc45.x, acc45.y, acc67.x, acc67.y};
        if (d0 + 8 <= dend) {
            float v0 = -acc[0] * inv, v1 = -acc[1] * inv;
            float v2 = -acc[2] * inv, v3 = -acc[3] * inv;
            float v4 = -acc[4] * inv, v5 = -acc[5] * inv;
            float v6 = -acc[6] * inv, v7 = -acc[7] * inv;
            float mx = fmaxf(fmaxf(fmaxf(v0, v1), fmaxf(v2, v3)),
                             fmaxf(fmaxf(v4, v5), fmaxf(v6, v7)));
            mx = fmaxf(mx, m);
            float sc = __expf(m - mx);
            float e0 = __expf(v0 - mx), e1 = __expf(v1 - mx);
            float e2 = __expf(v2 - mx), e3 = __expf(v3 - mx);
            float e4 = __expf(v4 - mx), e5 = __expf(v5 - mx);
            float e6 = __expf(v6 - mx), e7 = __expf(v7 - mx);
            l = l * sc + ((e0 + e1) + (e2 + e3)) + ((e4 + e5) + (e6 + e7));
            float fd0 = (float)d0;
            s_acc = s_acc * sc + e0 * fd0 + e1 * (fd0 + 1.f) +
                    e2 * (fd0 + 2.f) + e3 * (fd0 + 3.f) + e4 * (fd0 + 4.f) +
                    e5 * (fd0 + 5.f) + e6 * (fd0 + 6.f) + e7 * (fd0 + 7.f);
            m = mx;
        } else {
#pragma unroll
            for (int dd = 0; dd < 8; ++dd) {
                int d = d0 + dd;
                if (d < dend) {
                    float v = -acc[dd] * inv;
                    float mx = fmaxf(m, v);
                    float sc = __expf(m - mx);
                    float e = __expf(v - mx);
                    l = l * sc + e;
                    s_acc = s_acc * sc + e * (float)d;
                    m = mx;
                }
            }
        }
    }

    float* pz = part + (size_t)blockIdx.z * 3 * NPIX;
    pz[pix] = m;
    pz[NPIX + pix] = l;
    pz[2 * NPIX + pix] = s_acc;
}
#undef GW

// ---------------------------------------------------------------------------
// Kernel 4: merge NZ online-softmin partials per pixel -> disparity.
// ---------------------------------------------------------------------------
__global__ void reduce2_kernel(const float* __restrict__ part,
                               float* __restrict__ out) {
    int pix = blockIdx.x * blockDim.x + threadIdx.x;
    float M = -1e30f, L = 0.f, S = 0.f;
#pragma unroll
    for (int z = 0; z < NZ; ++z) {
        const float* pz = part + (size_t)z * 3 * NPIX;
        float m = pz[pix];
        float l = pz[NPIX + pix];
        float s = pz[2 * NPIX + pix];
        float mx = fmaxf(M, m);
        float a = __expf(M - mx);
        float b = __expf(m - mx);
        L = L * a + l * b;
        S = S * a + s * b;
        M = mx;
    }
    out[pix] = S / L;
}

// ---------------------------------------------------------------------------
extern "C" void kernel_launch(void* const* d_in, const int* in_sizes, int n_in,
                              void* d_out, int out_size, void* d_ws,
                              size_t ws_size, hipStream_t stream) {
    const float* x = (const float*)d_in[0];
    const float* lg1 = (const float*)d_in[1];
    const float* cw = (const float*)d_in[2];
    float* out = (float*)d_out;

    // ws: c fp32 [100352] | region A bf16 [NUPS] | region B bf16 [NUPS].
    // conv partials [8][NCONV] overlay region B; lga1 writes y1 to region B;
    // lga2 writes (m,l,s) partials to region A.
    float* c = (float*)d_ws;
    __hip_bfloat16* regA = (__hip_bfloat16*)((char*)d_ws + (size_t)NCONV * 4);
    __hip_bfloat16* y1 = regA + (size_t)NUPS;
    float* cpart = (float*)y1;
    float* part = (float*)regA;

    dim3 cgrid(NCONV / 1024, CGRP); // 98 x 8; each thread does 4 w-outputs
    conv3d_kernel<<<cgrid, 256, 0, stream>>>(x, cw, cpart);
    convfold_kernel<<<NCONV / 256, 256, 0, stream>>>(cpart, c);

    dim3 grid(WOUT / 16, HOUT / 16, NZ); // 32 x 16 x 2 = 1024 blocks
    lga1_kernel<<<grid, 256, 0, stream>>>(c, lg1, y1);
    lga2_kernel<<<grid, 256, 0, stream>>>(y1, lg1, part);

    reduce2_kernel<<<NPIX / 256, 256, 0, stream>>>(part, out);
}

// Round 11
// 327.087 us; speedup vs baseline: 1.2154x; 1.0429x over previous
//
#include <hip/hip_runtime.h>
#include <hip/hip_bf16.h>

#define DIN 49
#define HIN 32
#define WIN 64
#define CIN 32
#define DOUT 193
#define HOUT 256
#define WOUT 512
#define NPIX (HOUT * WOUT)      // 131072
#define NUPS (DOUT * NPIX)      // 25296896
#define NCONV (DIN * HIN * WIN) // 100352
#define DSPLIT 193
#define NZ 1 // single z-block: guidance preamble runs once; softmin completes
#define CGRP 8 // conv channel groups (4 ci each)

// LGA LDS geometry: fp32, d-contiguous per pixel (R7 measured-best layout).
#define ROWSTRIDE 33 // pixel-row stride in pixels
#define PIXSTRIDE 12 // words per pixel (10 planes + 2 pad; 48 B, 16B-aligned)
#define SUWORDS 7920

typedef __attribute__((ext_vector_type(2))) float v2f;
typedef __attribute__((ext_vector_type(4))) float v4f;

// Packed fp32 FMA (VOP3P, 3-address, register-only).
__device__ __forceinline__ v2f pk_fma(v2f a, v2f b, v2f c) {
    v2f d;
    asm("v_pk_fma_f32 %0, %1, %2, %3" : "=v"(d) : "v"(a), "v"(b), "v"(c));
    return d;
}

// ---------------------------------------------------------------------------
// Kernel 1: 3x3x3 conv, 32 -> 1 ch, zero pad 1, split 8 ways over channels.
// 4-wide w-vectorized (R10 measured win): one aligned float4 + 2 guarded
// edge scalars per (ch, kd, kh) row feeds 12 fmaf.
// ---------------------------------------------------------------------------
__global__ void conv3d_kernel(const float* __restrict__ x,
                              const float* __restrict__ w,
                              float* __restrict__ partial) {
    __shared__ float ws[4 * 27];
    const int grp = blockIdx.y;
    for (int t = threadIdx.x; t < 4 * 27; t += blockDim.x)
        ws[t] = w[grp * (4 * 27) + t];
    __syncthreads();

    int idx4 = blockIdx.x * blockDim.x + threadIdx.x; // 25088 = 98*256 exact
    int w4 = idx4 & 15;  // WIN/4 = 16
    int t2 = idx4 >> 4;
    int hq = t2 & 31;    // HIN = 32
    int dq = t2 >> 5;    // dq in [0, 49)
    int wq0 = w4 * 4;

    float acc0 = 0.f, acc1 = 0.f, acc2 = 0.f, acc3 = 0.f;
    const float* xg = x + (size_t)grp * 4 * NCONV;
#pragma unroll
    for (int cl = 0; cl < 4; ++cl) {
        const float* xb = xg + cl * NCONV;
        const float* wb = ws + cl * 27;
#pragma unroll
        for (int kd = 0; kd < 3; ++kd) {
            int zd = dq + kd - 1;
            if (zd < 0 || zd >= DIN) continue;
#pragma unroll
            for (int kh = 0; kh < 3; ++kh) {
                int zh = hq + kh - 1;
                if (zh < 0 || zh >= HIN) continue;
                const float* row = xb + (zd * HIN + zh) * WIN;
                float4 v = *(const float4*)(row + wq0);
                float xl = (wq0 > 0) ? row[wq0 - 1] : 0.f;
                float xr = (wq0 < WIN - 4) ? row[wq0 + 4] : 0.f;
                float w0 = wb[(kd * 3 + kh) * 3 + 0];
                float w1 = wb[(kd * 3 + kh) * 3 + 1];
                float w2 = wb[(kd * 3 + kh) * 3 + 2];
                acc0 = fmaf(w0, xl, acc0);
                acc0 = fmaf(w1, v.x, acc0);
                acc0 = fmaf(w2, v.y, acc0);
                acc1 = fmaf(w0, v.x, acc1);
                acc1 = fmaf(w1, v.y, acc1);
                acc1 = fmaf(w2, v.z, acc1);
                acc2 = fmaf(w0, v.y, acc2);
                acc2 = fmaf(w1, v.z, acc2);
                acc2 = fmaf(w2, v.w, acc2);
                acc3 = fmaf(w0, v.z, acc3);
                acc3 = fmaf(w1, v.w, acc3);
                acc3 = fmaf(w2, xr, acc3);
            }
        }
    }
    float4 o4 = make_float4(acc0, acc1, acc2, acc3);
    *(float4*)(partial + (size_t)grp * NCONV + (size_t)idx4 * 4) = o4;
}

// ---------------------------------------------------------------------------
// Kernel 1b: fold 8 conv partials -> c.
// ---------------------------------------------------------------------------
__global__ void convfold_kernel(const float* __restrict__ partial,
                                float* __restrict__ c) {
    int idx = blockIdx.x * blockDim.x + threadIdx.x;
    float s = 0.f;
#pragma unroll
    for (int g = 0; g < CGRP; ++g) s += partial[(size_t)g * NCONV + idx];
    c[idx] = s;
}

__device__ __forceinline__ unsigned short bf16bits(float f) {
    __hip_bfloat16 h = __float2bfloat16(f);
    unsigned short b;
    __builtin_memcpy(&b, &h, 2);
    return b;
}

// weight #idx (0..74), idx compile-time
#define GW(idx)                                                  \
    __uint_as_float(((idx) & 1) ? (gp[(idx) >> 1] & 0xFFFF0000u) \
                                : (gp[(idx) >> 1] << 16))

// Packed-pair tap body (R7 measured core): 8 pk_fma + 8 scalar fmaf.
#define TAP_PK(A0, A1, B0, B1, C0, g0, g1, g2)   \
    do {                                         \
        v2f g1b = {g1, g1};                      \
        v2f g2b = {g2, g2};                      \
        acc01 = pk_fma(g1b, A0, acc01);          \
        acc01 = pk_fma(g2b, A1, acc01);          \
        acc23 = pk_fma(g1b, A1, acc23);          \
        acc23 = pk_fma(g2b, B0, acc23);          \
        acc45 = pk_fma(g1b, B0, acc45);          \
        acc45 = pk_fma(g2b, B1, acc45);          \
        acc67 = pk_fma(g1b, B1, acc67);          \
        acc67 = pk_fma(g2b, C0, acc67);          \
        acc01.x = fmaf(g0, A0.y, acc01.x);       \
        acc01.y = fmaf(g0, A1.x, acc01.y);       \
        acc23.x = fmaf(g0, A1.y, acc23.x);       \
        acc23.y = fmaf(g0, B0.x, acc23.y);       \
        acc45.x = fmaf(g0, B0.y, acc45.x);       \
        acc45.y = fmaf(g0, B1.x, acc45.y);       \
        acc67.x = fmaf(g0, B1.y, acc67.x);       \
        acc67.y = fmaf(g0, C0.x, acc67.y);       \
    } while (0)

// ---------------------------------------------------------------------------
// lga1 staging phase A: trilinear d/h-lerp from c (L2-hot) into 6 packed
// bf16 regs per thread (R6 diet). Issued EARLY so the 12 L2 loads/job hide
// under the concurrent compute region (T14).
// ---------------------------------------------------------------------------
__device__ __forceinline__ void stageA1(const float* __restrict__ cvol,
                                        int tid, int h0p, int w0p, int dstart,
                                        unsigned (&aq0)[4], unsigned (&aq2)[2]) {
    aq2[0] = 0u;
    aq2[1] = 0u;
#pragma unroll
    for (int k = 0; k < 4; ++k) {
        const bool a = (k < 3) || (tid < 32); // NJOBS = 800
        int j = tid + k * 256;
        int seg = j & 3;
        int rowjob = j >> 2;
        int dl = rowjob / 20;
        int r = rowjob - dl * 20;
        int gh = h0p - 2 + r;
        int gwb = w0p - 8 + seg * 8;
        int gd = dstart - 1 + dl;
        if (a && gd >= 0 && gd < DOUT && gh >= 0 && gh < HOUT && gwb >= 0 &&
            (gwb + 8) <= WOUT) {
            float fd = (gd + 0.5f) * (49.0f / 193.0f) - 0.5f;
            fd = fminf(fmaxf(fd, 0.f), (float)(DIN - 1));
            int d0c = min((int)fd, DIN - 2);
            float ad = fd - (float)d0c;
            float fh = (gh + 0.5f) * 0.125f - 0.5f;
            fh = fminf(fmaxf(fh, 0.f), (float)(HIN - 1));
            int h0c = min((int)fh, HIN - 2);
            float ah = fh - (float)h0c;
            int g = gwb >> 3;
            int cm1 = max(g - 1, 0);
            int cp1 = min(g + 1, WIN - 1);
            const float* p00 = cvol + (d0c * HIN + h0c) * WIN;
            const float* p01 = p00 + WIN;
            const float* p10 = p00 + HIN * WIN;
            const float* p11 = p10 + WIN;
            float q00, q01, q10, q11, a0, a1, a2;
            q00 = p00[cm1]; q01 = p01[cm1];
            q10 = p10[cm1]; q11 = p11[cm1];
            a0 = (q00 + ah * (q01 - q00)) * (1.f - ad) +
                 (q10 + ah * (q11 - q10)) * ad;
            q00 = p00[g]; q01 = p01[g];
            q10 = p10[g]; q11 = p11[g];
            a1 = (q00 + ah * (q01 - q00)) * (1.f - ad) +
                 (q10 + ah * (q11 - q10)) * ad;
            q00 = p00[cp1]; q01 = p01[cp1];
            q10 = p10[cp1]; q11 = p11[cp1];
            a2 = (q00 + ah * (q01 - q00)) * (1.f - ad) +
                 (q10 + ah * (q11 - q10)) * ad;
            aq0[k] = (unsigned)bf16bits(a0) | ((unsigned)bf16bits(a1) << 16);
            aq2[k >> 1] |= ((unsigned)bf16bits(a2)) << ((k & 1) * 16);
        } else {
            aq0[k] = 0u;
        }
    }
}

// lga1 scatter phase B: compile-time-weight w-lerp from regs into LDS.
__device__ __forceinline__ void scat1(float* __restrict__ su, int tid,
                                      const unsigned (&aq0)[4],
                                      const unsigned (&aq2)[2]) {
#pragma unroll
    for (int k = 0; k < 4; ++k) {
        if (k < 3 || tid < 32) {
            int j = tid + k * 256;
            int seg = j & 3;
            int rowjob = j >> 2;
            int dl = rowjob / 20;
            int r = rowjob - dl * 20;
            int base = (r * ROWSTRIDE + seg * 8) * PIXSTRIDE + dl;
            float a0 = __uint_as_float(aq0[k] << 16);
            float a1 = __uint_as_float(aq0[k] & 0xFFFF0000u);
            float a2 = __uint_as_float((k & 1) ? (aq2[k >> 1] & 0xFFFF0000u)
                                               : (aq2[k >> 1] << 16));
            float d01 = a1 - a0, d12 = a2 - a1;
            su[base + 0 * PIXSTRIDE] = a0 + 0.5625f * d01;
            su[base + 1 * PIXSTRIDE] = a0 + 0.6875f * d01;
            su[base + 2 * PIXSTRIDE] = a0 + 0.8125f * d01;
            su[base + 3 * PIXSTRIDE] = a0 + 0.9375f * d01;
            su[base + 4 * PIXSTRIDE] = a1 + 0.0625f * d12;
            su[base + 5 * PIXSTRIDE] = a1 + 0.1875f * d12;
            su[base + 6 * PIXSTRIDE] = a1 + 0.3125f * d12;
            su[base + 7 * PIXSTRIDE] = a1 + 0.4375f * d12;
        }
    }
}

// lga2 staging phase A: one uint4 (8 bf16) HBM load per job into regs.
__device__ __forceinline__ void stageA2(const unsigned short* __restrict__ xus,
                                        int tid, int h0p, int w0p, int dstart,
                                        uint4 (&dat)[4]) {
#pragma unroll
    for (int k = 0; k < 4; ++k) {
        const bool a = (k < 3) || (tid < 32); // NJOBS = 800
        int j = tid + k * 256;
        int seg = j & 3;
        int rowjob = j >> 2;
        int dl = rowjob / 20;
        int r = rowjob - dl * 20;
        int gh = h0p - 2 + r;
        int gwb = w0p - 8 + seg * 8;
        int gd = dstart - 1 + dl;
        uint4 v = make_uint4(0u, 0u, 0u, 0u);
        if (a && gd >= 0 && gd < DOUT && gh >= 0 && gh < HOUT && gwb >= 0 &&
            (gwb + 8) <= WOUT)
            v = *(const uint4*)(xus + (size_t)gd * NPIX + gh * WOUT + gwb);
        dat[k] = v;
    }
}

// lga2 scatter phase B: unpack bf16 pairs from regs into LDS.
__device__ __forceinline__ void scat2(float* __restrict__ su, int tid,
                                      const uint4 (&dat)[4]) {
#pragma unroll
    for (int k = 0; k < 4; ++k) {
        if (k < 3 || tid < 32) {
            int j = tid + k * 256;
            int seg = j & 3;
            int rowjob = j >> 2;
            int dl = rowjob / 20;
            int r = rowjob - dl * 20;
            int base = (r * ROWSTRIDE + seg * 8) * PIXSTRIDE + dl;
            unsigned q;
            q = dat[k].x;
            su[base + 0 * PIXSTRIDE] = __uint_as_float(q << 16);
            su[base + 1 * PIXSTRIDE] = __uint_as_float(q & 0xFFFF0000u);
            q = dat[k].y;
            su[base + 2 * PIXSTRIDE] = __uint_as_float(q << 16);
            su[base + 3 * PIXSTRIDE] = __uint_as_float(q & 0xFFFF0000u);
            q = dat[k].z;
            su[base + 4 * PIXSTRIDE] = __uint_as_float(q << 16);
            su[base + 5 * PIXSTRIDE] = __uint_as_float(q & 0xFFFF0000u);
            q = dat[k].w;
            su[base + 6 * PIXSTRIDE] = __uint_as_float(q << 16);
            su[base + 7 * PIXSTRIDE] = __uint_as_float(q & 0xFFFF0000u);
        }
    }
}

// ---------------------------------------------------------------------------
// LGA pass 1. R7 fp32 core; phase A software-pipelined (R9). Single z-block
// (NZ=1): guidance preamble + lg1 fetch happen ONCE per pixel per pass.
// amdgpu_num_vgpr(128) pin (R6-proven).
// ---------------------------------------------------------------------------
__global__ __launch_bounds__(256)
__attribute__((amdgpu_num_vgpr(128))) void lga1_kernel(
    const float* __restrict__ cvol,
    const float* __restrict__ lg1,
    __hip_bfloat16* __restrict__ yout) {
    const int tid = threadIdx.x;
    const int tx = tid & 15;
    const int ty = tid >> 4;
    const int w0p = blockIdx.x * 16;
    const int h0p = blockIdx.y * 16;
    const int zb = 0;
    const int dend = DOUT;
    const int pix = (h0p + ty) * WOUT + (w0p + tx);

    __shared__ __align__(16) float su[SUWORDS];

    // prologue phase A (chunk 0): loads land under the guidance preamble
    unsigned aq0[4], aq2[2];
    stageA1(cvol, tid, h0p, w0p, zb, aq0, aq2);

    // ---- guidance: single pass, un-normalized, bf16 pairs (38 regs) ----
    float asum = 0.f;
    unsigned gp[38];
#pragma unroll
    for (int p = 0; p < 38; ++p) {
        int c0 = 2 * p, c1 = 2 * p + 1;
        float w0 = lg1[c0 * NPIX + pix];
        float w1 = (c1 < 75) ? lg1[c1 * NPIX + pix] : 0.f;
        unsigned b0 = bf16bits(w0), b1 = bf16bits(w1);
        asum += fabsf(__uint_as_float(b0 << 16)) +
                fabsf(__uint_as_float(b1 << 16));
        gp[p] = b0 | (b1 << 16);
    }
    const float inv = 1.f / fmaxf(asum, 1e-12f);

    const int pbase = (ty * ROWSTRIDE + tx + 6) * PIXSTRIDE;
    __hip_bfloat16* ybase = yout + pix;

    for (int d0 = zb; d0 < dend; d0 += 8) {
        __syncthreads(); // previous chunk's readers done (no-op first iter)
        scat1(su, tid, aq0, aq2);
        __syncthreads();
        if (d0 + 8 < dend)
            stageA1(cvol, tid, h0p, w0p, d0 + 8, aq0, aq2); // overlaps compute

        v2f acc01 = {0.f, 0.f}, acc23 = {0.f, 0.f};
        v2f acc45 = {0.f, 0.f}, acc67 = {0.f, 0.f};
#pragma unroll
        for (int i = 0; i < 5; ++i) {
#pragma unroll
            for (int j = 0; j < 5; ++j) {
                const int t = i * 5 + j;
                const float* sp = su + pbase + (i * ROWSTRIDE + j) * PIXSTRIDE;
                v4f va = *(const v4f*)sp;
                v4f vb = *(const v4f*)(sp + 4);
                v2f vc = *(const v2f*)(sp + 8);
                v2f A0 = va.xy, A1 = va.zw, B0 = vb.xy, B1 = vb.zw;
                const float g0 = GW(t);
                const float g1 = GW(25 + t);
                const float g2 = GW(50 + t);
                TAP_PK(A0, A1, B0, B1, vc, g0, g1, g2);
            }
        }

        float acc[8] = {acc01.x, acc01.y, acc23.x, acc23.y,
                        acc45.x, acc45.y, acc67.x, acc67.y};
        if (d0 + 8 <= dend) {
#pragma unroll
            for (int dd = 0; dd < 8; ++dd)
                ybase[(size_t)(d0 + dd) * NPIX] =
                    __float2bfloat16(acc[dd] * inv);
        } else {
#pragma unroll
            for (int dd = 0; dd < 8; ++dd)
                if (d0 + dd < dend)
                    ybase[(size_t)(d0 + dd) * NPIX] =
                        __float2bfloat16(acc[dd] * inv);
        }
    }
}

// ---------------------------------------------------------------------------
// LGA pass 2: same pipelined structure; NZ=1 so the online softmin completes
// per pixel — final S/L division fused here, reduce2 kernel eliminated.
// ---------------------------------------------------------------------------
__global__ __launch_bounds__(256)
__attribute__((amdgpu_num_vgpr(128))) void lga2_kernel(
    const __hip_bfloat16* __restrict__ xin,
    const float* __restrict__ lg1,
    float* __restrict__ out) {
    const int tid = threadIdx.x;
    const int tx = tid & 15;
    const int ty = tid >> 4;
    const int w0p = blockIdx.x * 16;
    const int h0p = blockIdx.y * 16;
    const int zb = 0;
    const int dend = DOUT;
    const int pix = (h0p + ty) * WOUT + (w0p + tx);
    const unsigned short* xus = (const unsigned short*)xin;

    __shared__ __align__(16) float su[SUWORDS];

    uint4 dat[4];
    stageA2(xus, tid, h0p, w0p, zb, dat);

    float asum = 0.f;
    unsigned gp[38];
#pragma unroll
    for (int p = 0; p < 38; ++p) {
        int c0 = 2 * p, c1 = 2 * p + 1;
        float w0 = lg1[c0 * NPIX + pix];
        float w1 = (c1 < 75) ? lg1[c1 * NPIX + pix] : 0.f;
        unsigned b0 = bf16bits(w0), b1 = bf16bits(w1);
        asum += fabsf(__uint_as_float(b0 << 16)) +
                fabsf(__uint_as_float(b1 << 16));
        gp[p] = b0 | (b1 << 16);
    }
    const float inv = 1.f / fmaxf(asum, 1e-12f);

    const int pbase = (ty * ROWSTRIDE + tx + 6) * PIXSTRIDE;

    float m = -1e30f, l = 0.f, s_acc = 0.f;

    for (int d0 = zb; d0 < dend; d0 += 8) {
        __syncthreads();
        scat2(su, tid, dat);
        __syncthreads();
        if (d0 + 8 < dend)
            stageA2(xus, tid, h0p, w0p, d0 + 8, dat); // overlaps compute

        v2f acc01 = {0.f, 0.f}, acc23 = {0.f, 0.f};
        v2f acc45 = {0.f, 0.f}, acc67 = {0.f, 0.f};
#pragma unroll
        for (int i = 0; i < 5; ++i) {
#pragma unroll
            for (int j = 0; j < 5; ++j) {
                const int t = i * 5 + j;
                const float* sp = su + pbase + (i * ROWSTRIDE + j) * PIXSTRIDE;
                v4f va = *(const v4f*)sp;
                v4f vb = *(const v4f*)(sp + 4);
                v2f vc = *(const v2f*)(sp + 8);
                v2f A0 = va.xy, A1 = va.zw, B0 = vb.xy, B1 = vb.zw;
                const float g0 = GW(t);
                const float g1 = GW(25 + t);
                const float g2 = GW(50 + t);
                TAP_PK(A0, A1, B0, B1, vc, g0, g1, g2);
            }
        }

        float acc[8] = {acc01.x, acc01.y, acc23.x, acc23.y,
                        acc45.x, acc45.y, acc67.x, acc67.y};
        if (d0 + 8 <= dend) {
            float v0 = -acc[0] * inv, v1 = -acc[1] * inv;
            float v2 = -acc[2] * inv, v3 = -acc[3] * inv;
            float v4 = -acc[4] * inv, v5 = -acc[5] * inv;
            float v6 = -acc[6] * inv, v7 = -acc[7] * inv;
            float mx = fmaxf(fmaxf(fmaxf(v0, v1), fmaxf(v2, v3)),
                             fmaxf(fmaxf(v4, v5), fmaxf(v6, v7)));
            mx = fmaxf(mx, m);
            float sc = __expf(m - mx);
            float e0 = __expf(v0 - mx), e1 = __expf(v1 - mx);
            float e2 = __expf(v2 - mx), e3 = __expf(v3 - mx);
            float e4 = __expf(v4 - mx), e5 = __expf(v5 - mx);
            float e6 = __expf(v6 - mx), e7 = __expf(v7 - mx);
            l = l * sc + ((e0 + e1) + (e2 + e3)) + ((e4 + e5) + (e6 + e7));
            float fd0 = (float)d0;
            s_acc = s_acc * sc + e0 * fd0 + e1 * (fd0 + 1.f) +
                    e2 * (fd0 + 2.f) + e3 * (fd0 + 3.f) + e4 * (fd0 + 4.f) +
                    e5 * (fd0 + 5.f) + e6 * (fd0 + 6.f) + e7 * (fd0 + 7.f);
            m = mx;
        } else {
#pragma unroll
            for (int dd = 0; dd < 8; ++dd) {
                int d = d0 + dd;
                if (d < dend) {
                    float v = -acc[dd] * inv;
                    float mx = fmaxf(m, v);
                    float sc = __expf(m - mx);
                    float e = __expf(v - mx);
                    l = l * sc + e;
                    s_acc = s_acc * sc + e * (float)d;
                    m = mx;
                }
            }
        }
    }

    out[pix] = s_acc / l;
}
#undef GW

// ---------------------------------------------------------------------------
extern "C" void kernel_launch(void* const* d_in, const int* in_sizes, int n_in,
                              void* d_out, int out_size, void* d_ws,
                              size_t ws_size, hipStream_t stream) {
    const float* x = (const float*)d_in[0];
    const float* lg1 = (const float*)d_in[1];
    const float* cw = (const float*)d_in[2];
    float* out = (float*)d_out;

    // ws: c fp32 [100352] | region A bf16 [NUPS] | region B bf16 [NUPS].
    // conv partials [8][NCONV] overlay region B; lga1 writes y1 to region B.
    float* c = (float*)d_ws;
    __hip_bfloat16* regA = (__hip_bfloat16*)((char*)d_ws + (size_t)NCONV * 4);
    __hip_bfloat16* y1 = regA + (size_t)NUPS;
    float* cpart = (float*)y1;

    dim3 cgrid(NCONV / 1024, CGRP); // 98 x 8; each thread does 4 w-outputs
    conv3d_kernel<<<cgrid, 256, 0, stream>>>(x, cw, cpart);
    convfold_kernel<<<NCONV / 256, 256, 0, stream>>>(cpart, c);

    dim3 grid(WOUT / 16, HOUT / 16, NZ); // 32 x 16 x 1 = 512 blocks
    lga1_kernel<<<grid, 256, 0, stream>>>(c, lg1, y1);
    lga2_kernel<<<grid, 256, 0, stream>>>(y1, lg1, out);
}

// Round 12
// 319.673 us; speedup vs baseline: 1.2435x; 1.0232x over previous
//
#include <hip/hip_runtime.h>
#include <hip/hip_bf16.h>

#define DIN 49
#define HIN 32
#define WIN 64
#define CIN 32
#define DOUT 193
#define HOUT 256
#define WOUT 512
#define NPIX (HOUT * WOUT)      // 131072
#define NUPS (DOUT * NPIX)      // 25296896
#define NCONV (DIN * HIN * WIN) // 100352
#define DSPLIT 193
#define NZ 1 // single z-block: guidance preamble runs once; softmin completes
#define CGRP 8 // conv channel groups (4 ci each)

// LGA LDS geometry: fp32, d-contiguous per pixel (R7 measured-best layout).
// DOUBLE-BUFFERED (2 x 31.7 KB = 63.4 KB): with NZ=1 the grid is 2 blocks/CU
// and LDS at 63.4 KB still fits 2 blocks/CU -> free in residency terms.
// Enables ONE barrier per chunk (25 vs 50 drains).
#define ROWSTRIDE 33 // pixel-row stride in pixels
#define PIXSTRIDE 12 // words per pixel (10 planes + 2 pad; 48 B, 16B-aligned)
#define SUWORDS 7920

typedef __attribute__((ext_vector_type(2))) float v2f;
typedef __attribute__((ext_vector_type(4))) float v4f;

// Packed fp32 FMA (VOP3P, 3-address, register-only).
__device__ __forceinline__ v2f pk_fma(v2f a, v2f b, v2f c) {
    v2f d;
    asm("v_pk_fma_f32 %0, %1, %2, %3" : "=v"(d) : "v"(a), "v"(b), "v"(c));
    return d;
}

// ---------------------------------------------------------------------------
// Kernel 1: 3x3x3 conv, 32 -> 1 ch, zero pad 1, split 8 ways over channels.
// 4-wide w-vectorized (R10 measured win): one aligned float4 + 2 guarded
// edge scalars per (ch, kd, kh) row feeds 12 fmaf.
// ---------------------------------------------------------------------------
__global__ void conv3d_kernel(const float* __restrict__ x,
                              const float* __restrict__ w,
                              float* __restrict__ partial) {
    __shared__ float ws[4 * 27];
    const int grp = blockIdx.y;
    for (int t = threadIdx.x; t < 4 * 27; t += blockDim.x)
        ws[t] = w[grp * (4 * 27) + t];
    __syncthreads();

    int idx4 = blockIdx.x * blockDim.x + threadIdx.x; // 25088 = 98*256 exact
    int w4 = idx4 & 15;  // WIN/4 = 16
    int t2 = idx4 >> 4;
    int hq = t2 & 31;    // HIN = 32
    int dq = t2 >> 5;    // dq in [0, 49)
    int wq0 = w4 * 4;

    float acc0 = 0.f, acc1 = 0.f, acc2 = 0.f, acc3 = 0.f;
    const float* xg = x + (size_t)grp * 4 * NCONV;
#pragma unroll
    for (int cl = 0; cl < 4; ++cl) {
        const float* xb = xg + cl * NCONV;
        const float* wb = ws + cl * 27;
#pragma unroll
        for (int kd = 0; kd < 3; ++kd) {
            int zd = dq + kd - 1;
            if (zd < 0 || zd >= DIN) continue;
#pragma unroll
            for (int kh = 0; kh < 3; ++kh) {
                int zh = hq + kh - 1;
                if (zh < 0 || zh >= HIN) continue;
                const float* row = xb + (zd * HIN + zh) * WIN;
                float4 v = *(const float4*)(row + wq0);
                float xl = (wq0 > 0) ? row[wq0 - 1] : 0.f;
                float xr = (wq0 < WIN - 4) ? row[wq0 + 4] : 0.f;
                float w0 = wb[(kd * 3 + kh) * 3 + 0];
                float w1 = wb[(kd * 3 + kh) * 3 + 1];
                float w2 = wb[(kd * 3 + kh) * 3 + 2];
                acc0 = fmaf(w0, xl, acc0);
                acc0 = fmaf(w1, v.x, acc0);
                acc0 = fmaf(w2, v.y, acc0);
                acc1 = fmaf(w0, v.x, acc1);
                acc1 = fmaf(w1, v.y, acc1);
                acc1 = fmaf(w2, v.z, acc1);
                acc2 = fmaf(w0, v.y, acc2);
                acc2 = fmaf(w1, v.z, acc2);
                acc2 = fmaf(w2, v.w, acc2);
                acc3 = fmaf(w0, v.z, acc3);
                acc3 = fmaf(w1, v.w, acc3);
                acc3 = fmaf(w2, xr, acc3);
            }
        }
    }
    float4 o4 = make_float4(acc0, acc1, acc2, acc3);
    *(float4*)(partial + (size_t)grp * NCONV + (size_t)idx4 * 4) = o4;
}

// ---------------------------------------------------------------------------
// Kernel 1b: fold 8 conv partials -> c.
// ---------------------------------------------------------------------------
__global__ void convfold_kernel(const float* __restrict__ partial,
                                float* __restrict__ c) {
    int idx = blockIdx.x * blockDim.x + threadIdx.x;
    float s = 0.f;
#pragma unroll
    for (int g = 0; g < CGRP; ++g) s += partial[(size_t)g * NCONV + idx];
    c[idx] = s;
}

__device__ __forceinline__ unsigned short bf16bits(float f) {
    __hip_bfloat16 h = __float2bfloat16(f);
    unsigned short b;
    __builtin_memcpy(&b, &h, 2);
    return b;
}

// weight #idx (0..74), idx compile-time
#define GW(idx)                                                  \
    __uint_as_float(((idx) & 1) ? (gp[(idx) >> 1] & 0xFFFF0000u) \
                                : (gp[(idx) >> 1] << 16))

// Packed-pair tap body (R7 measured core): 8 pk_fma + 8 scalar fmaf.
#define TAP_PK(A0, A1, B0, B1, C0, g0, g1, g2)   \
    do {                                         \
        v2f g1b = {g1, g1};                      \
        v2f g2b = {g2, g2};                      \
        acc01 = pk_fma(g1b, A0, acc01);          \
        acc01 = pk_fma(g2b, A1, acc01);          \
        acc23 = pk_fma(g1b, A1, acc23);          \
        acc23 = pk_fma(g2b, B0, acc23);          \
        acc45 = pk_fma(g1b, B0, acc45);          \
        acc45 = pk_fma(g2b, B1, acc45);          \
        acc67 = pk_fma(g1b, B1, acc67);          \
        acc67 = pk_fma(g2b, C0, acc67);          \
        acc01.x = fmaf(g0, A0.y, acc01.x);       \
        acc01.y = fmaf(g0, A1.x, acc01.y);       \
        acc23.x = fmaf(g0, A1.y, acc23.x);       \
        acc23.y = fmaf(g0, B0.x, acc23.y);       \
        acc45.x = fmaf(g0, B0.y, acc45.x);       \
        acc45.y = fmaf(g0, B1.x, acc45.y);       \
        acc67.x = fmaf(g0, B1.y, acc67.x);       \
        acc67.y = fmaf(g0, C0.x, acc67.y);       \
    } while (0)

// ---------------------------------------------------------------------------
// lga1 staging phase A: trilinear d/h-lerp from c (L2-hot) into 6 packed
// bf16 regs per thread (R6 diet). Issued EARLY so the 12 L2 loads/job hide
// under the concurrent compute region (T14).
// ---------------------------------------------------------------------------
__device__ __forceinline__ void stageA1(const float* __restrict__ cvol,
                                        int tid, int h0p, int w0p, int dstart,
                                        unsigned (&aq0)[4], unsigned (&aq2)[2]) {
    aq2[0] = 0u;
    aq2[1] = 0u;
#pragma unroll
    for (int k = 0; k < 4; ++k) {
        const bool a = (k < 3) || (tid < 32); // NJOBS = 800
        int j = tid + k * 256;
        int seg = j & 3;
        int rowjob = j >> 2;
        int dl = rowjob / 20;
        int r = rowjob - dl * 20;
        int gh = h0p - 2 + r;
        int gwb = w0p - 8 + seg * 8;
        int gd = dstart - 1 + dl;
        if (a && gd >= 0 && gd < DOUT && gh >= 0 && gh < HOUT && gwb >= 0 &&
            (gwb + 8) <= WOUT) {
            float fd = (gd + 0.5f) * (49.0f / 193.0f) - 0.5f;
            fd = fminf(fmaxf(fd, 0.f), (float)(DIN - 1));
            int d0c = min((int)fd, DIN - 2);
            float ad = fd - (float)d0c;
            float fh = (gh + 0.5f) * 0.125f - 0.5f;
            fh = fminf(fmaxf(fh, 0.f), (float)(HIN - 1));
            int h0c = min((int)fh, HIN - 2);
            float ah = fh - (float)h0c;
            int g = gwb >> 3;
            int cm1 = max(g - 1, 0);
            int cp1 = min(g + 1, WIN - 1);
            const float* p00 = cvol + (d0c * HIN + h0c) * WIN;
            const float* p01 = p00 + WIN;
            const float* p10 = p00 + HIN * WIN;
            const float* p11 = p10 + WIN;
            float q00, q01, q10, q11, a0, a1, a2;
            q00 = p00[cm1]; q01 = p01[cm1];
            q10 = p10[cm1]; q11 = p11[cm1];
            a0 = (q00 + ah * (q01 - q00)) * (1.f - ad) +
                 (q10 + ah * (q11 - q10)) * ad;
            q00 = p00[g]; q01 = p01[g];
            q10 = p10[g]; q11 = p11[g];
            a1 = (q00 + ah * (q01 - q00)) * (1.f - ad) +
                 (q10 + ah * (q11 - q10)) * ad;
            q00 = p00[cp1]; q01 = p01[cp1];
            q10 = p10[cp1]; q11 = p11[cp1];
            a2 = (q00 + ah * (q01 - q00)) * (1.f - ad) +
                 (q10 + ah * (q11 - q10)) * ad;
            aq0[k] = (unsigned)bf16bits(a0) | ((unsigned)bf16bits(a1) << 16);
            aq2[k >> 1] |= ((unsigned)bf16bits(a2)) << ((k & 1) * 16);
        } else {
            aq0[k] = 0u;
        }
    }
}

// lga1 scatter phase B: compile-time-weight w-lerp from regs into LDS.
__device__ __forceinline__ void scat1(float* __restrict__ su, int tid,
                                      const unsigned (&aq0)[4],
                                      const unsigned (&aq2)[2]) {
#pragma unroll
    for (int k = 0; k < 4; ++k) {
        if (k < 3 || tid < 32) {
            int j = tid + k * 256;
            int seg = j & 3;
            int rowjob = j >> 2;
            int dl = rowjob / 20;
            int r = rowjob - dl * 20;
            int base = (r * ROWSTRIDE + seg * 8) * PIXSTRIDE + dl;
            float a0 = __uint_as_float(aq0[k] << 16);
            float a1 = __uint_as_float(aq0[k] & 0xFFFF0000u);
            float a2 = __uint_as_float((k & 1) ? (aq2[k >> 1] & 0xFFFF0000u)
                                               : (aq2[k >> 1] << 16));
            float d01 = a1 - a0, d12 = a2 - a1;
            su[base + 0 * PIXSTRIDE] = a0 + 0.5625f * d01;
            su[base + 1 * PIXSTRIDE] = a0 + 0.6875f * d01;
            su[base + 2 * PIXSTRIDE] = a0 + 0.8125f * d01;
            su[base + 3 * PIXSTRIDE] = a0 + 0.9375f * d01;
            su[base + 4 * PIXSTRIDE] = a1 + 0.0625f * d12;
            su[base + 5 * PIXSTRIDE] = a1 + 0.1875f * d12;
            su[base + 6 * PIXSTRIDE] = a1 + 0.3125f * d12;
            su[base + 7 * PIXSTRIDE] = a1 + 0.4375f * d12;
        }
    }
}

// lga2 staging phase A: one uint4 (8 bf16) HBM load per job into regs.
__device__ __forceinline__ void stageA2(const unsigned short* __restrict__ xus,
                                        int tid, int h0p, int w0p, int dstart,
                                        uint4 (&dat)[4]) {
#pragma unroll
    for (int k = 0; k < 4; ++k) {
        const bool a = (k < 3) || (tid < 32); // NJOBS = 800
        int j = tid + k * 256;
        int seg = j & 3;
        int rowjob = j >> 2;
        int dl = rowjob / 20;
        int r = rowjob - dl * 20;
        int gh = h0p - 2 + r;
        int gwb = w0p - 8 + seg * 8;
        int gd = dstart - 1 + dl;
        uint4 v = make_uint4(0u, 0u, 0u, 0u);
        if (a && gd >= 0 && gd < DOUT && gh >= 0 && gh < HOUT && gwb >= 0 &&
            (gwb + 8) <= WOUT)
            v = *(const uint4*)(xus + (size_t)gd * NPIX + gh * WOUT + gwb);
        dat[k] = v;
    }
}

// lga2 scatter phase B: unpack bf16 pairs from regs into LDS.
__device__ __forceinline__ void scat2(float* __restrict__ su, int tid,
                                      const uint4 (&dat)[4]) {
#pragma unroll
    for (int k = 0; k < 4; ++k) {
        if (k < 3 || tid < 32) {
            int j = tid + k * 256;
            int seg = j & 3;
            int rowjob = j >> 2;
            int dl = rowjob / 20;
            int r = rowjob - dl * 20;
            int base = (r * ROWSTRIDE + seg * 8) * PIXSTRIDE + dl;
            unsigned q;
            q = dat[k].x;
            su[base + 0 * PIXSTRIDE] = __uint_as_float(q << 16);
            su[base + 1 * PIXSTRIDE] = __uint_as_float(q & 0xFFFF0000u);
            q = dat[k].y;
            su[base + 2 * PIXSTRIDE] = __uint_as_float(q << 16);
            su[base + 3 * PIXSTRIDE] = __uint_as_float(q & 0xFFFF0000u);
            q = dat[k].z;
            su[base + 4 * PIXSTRIDE] = __uint_as_float(q << 16);
            su[base + 5 * PIXSTRIDE] = __uint_as_float(q & 0xFFFF0000u);
            q = dat[k].w;
            su[base + 6 * PIXSTRIDE] = __uint_as_float(q << 16);
            su[base + 7 * PIXSTRIDE] = __uint_as_float(q & 0xFFFF0000u);
        }
    }
}

// ---------------------------------------------------------------------------
// LGA pass 1. fp32 double-buffered su, ONE barrier per chunk: after the
// barrier, {stageA(next) | compute(buf[pb]) | scat(next -> buf[pb^1]) |
// y-write} share one scheduling region. Race-safety: readers of buf[pb^1]
// finished last iter, fenced by this iter's barrier; writers of buf[pb]
// were last iter's scat, fenced likewise. amdgpu_num_vgpr(128) pin.
// ---------------------------------------------------------------------------
__global__ __launch_bounds__(256)
__attribute__((amdgpu_num_vgpr(128))) void lga1_kernel(
    const float* __restrict__ cvol,
    const float* __restrict__ lg1,
    __hip_bfloat16* __restrict__ yout) {
    const int tid = threadIdx.x;
    const int tx = tid & 15;
    const int ty = tid >> 4;
    const int w0p = blockIdx.x * 16;
    const int h0p = blockIdx.y * 16;
    const int zb = 0;
    const int dend = DOUT;
    const int pix = (h0p + ty) * WOUT + (w0p + tx);

    __shared__ __align__(16) float su[2 * SUWORDS];

    // prologue phase A (chunk 0): loads land under the guidance preamble
    unsigned aq0[4], aq2[2];
    stageA1(cvol, tid, h0p, w0p, zb, aq0, aq2);

    // ---- guidance: single pass, un-normalized, bf16 pairs (38 regs) ----
    float asum = 0.f;
    unsigned gp[38];
#pragma unroll
    for (int p = 0; p < 38; ++p) {
        int c0 = 2 * p, c1 = 2 * p + 1;
        float w0 = lg1[c0 * NPIX + pix];
        float w1 = (c1 < 75) ? lg1[c1 * NPIX + pix] : 0.f;
        unsigned b0 = bf16bits(w0), b1 = bf16bits(w1);
        asum += fabsf(__uint_as_float(b0 << 16)) +
                fabsf(__uint_as_float(b1 << 16));
        gp[p] = b0 | (b1 << 16);
    }
    const float inv = 1.f / fmaxf(asum, 1e-12f);

    const int pbase = (ty * ROWSTRIDE + tx + 6) * PIXSTRIDE;
    __hip_bfloat16* ybase = yout + pix;

    scat1(su, tid, aq0, aq2); // chunk 0 -> buf0
    int pb = 0;
    for (int d0 = zb; d0 < dend; d0 += 8) {
        __syncthreads(); // buf[pb] writes visible; buf[pb^1] readers done
        const bool hn = (d0 + 8 < dend);
        if (hn) stageA1(cvol, tid, h0p, w0p, d0 + 8, aq0, aq2);

        const float* sw = su + pb * SUWORDS + pbase;
        v2f acc01 = {0.f, 0.f}, acc23 = {0.f, 0.f};
        v2f acc45 = {0.f, 0.f}, acc67 = {0.f, 0.f};
#pragma unroll
        for (int i = 0; i < 5; ++i) {
#pragma unroll
            for (int j = 0; j < 5; ++j) {
                const int t = i * 5 + j;
                const float* sp = sw + (i * ROWSTRIDE + j) * PIXSTRIDE;
                v4f va = *(const v4f*)sp;
                v4f vb = *(const v4f*)(sp + 4);
                v2f vc = *(const v2f*)(sp + 8);
                v2f A0 = va.xy, A1 = va.zw, B0 = vb.xy, B1 = vb.zw;
                const float g0 = GW(t);
                const float g1 = GW(25 + t);
                const float g2 = GW(50 + t);
                TAP_PK(A0, A1, B0, B1, vc, g0, g1, g2);
            }
        }

        if (hn) scat1(su + (pb ^ 1) * SUWORDS, tid, aq0, aq2);

        float acc[8] = {acc01.x, acc01.y, acc23.x, acc23.y,
                        acc45.x, acc45.y, acc67.x, acc67.y};
        if (d0 + 8 <= dend) {
#pragma unroll
            for (int dd = 0; dd < 8; ++dd)
                ybase[(size_t)(d0 + dd) * NPIX] =
                    __float2bfloat16(acc[dd] * inv);
        } else {
#pragma unroll
            for (int dd = 0; dd < 8; ++dd)
                if (d0 + dd < dend)
                    ybase[(size_t)(d0 + dd) * NPIX] =
                        __float2bfloat16(acc[dd] * inv);
        }
        pb ^= 1;
    }
}

// ---------------------------------------------------------------------------
// LGA pass 2: same single-barrier double-buffered structure; phase A is a
// pure uint4 HBM load; online softmin completes per pixel, S/L fused.
// ---------------------------------------------------------------------------
__global__ __launch_bounds__(256)
__attribute__((amdgpu_num_vgpr(128))) void lga2_kernel(
    const __hip_bfloat16* __restrict__ xin,
    const float* __restrict__ lg1,
    float* __restrict__ out) {
    const int tid = threadIdx.x;
    const int tx = tid & 15;
    const int ty = tid >> 4;
    const int w0p = blockIdx.x * 16;
    const int h0p = blockIdx.y * 16;
    const int zb = 0;
    const int dend = DOUT;
    const int pix = (h0p + ty) * WOUT + (w0p + tx);
    const unsigned short* xus = (const unsigned short*)xin;

    __shared__ __align__(16) float su[2 * SUWORDS];

    uint4 dat[4];
    stageA2(xus, tid, h0p, w0p, zb, dat);

    float asum = 0.f;
    unsigned gp[38];
#pragma unroll
    for (int p = 0; p < 38; ++p) {
        int c0 = 2 * p, c1 = 2 * p + 1;
        float w0 = lg1[c0 * NPIX + pix];
        float w1 = (c1 < 75) ? lg1[c1 * NPIX + pix] : 0.f;
        unsigned b0 = bf16bits(w0), b1 = bf16bits(w1);
        asum += fabsf(__uint_as_float(b0 << 16)) +
                fabsf(__uint_as_float(b1 << 16));
        gp[p] = b0 | (b1 << 16);
    }
    const float inv = 1.f / fmaxf(asum, 1e-12f);

    const int pbase = (ty * ROWSTRIDE + tx + 6) * PIXSTRIDE;

    float m = -1e30f, l = 0.f, s_acc = 0.f;

    scat2(su, tid, dat); // chunk 0 -> buf0
    int pb = 0;
    for (int d0 = zb; d0 < dend; d0 += 8) {
        __syncthreads();
        const bool hn = (d0 + 8 < dend);
        if (hn) stageA2(xus, tid, h0p, w0p, d0 + 8, dat);

        const float* sw = su + pb * SUWORDS + pbase;
        v2f acc01 = {0.f, 0.f}, acc23 = {0.f, 0.f};
        v2f acc45 = {0.f, 0.f}, acc67 = {0.f, 0.f};
#pragma unroll
        for (int i = 0; i < 5; ++i) {
#pragma unroll
            for (int j = 0; j < 5; ++j) {
                const int t = i * 5 + j;
                const float* sp = sw + (i * ROWSTRIDE + j) * PIXSTRIDE;
                v4f va = *(const v4f*)sp;
                v4f vb = *(const v4f*)(sp + 4);
                v2f vc = *(const v2f*)(sp + 8);
                v2f A0 = va.xy, A1 = va.zw, B0 = vb.xy, B1 = vb.zw;
                const float g0 = GW(t);
                const float g1 = GW(25 + t);
                const float g2 = GW(50 + t);
                TAP_PK(A0, A1, B0, B1, vc, g0, g1, g2);
            }
        }

        if (hn) scat2(su + (pb ^ 1) * SUWORDS, tid, dat);

        float acc[8] = {acc01.x, acc01.y, acc23.x, acc23.y,
                        acc45.x, acc45.y, acc67.x, acc67.y};
        if (d0 + 8 <= dend) {
            float v0 = -acc[0] * inv, v1 = -acc[1] * inv;
            float v2 = -acc[2] * inv, v3 = -acc[3] * inv;
            float v4 = -acc[4] * inv, v5 = -acc[5] * inv;
            float v6 = -acc[6] * inv, v7 = -acc[7] * inv;
            float mx = fmaxf(fmaxf(fmaxf(v0, v1), fmaxf(v2, v3)),
                             fmaxf(fmaxf(v4, v5), fmaxf(v6, v7)));
            mx = fmaxf(mx, m);
            float sc = __expf(m - mx);
            float e0 = __expf(v0 - mx), e1 = __expf(v1 - mx);
            float e2 = __expf(v2 - mx), e3 = __expf(v3 - mx);
            float e4 = __expf(v4 - mx), e5 = __expf(v5 - mx);
            float e6 = __expf(v6 - mx), e7 = __expf(v7 - mx);
            l = l * sc + ((e0 + e1) + (e2 + e3)) + ((e4 + e5) + (e6 + e7));
            float fd0 = (float)d0;
            s_acc = s_acc * sc + e0 * fd0 + e1 * (fd0 + 1.f) +
                    e2 * (fd0 + 2.f) + e3 * (fd0 + 3.f) + e4 * (fd0 + 4.f) +
                    e5 * (fd0 + 5.f) + e6 * (fd0 + 6.f) + e7 * (fd0 + 7.f);
            m = mx;
        } else {
#pragma unroll
            for (int dd = 0; dd < 8; ++dd) {
                int d = d0 + dd;
                if (d < dend) {
                    float v = -acc[dd] * inv;
                    float mx = fmaxf(m, v);
                    float sc = __expf(m - mx);
                    float e = __expf(v - mx);
                    l = l * sc + e;
                    s_acc = s_acc * sc + e * (float)d;
                    m = mx;
                }
            }
        }
        pb ^= 1;
    }

    out[pix] = s_acc / l;
}
#undef GW

// ---------------------------------------------------------------------------
extern "C" void kernel_launch(void* const* d_in, const int* in_sizes, int n_in,
                              void* d_out, int out_size, void* d_ws,
                              size_t ws_size, hipStream_t stream) {
    const float* x = (const float*)d_in[0];
    const float* lg1 = (const float*)d_in[1];
    const float* cw = (const float*)d_in[2];
    float* out = (float*)d_out;

    // ws: c fp32 [100352] | region A bf16 [NUPS] | region B bf16 [NUPS].
    // conv partials [8][NCONV] overlay region B; lga1 writes y1 to region B.
    float* c = (float*)d_ws;
    __hip_bfloat16* regA = (__hip_bfloat16*)((char*)d_ws + (size_t)NCONV * 4);
    __hip_bfloat16* y1 = regA + (size_t)NUPS;
    float* cpart = (float*)y1;

    dim3 cgrid(NCONV / 1024, CGRP); // 98 x 8; each thread does 4 w-outputs
    conv3d_kernel<<<cgrid, 256, 0, stream>>>(x, cw, cpart);
    convfold_kernel<<<NCONV / 256, 256, 0, stream>>>(cpart, c);

    dim3 grid(WOUT / 16, HOUT / 16, NZ); // 32 x 16 x 1 = 512 blocks
    lga1_kernel<<<grid, 256, 0, stream>>>(c, lg1, y1);
    lga2_kernel<<<grid, 256, 0, stream>>>(y1, lg1, out);
}

// Round 13
// 297.469 us; speedup vs baseline: 1.3364x; 1.0746x over previous
//
#include <hip/hip_runtime.h>
#include <hip/hip_bf16.h>

#define DIN 49
#define HIN 32
#define WIN 64
#define CIN 32
#define DOUT 193
#define HOUT 256
#define WOUT 512
#define NPIX (HOUT * WOUT)      // 131072
#define NUPS (DOUT * NPIX)      // 25296896
#define NCONV (DIN * HIN * WIN) // 100352
#define DSPLIT 193
#define NZ 1 // single z-block: guidance preamble runs once; softmin completes
#define CGRP 8 // conv channel groups (4 ci each)

// LGA LDS geometry: bf16-PACKED, d-contiguous per pixel, consumed by
// v_dot2_f32_bf16 (no unpack — R8's fatal tax eliminated).
// PIXW = 6 words/pixel (10 planes in 5 packed words + 1 pad word; 24 B).
// Double-buffered: 2 x 15.8 KB = 31.7 KB. Reads per tap: b64+b64+b32 =
// 12 bank-clk vs fp32's 24; starts 6*(tx+ty) mod 32 tile all banks
// conflict-free. Single barrier per chunk (R12 schedule).
#define ROWSTRIDE 33 // pixel-row stride in pixels
#define PIXW 6       // words per pixel
#define SUWORDS (20 * ROWSTRIDE * PIXW) // 3960 words per buffer

typedef __attribute__((ext_vector_type(2))) float v2f;

// v_dot2_f32_bf16: d = a.lo*b.lo + a.hi*b.hi + c (packed bf16 operands).
__device__ __forceinline__ float dot2bf(unsigned a, unsigned b, float c) {
    float d;
    asm("v_dot2_f32_bf16 %0, %1, %2, %3"
        : "=v"(d)
        : "v"(a), "v"(b), "v"(c));
    return d;
}

// ---------------------------------------------------------------------------
// Kernel 1: 3x3x3 conv, 32 -> 1 ch, zero pad 1, split 8 ways over channels.
// 4-wide w-vectorized (R10 measured win).
// ---------------------------------------------------------------------------
__global__ void conv3d_kernel(const float* __restrict__ x,
                              const float* __restrict__ w,
                              float* __restrict__ partial) {
    __shared__ float ws[4 * 27];
    const int grp = blockIdx.y;
    for (int t = threadIdx.x; t < 4 * 27; t += blockDim.x)
        ws[t] = w[grp * (4 * 27) + t];
    __syncthreads();

    int idx4 = blockIdx.x * blockDim.x + threadIdx.x; // 25088 = 98*256 exact
    int w4 = idx4 & 15;  // WIN/4 = 16
    int t2 = idx4 >> 4;
    int hq = t2 & 31;    // HIN = 32
    int dq = t2 >> 5;    // dq in [0, 49)
    int wq0 = w4 * 4;

    float acc0 = 0.f, acc1 = 0.f, acc2 = 0.f, acc3 = 0.f;
    const float* xg = x + (size_t)grp * 4 * NCONV;
#pragma unroll
    for (int cl = 0; cl < 4; ++cl) {
        const float* xb = xg + cl * NCONV;
        const float* wb = ws + cl * 27;
#pragma unroll
        for (int kd = 0; kd < 3; ++kd) {
            int zd = dq + kd - 1;
            if (zd < 0 || zd >= DIN) continue;
#pragma unroll
            for (int kh = 0; kh < 3; ++kh) {
                int zh = hq + kh - 1;
                if (zh < 0 || zh >= HIN) continue;
                const float* row = xb + (zd * HIN + zh) * WIN;
                float4 v = *(const float4*)(row + wq0);
                float xl = (wq0 > 0) ? row[wq0 - 1] : 0.f;
                float xr = (wq0 < WIN - 4) ? row[wq0 + 4] : 0.f;
                float w0 = wb[(kd * 3 + kh) * 3 + 0];
                float w1 = wb[(kd * 3 + kh) * 3 + 1];
                float w2 = wb[(kd * 3 + kh) * 3 + 2];
                acc0 = fmaf(w0, xl, acc0);
                acc0 = fmaf(w1, v.x, acc0);
                acc0 = fmaf(w2, v.y, acc0);
                acc1 = fmaf(w0, v.x, acc1);
                acc1 = fmaf(w1, v.y, acc1);
                acc1 = fmaf(w2, v.z, acc1);
                acc2 = fmaf(w0, v.y, acc2);
                acc2 = fmaf(w1, v.z, acc2);
                acc2 = fmaf(w2, v.w, acc2);
                acc3 = fmaf(w0, v.z, acc3);
                acc3 = fmaf(w1, v.w, acc3);
                acc3 = fmaf(w2, xr, acc3);
            }
        }
    }
    float4 o4 = make_float4(acc0, acc1, acc2, acc3);
    *(float4*)(partial + (size_t)grp * NCONV + (size_t)idx4 * 4) = o4;
}

// ---------------------------------------------------------------------------
// Kernel 1b: fold 8 conv partials -> c.
// ---------------------------------------------------------------------------
__global__ void convfold_kernel(const float* __restrict__ partial,
                                float* __restrict__ c) {
    int idx = blockIdx.x * blockDim.x + threadIdx.x;
    float s = 0.f;
#pragma unroll
    for (int g = 0; g < CGRP; ++g) s += partial[(size_t)g * NCONV + idx];
    c[idx] = s;
}

__device__ __forceinline__ unsigned short bf16bits(float f) {
    __hip_bfloat16 h = __float2bfloat16(f);
    unsigned short b;
    __builtin_memcpy(&b, &h, 2);
    return b;
}

// Tap body: 16 dot2 + compile-time-parity weight packing (~8 int ops,
// mostly folded to v_alignbit/v_perm). gp[] holds bf16 channel pairs:
// g0 = GW(t) half (t&1), g1 = GW(25+t) half (!(t&1)), g2 = GW(50+t) half
// (t&1). Packed weight words (lo,hi): W10=(g1,g0) W2z=(g2,0) Wz1=(0,g1)
// W02=(g0,g2).
#define TAP_DOT2(sp, t)                                              \
    do {                                                             \
        uint2 wa = *(const uint2*)(sp);                              \
        uint2 wb = *(const uint2*)((sp) + 2);                        \
        unsigned wcw = (sp)[4];                                      \
        const unsigned g0w = gp[(t) >> 1];                           \
        const unsigned g1w = gp[(25 + (t)) >> 1];                    \
        const unsigned g2w = gp[(50 + (t)) >> 1];                    \
        unsigned W10, W2z, Wz1, W02;                                 \
        if ((t) & 1) {                                               \
            W10 = (g1w & 0xFFFFu) | (g0w & 0xFFFF0000u);             \
            W2z = g2w >> 16;                                         \
            Wz1 = g1w << 16;                                         \
            W02 = (g0w >> 16) | (g2w & 0xFFFF0000u);                 \
        } else {                                                     \
            W10 = (g1w >> 16) | (g0w << 16);                         \
            W2z = g2w & 0xFFFFu;                                     \
            Wz1 = g1w & 0xFFFF0000u;                                 \
            W02 = (g0w & 0xFFFFu) | (g2w << 16);                     \
        }                                                            \
        acc0 = dot2bf(wa.x, W10, acc0);                              \
        acc0 = dot2bf(wa.y, W2z, acc0);                              \
        acc1 = dot2bf(wa.x, Wz1, acc1);                              \
        acc1 = dot2bf(wa.y, W02, acc1);                              \
        acc2 = dot2bf(wa.y, W10, acc2);                              \
        acc2 = dot2bf(wb.x, W2z, acc2);                              \
        acc3 = dot2bf(wa.y, Wz1, acc3);                              \
        acc3 = dot2bf(wb.x, W02, acc3);                              \
        acc4 = dot2bf(wb.x, W10, acc4);                              \
        acc4 = dot2bf(wb.y, W2z, acc4);                              \
        acc5 = dot2bf(wb.x, Wz1, acc5);                              \
        acc5 = dot2bf(wb.y, W02, acc5);                              \
        acc6 = dot2bf(wb.y, W10, acc6);                              \
        acc6 = dot2bf(wcw, W2z, acc6);                               \
        acc7 = dot2bf(wb.y, Wz1, acc7);                              \
        acc7 = dot2bf(wcw, W02, acc7);                               \
    } while (0)

// ---------------------------------------------------------------------------
// lga1 staging phase A: trilinear d/h-lerp from c (L2-hot) into 6 packed
// bf16 regs per thread (R6 diet). Issued EARLY (T14).
// ---------------------------------------------------------------------------
__device__ __forceinline__ void stageA1(const float* __restrict__ cvol,
                                        int tid, int h0p, int w0p, int dstart,
                                        unsigned (&aq0)[4], unsigned (&aq2)[2]) {
    aq2[0] = 0u;
    aq2[1] = 0u;
#pragma unroll
    for (int k = 0; k < 4; ++k) {
        const bool a = (k < 3) || (tid < 32); // NJOBS = 800
        int j = tid + k * 256;
        int seg = j & 3;
        int rowjob = j >> 2;
        int dl = rowjob / 20;
        int r = rowjob - dl * 20;
        int gh = h0p - 2 + r;
        int gwb = w0p - 8 + seg * 8;
        int gd = dstart - 1 + dl;
        if (a && gd >= 0 && gd < DOUT && gh >= 0 && gh < HOUT && gwb >= 0 &&
            (gwb + 8) <= WOUT) {
            float fd = (gd + 0.5f) * (49.0f / 193.0f) - 0.5f;
            fd = fminf(fmaxf(fd, 0.f), (float)(DIN - 1));
            int d0c = min((int)fd, DIN - 2);
            float ad = fd - (float)d0c;
            float fh = (gh + 0.5f) * 0.125f - 0.5f;
            fh = fminf(fmaxf(fh, 0.f), (float)(HIN - 1));
            int h0c = min((int)fh, HIN - 2);
            float ah = fh - (float)h0c;
            int g = gwb >> 3;
            int cm1 = max(g - 1, 0);
            int cp1 = min(g + 1, WIN - 1);
            const float* p00 = cvol + (d0c * HIN + h0c) * WIN;
            const float* p01 = p00 + WIN;
            const float* p10 = p00 + HIN * WIN;
            const float* p11 = p10 + WIN;
            float q00, q01, q10, q11, a0, a1, a2;
            q00 = p00[cm1]; q01 = p01[cm1];
            q10 = p10[cm1]; q11 = p11[cm1];
            a0 = (q00 + ah * (q01 - q00)) * (1.f - ad) +
                 (q10 + ah * (q11 - q10)) * ad;
            q00 = p00[g]; q01 = p01[g];
            q10 = p10[g]; q11 = p11[g];
            a1 = (q00 + ah * (q01 - q00)) * (1.f - ad) +
                 (q10 + ah * (q11 - q10)) * ad;
            q00 = p00[cp1]; q01 = p01[cp1];
            q10 = p10[cp1]; q11 = p11[cp1];
            a2 = (q00 + ah * (q01 - q00)) * (1.f - ad) +
                 (q10 + ah * (q11 - q10)) * ad;
            aq0[k] = (unsigned)bf16bits(a0) | ((unsigned)bf16bits(a1) << 16);
            aq2[k >> 1] |= ((unsigned)bf16bits(a2)) << ((k & 1) * 16);
        } else {
            aq0[k] = 0u;
        }
    }
}

// lga1 scatter phase B: w-lerp from regs, bf16 half-word stores into LDS.
// Plane dl of pixel p lives at half-index p*12 + dl (12 halves = 6 words).
__device__ __forceinline__ void scat1(unsigned short* __restrict__ su16,
                                      int tid, const unsigned (&aq0)[4],
                                      const unsigned (&aq2)[2]) {
#pragma unroll
    for (int k = 0; k < 4; ++k) {
        if (k < 3 || tid < 32) {
            int j = tid + k * 256;
            int seg = j & 3;
            int rowjob = j >> 2;
            int dl = rowjob / 20;
            int r = rowjob - dl * 20;
            int hb = (r * ROWSTRIDE + seg * 8) * (2 * PIXW) + dl;
            float a0 = __uint_as_float(aq0[k] << 16);
            float a1 = __uint_as_float(aq0[k] & 0xFFFF0000u);
            float a2 = __uint_as_float((k & 1) ? (aq2[k >> 1] & 0xFFFF0000u)
                                               : (aq2[k >> 1] << 16));
            float d01 = a1 - a0, d12 = a2 - a1;
            su16[hb + 0 * 2 * PIXW] = bf16bits(a0 + 0.5625f * d01);
            su16[hb + 1 * 2 * PIXW] = bf16bits(a0 + 0.6875f * d01);
            su16[hb + 2 * 2 * PIXW] = bf16bits(a0 + 0.8125f * d01);
            su16[hb + 3 * 2 * PIXW] = bf16bits(a0 + 0.9375f * d01);
            su16[hb + 4 * 2 * PIXW] = bf16bits(a1 + 0.0625f * d12);
            su16[hb + 5 * 2 * PIXW] = bf16bits(a1 + 0.1875f * d12);
            su16[hb + 6 * 2 * PIXW] = bf16bits(a1 + 0.3125f * d12);
            su16[hb + 7 * 2 * PIXW] = bf16bits(a1 + 0.4375f * d12);
        }
    }
}

// lga2 staging phase A: one uint4 (8 bf16) HBM load per job into regs.
__device__ __forceinline__ void stageA2(const unsigned short* __restrict__ xus,
                                        int tid, int h0p, int w0p, int dstart,
                                        uint4 (&dat)[4]) {
#pragma unroll
    for (int k = 0; k < 4; ++k) {
        const bool a = (k < 3) || (tid < 32); // NJOBS = 800
        int j = tid + k * 256;
        int seg = j & 3;
        int rowjob = j >> 2;
        int dl = rowjob / 20;
        int r = rowjob - dl * 20;
        int gh = h0p - 2 + r;
        int gwb = w0p - 8 + seg * 8;
        int gd = dstart - 1 + dl;
        uint4 v = make_uint4(0u, 0u, 0u, 0u);
        if (a && gd >= 0 && gd < DOUT && gh >= 0 && gh < HOUT && gwb >= 0 &&
            (gwb + 8) <= WOUT)
            v = *(const uint4*)(xus + (size_t)gd * NPIX + gh * WOUT + gwb);
        dat[k] = v;
    }
}

// lga2 scatter phase B: bf16 half-word stores straight from packed regs
// (hi halves pattern-match to ds_write_b16_d16_hi — zero unpack VALU).
__device__ __forceinline__ void scat2(unsigned short* __restrict__ su16,
                                      int tid, const uint4 (&dat)[4]) {
#pragma unroll
    for (int k = 0; k < 4; ++k) {
        if (k < 3 || tid < 32) {
            int j = tid + k * 256;
            int seg = j & 3;
            int rowjob = j >> 2;
            int dl = rowjob / 20;
            int r = rowjob - dl * 20;
            int hb = (r * ROWSTRIDE + seg * 8) * (2 * PIXW) + dl;
            su16[hb + 0 * 2 * PIXW] = (unsigned short)(dat[k].x);
            su16[hb + 1 * 2 * PIXW] = (unsigned short)(dat[k].x >> 16);
            su16[hb + 2 * 2 * PIXW] = (unsigned short)(dat[k].y);
            su16[hb + 3 * 2 * PIXW] = (unsigned short)(dat[k].y >> 16);
            su16[hb + 4 * 2 * PIXW] = (unsigned short)(dat[k].z);
            su16[hb + 5 * 2 * PIXW] = (unsigned short)(dat[k].z >> 16);
            su16[hb + 6 * 2 * PIXW] = (unsigned short)(dat[k].w);
            su16[hb + 7 * 2 * PIXW] = (unsigned short)(dat[k].w >> 16);
        }
    }
}

// ---------------------------------------------------------------------------
// LGA pass 1. bf16-packed double-buffered su + dot2 taps; single barrier
// per chunk (R12 schedule). amdgpu_num_vgpr(128) pin.
// ---------------------------------------------------------------------------
__global__ __launch_bounds__(256)
__attribute__((amdgpu_num_vgpr(128))) void lga1_kernel(
    const float* __restrict__ cvol,
    const float* __restrict__ lg1,
    __hip_bfloat16* __restrict__ yout) {
    const int tid = threadIdx.x;
    const int tx = tid & 15;
    const int ty = tid >> 4;
    const int w0p = blockIdx.x * 16;
    const int h0p = blockIdx.y * 16;
    const int zb = 0;
    const int dend = DOUT;
    const int pix = (h0p + ty) * WOUT + (w0p + tx);

    __shared__ __align__(16) unsigned su[2 * SUWORDS];

    // prologue phase A (chunk 0): loads land under the guidance preamble
    unsigned aq0[4], aq2[2];
    stageA1(cvol, tid, h0p, w0p, zb, aq0, aq2);

    // ---- guidance: single pass, un-normalized, bf16 pairs (38 regs) ----
    float asum = 0.f;
    unsigned gp[38];
#pragma unroll
    for (int p = 0; p < 38; ++p) {
        int c0 = 2 * p, c1 = 2 * p + 1;
        float w0 = lg1[c0 * NPIX + pix];
        float w1 = (c1 < 75) ? lg1[c1 * NPIX + pix] : 0.f;
        unsigned b0 = bf16bits(w0), b1 = bf16bits(w1);
        asum += fabsf(__uint_as_float(b0 << 16)) +
                fabsf(__uint_as_float(b1 << 16));
        gp[p] = b0 | (b1 << 16);
    }
    const float inv = 1.f / fmaxf(asum, 1e-12f);

    const int pbase = (ty * ROWSTRIDE + tx + 6) * PIXW;
    __hip_bfloat16* ybase = yout + pix;

    scat1((unsigned short*)su, tid, aq0, aq2); // chunk 0 -> buf0
    int pb = 0;
    for (int d0 = zb; d0 < dend; d0 += 8) {
        __syncthreads(); // buf[pb] writes visible; buf[pb^1] readers done
        const bool hn = (d0 + 8 < dend);
        if (hn) stageA1(cvol, tid, h0p, w0p, d0 + 8, aq0, aq2);

        const unsigned* sw = su + pb * SUWORDS + pbase;
        float acc0 = 0.f, acc1 = 0.f, acc2 = 0.f, acc3 = 0.f;
        float acc4 = 0.f, acc5 = 0.f, acc6 = 0.f, acc7 = 0.f;
#pragma unroll
        for (int i = 0; i < 5; ++i) {
#pragma unroll
            for (int j = 0; j < 5; ++j) {
                const int t = i * 5 + j;
                TAP_DOT2(sw + (i * ROWSTRIDE + j) * PIXW, t);
            }
        }

        if (hn) scat1((unsigned short*)(su + (pb ^ 1) * SUWORDS), tid, aq0, aq2);

        float acc[8] = {acc0, acc1, acc2, acc3, acc4, acc5, acc6, acc7};
        if (d0 + 8 <= dend) {
#pragma unroll
            for (int dd = 0; dd < 8; ++dd)
                ybase[(size_t)(d0 + dd) * NPIX] =
                    __float2bfloat16(acc[dd] * inv);
        } else {
#pragma unroll
            for (int dd = 0; dd < 8; ++dd)
                if (d0 + dd < dend)
                    ybase[(size_t)(d0 + dd) * NPIX] =
                        __float2bfloat16(acc[dd] * inv);
        }
        pb ^= 1;
    }
}

// ---------------------------------------------------------------------------
// LGA pass 2: same structure; phase A is a pure uint4 HBM load; online
// softmin completes per pixel, S/L fused.
// ---------------------------------------------------------------------------
__global__ __launch_bounds__(256)
__attribute__((amdgpu_num_vgpr(128))) void lga2_kernel(
    const __hip_bfloat16* __restrict__ xin,
    const float* __restrict__ lg1,
    float* __restrict__ out) {
    const int tid = threadIdx.x;
    const int tx = tid & 15;
    const int ty = tid >> 4;
    const int w0p = blockIdx.x * 16;
    const int h0p = blockIdx.y * 16;
    const int zb = 0;
    const int dend = DOUT;
    const int pix = (h0p + ty) * WOUT + (w0p + tx);
    const unsigned short* xus = (const unsigned short*)xin;

    __shared__ __align__(16) unsigned su[2 * SUWORDS];

    uint4 dat[4];
    stageA2(xus, tid, h0p, w0p, zb, dat);

    float asum = 0.f;
    unsigned gp[38];
#pragma unroll
    for (int p = 0; p < 38; ++p) {
        int c0 = 2 * p, c1 = 2 * p + 1;
        float w0 = lg1[c0 * NPIX + pix];
        float w1 = (c1 < 75) ? lg1[c1 * NPIX + pix] : 0.f;
        unsigned b0 = bf16bits(w0), b1 = bf16bits(w1);
        asum += fabsf(__uint_as_float(b0 << 16)) +
                fabsf(__uint_as_float(b1 << 16));
        gp[p] = b0 | (b1 << 16);
    }
    const float inv = 1.f / fmaxf(asum, 1e-12f);

    const int pbase = (ty * ROWSTRIDE + tx + 6) * PIXW;

    float m = -1e30f, l = 0.f, s_acc = 0.f;

    scat2((unsigned short*)su, tid, dat); // chunk 0 -> buf0
    int pb = 0;
    for (int d0 = zb; d0 < dend; d0 += 8) {
        __syncthreads();
        const bool hn = (d0 + 8 < dend);
        if (hn) stageA2(xus, tid, h0p, w0p, d0 + 8, dat);

        const unsigned* sw = su + pb * SUWORDS + pbase;
        float acc0 = 0.f, acc1 = 0.f, acc2 = 0.f, acc3 = 0.f;
        float acc4 = 0.f, acc5 = 0.f, acc6 = 0.f, acc7 = 0.f;
#pragma unroll
        for (int i = 0; i < 5; ++i) {
#pragma unroll
            for (int j = 0; j < 5; ++j) {
                const int t = i * 5 + j;
                TAP_DOT2(sw + (i * ROWSTRIDE + j) * PIXW, t);
            }
        }

        if (hn) scat2((unsigned short*)(su + (pb ^ 1) * SUWORDS), tid, dat);

        float acc[8] = {acc0, acc1, acc2, acc3, acc4, acc5, acc6, acc7};
        if (d0 + 8 <= dend) {
            float v0 = -acc[0] * inv, v1 = -acc[1] * inv;
            float v2 = -acc[2] * inv, v3 = -acc[3] * inv;
            float v4 = -acc[4] * inv, v5 = -acc[5] * inv;
            float v6 = -acc[6] * inv, v7 = -acc[7] * inv;
            float mx = fmaxf(fmaxf(fmaxf(v0, v1), fmaxf(v2, v3)),
                             fmaxf(fmaxf(v4, v5), fmaxf(v6, v7)));
            mx = fmaxf(mx, m);
            float sc = __expf(m - mx);
            float e0 = __expf(v0 - mx), e1 = __expf(v1 - mx);
            float e2 = __expf(v2 - mx), e3 = __expf(v3 - mx);
            float e4 = __expf(v4 - mx), e5 = __expf(v5 - mx);
            float e6 = __expf(v6 - mx), e7 = __expf(v7 - mx);
            l = l * sc + ((e0 + e1) + (e2 + e3)) + ((e4 + e5) + (e6 + e7));
            float fd0 = (float)d0;
            s_acc = s_acc * sc + e0 * fd0 + e1 * (fd0 + 1.f) +
                    e2 * (fd0 + 2.f) + e3 * (fd0 + 3.f) + e4 * (fd0 + 4.f) +
                    e5 * (fd0 + 5.f) + e6 * (fd0 + 6.f) + e7 * (fd0 + 7.f);
            m = mx;
        } else {
#pragma unroll
            for (int dd = 0; dd < 8; ++dd) {
                int d = d0 + dd;
                if (d < dend) {
                    float v = -acc[dd] * inv;
                    float mx = fmaxf(m, v);
                    float sc = __expf(m - mx);
                    float e = __expf(v - mx);
                    l = l * sc + e;
                    s_acc = s_acc * sc + e * (float)d;
                    m = mx;
                }
            }
        }
        pb ^= 1;
    }

    out[pix] = s_acc / l;
}

// ---------------------------------------------------------------------------
extern "C" void kernel_launch(void* const* d_in, const int* in_sizes, int n_in,
                              void* d_out, int out_size, void* d_ws,
                              size_t ws_size, hipStream_t stream) {
    const float* x = (const float*)d_in[0];
    const float* lg1 = (const float*)d_in[1];
    const float* cw = (const float*)d_in[2];
    float* out = (float*)d_out;

    // ws: c fp32 [100352] | region A bf16 [NUPS] | region B bf16 [NUPS].
    // conv partials [8][NCONV] overlay region B; lga1 writes y1 to region B.
    float* c = (float*)d_ws;
    __hip_bfloat16* regA = (__hip_bfloat16*)((char*)d_ws + (size_t)NCONV * 4);
    __hip_bfloat16* y1 = regA + (size_t)NUPS;
    float* cpart = (float*)y1;

    dim3 cgrid(NCONV / 1024, CGRP); // 98 x 8; each thread does 4 w-outputs
    conv3d_kernel<<<cgrid, 256, 0, stream>>>(x, cw, cpart);
    convfold_kernel<<<NCONV / 256, 256, 0, stream>>>(cpart, c);

    dim3 grid(WOUT / 16, HOUT / 16, NZ); // 32 x 16 x 1 = 512 blocks
    lga1_kernel<<<grid, 256, 0, stream>>>(c, lg1, y1);
    lga2_kernel<<<grid, 256, 0, stream>>>(y1, lg1, out);
}

// Round 14
// 297.287 us; speedup vs baseline: 1.3372x; 1.0006x over previous
//
#include <hip/hip_runtime.h>
#include <hip/hip_bf16.h>

#define DIN 49
#define HIN 32
#define WIN 64
#define CIN 32
#define DOUT 193
#define HOUT 256
#define WOUT 512
#define NPIX (HOUT * WOUT)      // 131072
#define NUPS (DOUT * NPIX)      // 25296896
#define NCONV (DIN * HIN * WIN) // 100352
#define NZ 1
#define CGRP 8 // conv channel groups (4 ci each)

// LGA LDS geometry: bf16-packed, d-contiguous per pixel, dot2-consumed
// (R13 measured win). CHUNK=16: 18 halo planes -> PIXW=10 words/pixel
// (18 halves + 2 pad; word base even => b64-aligned). Double-buffered:
// 2 x 25.8 KB = 51.6 KB (>=2 blocks/CU preserved). Barriers 25 -> 13;
// per-tap weight packing amortized over 2x outputs.
#define ROWSTRIDE 33 // pixel-row stride in pixels
#define PIXW 10      // words per pixel
#define SUWORDS (20 * ROWSTRIDE * PIXW) // 6600 words per buffer
#define CHUNK 16
#define NPL 18   // CHUNK + 2 halo planes
// staging jobs: 20 rows x 4 segs x 18 planes = 1440; k<6 with tail 160
#define JGUARD(k, tid) ((k) < 5 || (tid) < 160)

typedef __attribute__((ext_vector_type(2))) float v2f;

// v_dot2_f32_bf16: d = a.lo*b.lo + a.hi*b.hi + c (packed bf16 operands).
__device__ __forceinline__ float dot2bf(unsigned a, unsigned b, float c) {
    float d;
    asm("v_dot2_f32_bf16 %0, %1, %2, %3"
        : "=v"(d)
        : "v"(a), "v"(b), "v"(c));
    return d;
}

// ---------------------------------------------------------------------------
// Kernel 1: 3x3x3 conv, 32 -> 1 ch, zero pad 1, split 8 ways over channels.
// 4-wide w-vectorized (R10 measured win).
// ---------------------------------------------------------------------------
__global__ void conv3d_kernel(const float* __restrict__ x,
                              const float* __restrict__ w,
                              float* __restrict__ partial) {
    __shared__ float ws[4 * 27];
    const int grp = blockIdx.y;
    for (int t = threadIdx.x; t < 4 * 27; t += blockDim.x)
        ws[t] = w[grp * (4 * 27) + t];
    __syncthreads();

    int idx4 = blockIdx.x * blockDim.x + threadIdx.x; // 25088 = 98*256 exact
    int w4 = idx4 & 15;  // WIN/4 = 16
    int t2 = idx4 >> 4;
    int hq = t2 & 31;    // HIN = 32
    int dq = t2 >> 5;    // dq in [0, 49)
    int wq0 = w4 * 4;

    float acc0 = 0.f, acc1 = 0.f, acc2 = 0.f, acc3 = 0.f;
    const float* xg = x + (size_t)grp * 4 * NCONV;
#pragma unroll
    for (int cl = 0; cl < 4; ++cl) {
        const float* xb = xg + cl * NCONV;
        const float* wb = ws + cl * 27;
#pragma unroll
        for (int kd = 0; kd < 3; ++kd) {
            int zd = dq + kd - 1;
            if (zd < 0 || zd >= DIN) continue;
#pragma unroll
            for (int kh = 0; kh < 3; ++kh) {
                int zh = hq + kh - 1;
                if (zh < 0 || zh >= HIN) continue;
                const float* row = xb + (zd * HIN + zh) * WIN;
                float4 v = *(const float4*)(row + wq0);
                float xl = (wq0 > 0) ? row[wq0 - 1] : 0.f;
                float xr = (wq0 < WIN - 4) ? row[wq0 + 4] : 0.f;
                float w0 = wb[(kd * 3 + kh) * 3 + 0];
                float w1 = wb[(kd * 3 + kh) * 3 + 1];
                float w2 = wb[(kd * 3 + kh) * 3 + 2];
                acc0 = fmaf(w0, xl, acc0);
                acc0 = fmaf(w1, v.x, acc0);
                acc0 = fmaf(w2, v.y, acc0);
                acc1 = fmaf(w0, v.x, acc1);
                acc1 = fmaf(w1, v.y, acc1);
                acc1 = fmaf(w2, v.z, acc1);
                acc2 = fmaf(w0, v.y, acc2);
                acc2 = fmaf(w1, v.z, acc2);
                acc2 = fmaf(w2, v.w, acc2);
                acc3 = fmaf(w0, v.z, acc3);
                acc3 = fmaf(w1, v.w, acc3);
                acc3 = fmaf(w2, xr, acc3);
            }
        }
    }
    float4 o4 = make_float4(acc0, acc1, acc2, acc3);
    *(float4*)(partial + (size_t)grp * NCONV + (size_t)idx4 * 4) = o4;
}

// ---------------------------------------------------------------------------
// Kernel 1b: fold 8 conv partials -> c.
// ---------------------------------------------------------------------------
__global__ void convfold_kernel(const float* __restrict__ partial,
                                float* __restrict__ c) {
    int idx = blockIdx.x * blockDim.x + threadIdx.x;
    float s = 0.f;
#pragma unroll
    for (int g = 0; g < CGRP; ++g) s += partial[(size_t)g * NCONV + idx];
    c[idx] = s;
}

__device__ __forceinline__ unsigned short bf16bits(float f) {
    __hip_bfloat16 h = __float2bfloat16(f);
    unsigned short b;
    __builtin_memcpy(&b, &h, 2);
    return b;
}

// Tap body for CHUNK=16: 9 LDS words (4x b64 + b32), 32 dot2, one set of
// packed weight words per tap (amortized over 16 outputs). gp[] holds bf16
// channel pairs; parity of t selects halves at compile time.
#define TAP16(sp, t)                                                 \
    do {                                                             \
        unsigned u0, u1, u2, u3, u4, u5, u6, u7, u8;                 \
        { uint2 q = *(const uint2*)(sp);       u0 = q.x; u1 = q.y; } \
        { uint2 q = *(const uint2*)((sp) + 2); u2 = q.x; u3 = q.y; } \
        { uint2 q = *(const uint2*)((sp) + 4); u4 = q.x; u5 = q.y; } \
        { uint2 q = *(const uint2*)((sp) + 6); u6 = q.x; u7 = q.y; } \
        u8 = (sp)[8];                                                \
        const unsigned g0w = gp[(t) >> 1];                           \
        const unsigned g1w = gp[(25 + (t)) >> 1];                    \
        const unsigned g2w = gp[(50 + (t)) >> 1];                    \
        unsigned W10, W2z, Wz1, W02;                                 \
        if ((t) & 1) {                                               \
            W10 = (g1w & 0xFFFFu) | (g0w & 0xFFFF0000u);             \
            W2z = g2w >> 16;                                         \
            Wz1 = g1w << 16;                                         \
            W02 = (g0w >> 16) | (g2w & 0xFFFF0000u);                 \
        } else {                                                     \
            W10 = (g1w >> 16) | (g0w << 16);                         \
            W2z = g2w & 0xFFFFu;                                     \
            Wz1 = g1w & 0xFFFF0000u;                                 \
            W02 = (g0w & 0xFFFFu) | (g2w << 16);                     \
        }                                                            \
        acc[0] = dot2bf(u0, W10, acc[0]);                            \
        acc[0] = dot2bf(u1, W2z, acc[0]);                            \
        acc[1] = dot2bf(u0, Wz1, acc[1]);                            \
        acc[1] = dot2bf(u1, W02, acc[1]);                            \
        acc[2] = dot2bf(u1, W10, acc[2]);                            \
        acc[2] = dot2bf(u2, W2z, acc[2]);                            \
        acc[3] = dot2bf(u1, Wz1, acc[3]);                            \
        acc[3] = dot2bf(u2, W02, acc[3]);                            \
        acc[4] = dot2bf(u2, W10, acc[4]);                            \
        acc[4] = dot2bf(u3, W2z, acc[4]);                            \
        acc[5] = dot2bf(u2, Wz1, acc[5]);                            \
        acc[5] = dot2bf(u3, W02, acc[5]);                            \
        acc[6] = dot2bf(u3, W10, acc[6]);                            \
        acc[6] = dot2bf(u4, W2z, acc[6]);                            \
        acc[7] = dot2bf(u3, Wz1, acc[7]);                            \
        acc[7] = dot2bf(u4, W02, acc[7]);                            \
        acc[8] = dot2bf(u4, W10, acc[8]);                            \
        acc[8] = dot2bf(u5, W2z, acc[8]);                            \
        acc[9] = dot2bf(u4, Wz1, acc[9]);                            \
        acc[9] = dot2bf(u5, W02, acc[9]);                            \
        acc[10] = dot2bf(u5, W10, acc[10]);                          \
        acc[10] = dot2bf(u6, W2z, acc[10]);                          \
        acc[11] = dot2bf(u5, Wz1, acc[11]);                          \
        acc[11] = dot2bf(u6, W02, acc[11]);                          \
        acc[12] = dot2bf(u6, W10, acc[12]);                          \
        acc[12] = dot2bf(u7, W2z, acc[12]);                          \
        acc[13] = dot2bf(u6, Wz1, acc[13]);                          \
        acc[13] = dot2bf(u7, W02, acc[13]);                          \
        acc[14] = dot2bf(u7, W10, acc[14]);                          \
        acc[14] = dot2bf(u8, W2z, acc[14]);                          \
        acc[15] = dot2bf(u7, Wz1, acc[15]);                          \
        acc[15] = dot2bf(u8, W02, acc[15]);                          \
    } while (0)

// job decode (1440 jobs): seg in [0,4), dl in [0,18), r in [0,20)
__device__ __forceinline__ void jdec(int j, int& seg, int& dl, int& r) {
    seg = j & 3;
    int rowjob = j >> 2; // [0, 360)
    dl = rowjob / 20;
    r = rowjob - dl * 20;
}

// ---------------------------------------------------------------------------
// lga1 staging phase A: trilinear d/h-lerp from c (L2-hot) into packed
// bf16 regs (9 regs for 6 jobs). Issued EARLY (T14).
// ---------------------------------------------------------------------------
__device__ __forceinline__ void stageA1(const float* __restrict__ cvol,
                                        int tid, int h0p, int w0p, int dstart,
                                        unsigned (&aq0)[6], unsigned (&aq2)[3]) {
    aq2[0] = 0u;
    aq2[1] = 0u;
    aq2[2] = 0u;
#pragma unroll
    for (int k = 0; k < 6; ++k) {
        const bool a = JGUARD(k, tid);
        int j = tid + k * 256;
        int seg, dl, r;
        jdec(j, seg, dl, r);
        int gh = h0p - 2 + r;
        int gwb = w0p - 8 + seg * 8;
        int gd = dstart - 1 + dl;
        if (a && gd >= 0 && gd < DOUT && gh >= 0 && gh < HOUT && gwb >= 0 &&
            (gwb + 8) <= WOUT) {
            float fd = (gd + 0.5f) * (49.0f / 193.0f) - 0.5f;
            fd = fminf(fmaxf(fd, 0.f), (float)(DIN - 1));
            int d0c = min((int)fd, DIN - 2);
            float ad = fd - (float)d0c;
            float fh = (gh + 0.5f) * 0.125f - 0.5f;
            fh = fminf(fmaxf(fh, 0.f), (float)(HIN - 1));
            int h0c = min((int)fh, HIN - 2);
            float ah = fh - (float)h0c;
            int g = gwb >> 3;
            int cm1 = max(g - 1, 0);
            int cp1 = min(g + 1, WIN - 1);
            const float* p00 = cvol + (d0c * HIN + h0c) * WIN;
            const float* p01 = p00 + WIN;
            const float* p10 = p00 + HIN * WIN;
            const float* p11 = p10 + WIN;
            float q00, q01, q10, q11, a0, a1, a2;
            q00 = p00[cm1]; q01 = p01[cm1];
            q10 = p10[cm1]; q11 = p11[cm1];
            a0 = (q00 + ah * (q01 - q00)) * (1.f - ad) +
                 (q10 + ah * (q11 - q10)) * ad;
            q00 = p00[g]; q01 = p01[g];
            q10 = p10[g]; q11 = p11[g];
            a1 = (q00 + ah * (q01 - q00)) * (1.f - ad) +
                 (q10 + ah * (q11 - q10)) * ad;
            q00 = p00[cp1]; q01 = p01[cp1];
            q10 = p10[cp1]; q11 = p11[cp1];
            a2 = (q00 + ah * (q01 - q00)) * (1.f - ad) +
                 (q10 + ah * (q11 - q10)) * ad;
            aq0[k] = (unsigned)bf16bits(a0) | ((unsigned)bf16bits(a1) << 16);
            aq2[k >> 1] |= ((unsigned)bf16bits(a2)) << ((k & 1) * 16);
        } else {
            aq0[k] = 0u;
        }
    }
}

// lga1 scatter phase B: w-lerp from regs, bf16 half-word stores into LDS.
// Plane dl of pixel p lives at half-index p*2*PIXW + dl.
__device__ __forceinline__ void scat1(unsigned short* __restrict__ su16,
                                      int tid, const unsigned (&aq0)[6],
                                      const unsigned (&aq2)[3]) {
#pragma unroll
    for (int k = 0; k < 6; ++k) {
        if (JGUARD(k, tid)) {
            int j = tid + k * 256;
            int seg, dl, r;
            jdec(j, seg, dl, r);
            int hb = (r * ROWSTRIDE + seg * 8) * (2 * PIXW) + dl;
            float a0 = __uint_as_float(aq0[k] << 16);
            float a1 = __uint_as_float(aq0[k] & 0xFFFF0000u);
            float a2 = __uint_as_float((k & 1) ? (aq2[k >> 1] & 0xFFFF0000u)
                                               : (aq2[k >> 1] << 16));
            float d01 = a1 - a0, d12 = a2 - a1;
            su16[hb + 0 * 2 * PIXW] = bf16bits(a0 + 0.5625f * d01);
            su16[hb + 1 * 2 * PIXW] = bf16bits(a0 + 0.6875f * d01);
            su16[hb + 2 * 2 * PIXW] = bf16bits(a0 + 0.8125f * d01);
            su16[hb + 3 * 2 * PIXW] = bf16bits(a0 + 0.9375f * d01);
            su16[hb + 4 * 2 * PIXW] = bf16bits(a1 + 0.0625f * d12);
            su16[hb + 5 * 2 * PIXW] = bf16bits(a1 + 0.1875f * d12);
            su16[hb + 6 * 2 * PIXW] = bf16bits(a1 + 0.3125f * d12);
            su16[hb + 7 * 2 * PIXW] = bf16bits(a1 + 0.4375f * d12);
        }
    }
}

// lga2 staging phase A: one uint4 (8 bf16) HBM load per job into regs.
__device__ __forceinline__ void stageA2(const unsigned short* __restrict__ xus,
                                        int tid, int h0p, int w0p, int dstart,
                                        uint4 (&dat)[6]) {
#pragma unroll
    for (int k = 0; k < 6; ++k) {
        const bool a = JGUARD(k, tid);
        int j = tid + k * 256;
        int seg, dl, r;
        jdec(j, seg, dl, r);
        int gh = h0p - 2 + r;
        int gwb = w0p - 8 + seg * 8;
        int gd = dstart - 1 + dl;
        uint4 v = make_uint4(0u, 0u, 0u, 0u);
        if (a && gd >= 0 && gd < DOUT && gh >= 0 && gh < HOUT && gwb >= 0 &&
            (gwb + 8) <= WOUT)
            v = *(const uint4*)(xus + (size_t)gd * NPIX + gh * WOUT + gwb);
        dat[k] = v;
    }
}

// lga2 scatter phase B: bf16 half-word stores straight from packed regs.
__device__ __forceinline__ void scat2(unsigned short* __restrict__ su16,
                                      int tid, const uint4 (&dat)[6]) {
#pragma unroll
    for (int k = 0; k < 6; ++k) {
        if (JGUARD(k, tid)) {
            int j = tid + k * 256;
            int seg, dl, r;
            jdec(j, seg, dl, r);
            int hb = (r * ROWSTRIDE + seg * 8) * (2 * PIXW) + dl;
            su16[hb + 0 * 2 * PIXW] = (unsigned short)(dat[k].x);
            su16[hb + 1 * 2 * PIXW] = (unsigned short)(dat[k].x >> 16);
            su16[hb + 2 * 2 * PIXW] = (unsigned short)(dat[k].y);
            su16[hb + 3 * 2 * PIXW] = (unsigned short)(dat[k].y >> 16);
            su16[hb + 4 * 2 * PIXW] = (unsigned short)(dat[k].z);
            su16[hb + 5 * 2 * PIXW] = (unsigned short)(dat[k].z >> 16);
            su16[hb + 6 * 2 * PIXW] = (unsigned short)(dat[k].w);
            su16[hb + 7 * 2 * PIXW] = (unsigned short)(dat[k].w >> 16);
        }
    }
}

// ---------------------------------------------------------------------------
// LGA pass 1. bf16 double-buffered su + dot2 taps, CHUNK=16 (13 barriers).
// amdgpu_num_vgpr(128) pin.
// ---------------------------------------------------------------------------
__global__ __launch_bounds__(256)
__attribute__((amdgpu_num_vgpr(128))) void lga1_kernel(
    const float* __restrict__ cvol,
    const float* __restrict__ lg1,
    __hip_bfloat16* __restrict__ yout) {
    const int tid = threadIdx.x;
    const int tx = tid & 15;
    const int ty = tid >> 4;
    const int w0p = blockIdx.x * 16;
    const int h0p = blockIdx.y * 16;
    const int dend = DOUT;
    const int pix = (h0p + ty) * WOUT + (w0p + tx);

    __shared__ __align__(16) unsigned su[2 * SUWORDS];

    // prologue phase A (chunk 0): loads land under the guidance preamble
    unsigned aq0[6], aq2[3];
    stageA1(cvol, tid, h0p, w0p, 0, aq0, aq2);

    // ---- guidance: single pass, un-normalized, bf16 pairs (38 regs) ----
    float asum = 0.f;
    unsigned gp[38];
#pragma unroll
    for (int p = 0; p < 38; ++p) {
        int c0 = 2 * p, c1 = 2 * p + 1;
        float w0 = lg1[c0 * NPIX + pix];
        float w1 = (c1 < 75) ? lg1[c1 * NPIX + pix] : 0.f;
        unsigned b0 = bf16bits(w0), b1 = bf16bits(w1);
        asum += fabsf(__uint_as_float(b0 << 16)) +
                fabsf(__uint_as_float(b1 << 16));
        gp[p] = b0 | (b1 << 16);
    }
    const float inv = 1.f / fmaxf(asum, 1e-12f);

    const int pbase = (ty * ROWSTRIDE + tx + 6) * PIXW;
    __hip_bfloat16* ybase = yout + pix;

    scat1((unsigned short*)su, tid, aq0, aq2); // chunk 0 -> buf0
    int pb = 0;
    for (int d0 = 0; d0 < dend; d0 += CHUNK) {
        __syncthreads(); // buf[pb] writes visible; buf[pb^1] readers done
        const bool hn = (d0 + CHUNK < dend);
        if (hn) stageA1(cvol, tid, h0p, w0p, d0 + CHUNK, aq0, aq2);

        const unsigned* sw = su + pb * SUWORDS + pbase;
        float acc[16];
#pragma unroll
        for (int d = 0; d < 16; ++d) acc[d] = 0.f;
#pragma unroll
        for (int i = 0; i < 5; ++i) {
#pragma unroll
            for (int j = 0; j < 5; ++j) {
                const int t = i * 5 + j;
                TAP16(sw + (i * ROWSTRIDE + j) * PIXW, t);
            }
        }

        if (hn) scat1((unsigned short*)(su + (pb ^ 1) * SUWORDS), tid, aq0, aq2);

        if (d0 + CHUNK <= dend) {
#pragma unroll
            for (int dd = 0; dd < CHUNK; ++dd)
                ybase[(size_t)(d0 + dd) * NPIX] =
                    __float2bfloat16(acc[dd] * inv);
        } else {
#pragma unroll
            for (int dd = 0; dd < CHUNK; ++dd)
                if (d0 + dd < dend)
                    ybase[(size_t)(d0 + dd) * NPIX] =
                        __float2bfloat16(acc[dd] * inv);
        }
        pb ^= 1;
    }
}

// ---------------------------------------------------------------------------
// LGA pass 2: same structure; phase A is a pure uint4 HBM load; online
// softmin completes per pixel, S/L fused.
// ---------------------------------------------------------------------------
__global__ __launch_bounds__(256)
__attribute__((amdgpu_num_vgpr(128))) void lga2_kernel(
    const __hip_bfloat16* __restrict__ xin,
    const float* __restrict__ lg1,
    float* __restrict__ out) {
    const int tid = threadIdx.x;
    const int tx = tid & 15;
    const int ty = tid >> 4;
    const int w0p = blockIdx.x * 16;
    const int h0p = blockIdx.y * 16;
    const int dend = DOUT;
    const int pix = (h0p + ty) * WOUT + (w0p + tx);
    const unsigned short* xus = (const unsigned short*)xin;

    __shared__ __align__(16) unsigned su[2 * SUWORDS];

    uint4 dat[6];
    stageA2(xus, tid, h0p, w0p, 0, dat);

    float asum = 0.f;
    unsigned gp[38];
#pragma unroll
    for (int p = 0; p < 38; ++p) {
        int c0 = 2 * p, c1 = 2 * p + 1;
        float w0 = lg1[c0 * NPIX + pix];
        float w1 = (c1 < 75) ? lg1[c1 * NPIX + pix] : 0.f;
        unsigned b0 = bf16bits(w0), b1 = bf16bits(w1);
        asum += fabsf(__uint_as_float(b0 << 16)) +
                fabsf(__uint_as_float(b1 << 16));
        gp[p] = b0 | (b1 << 16);
    }
    const float inv = 1.f / fmaxf(asum, 1e-12f);

    const int pbase = (ty * ROWSTRIDE + tx + 6) * PIXW;

    float m = -1e30f, l = 0.f, s_acc = 0.f;

    scat2((unsigned short*)su, tid, dat); // chunk 0 -> buf0
    int pb = 0;
    for (int d0 = 0; d0 < dend; d0 += CHUNK) {
        __syncthreads();
        const bool hn = (d0 + CHUNK < dend);
        if (hn) stageA2(xus, tid, h0p, w0p, d0 + CHUNK, dat);

        const unsigned* sw = su + pb * SUWORDS + pbase;
        float acc[16];
#pragma unroll
        for (int d = 0; d < 16; ++d) acc[d] = 0.f;
#pragma unroll
        for (int i = 0; i < 5; ++i) {
#pragma unroll
            for (int j = 0; j < 5; ++j) {
                const int t = i * 5 + j;
                TAP16(sw + (i * ROWSTRIDE + j) * PIXW, t);
            }
        }

        if (hn) scat2((unsigned short*)(su + (pb ^ 1) * SUWORDS), tid, dat);

        if (d0 + CHUNK <= dend) {
            float v[16];
            float mx = m;
#pragma unroll
            for (int d = 0; d < 16; ++d) {
                v[d] = -acc[d] * inv;
                mx = fmaxf(mx, v[d]);
            }
            float sc = __expf(m - mx);
            float sum = 0.f, ssum = 0.f;
#pragma unroll
            for (int d = 0; d < 16; ++d) {
                float e = __expf(v[d] - mx);
                sum += e;
                ssum += e * (float)(d0 + d);
            }
            l = l * sc + sum;
            s_acc = s_acc * sc + ssum;
            m = mx;
        } else {
#pragma unroll
            for (int dd = 0; dd < CHUNK; ++dd) {
                int d = d0 + dd;
                if (d < dend) {
                    float vv = -acc[dd] * inv;
                    float mx = fmaxf(m, vv);
                    float sc = __expf(m - mx);
                    float e = __expf(vv - mx);
                    l = l * sc + e;
                    s_acc = s_acc * sc + e * (float)d;
                    m = mx;
                }
            }
        }
        pb ^= 1;
    }

    out[pix] = s_acc / l;
}

// ---------------------------------------------------------------------------
extern "C" void kernel_launch(void* const* d_in, const int* in_sizes, int n_in,
                              void* d_out, int out_size, void* d_ws,
                              size_t ws_size, hipStream_t stream) {
    const float* x = (const float*)d_in[0];
    const float* lg1 = (const float*)d_in[1];
    const float* cw = (const float*)d_in[2];
    float* out = (float*)d_out;

    // ws: c fp32 [100352] | region A bf16 [NUPS] | region B bf16 [NUPS].
    // conv partials [8][NCONV] overlay region B; lga1 writes y1 to region B.
    float* c = (float*)d_ws;
    __hip_bfloat16* regA = (__hip_bfloat16*)((char*)d_ws + (size_t)NCONV * 4);
    __hip_bfloat16* y1 = regA + (size_t)NUPS;
    float* cpart = (float*)y1;

    dim3 cgrid(NCONV / 1024, CGRP); // 98 x 8; each thread does 4 w-outputs
    conv3d_kernel<<<cgrid, 256, 0, stream>>>(x, cw, cpart);
    convfold_kernel<<<NCONV / 256, 256, 0, stream>>>(cpart, c);

    dim3 grid(WOUT / 16, HOUT / 16, NZ); // 32 x 16 x 1 = 512 blocks
    lga1_kernel<<<grid, 256, 0, stream>>>(c, lg1, y1);
    lga2_kernel<<<grid, 256, 0, stream>>>(y1, lg1, out);
}

// Round 15
// 288.414 us; speedup vs baseline: 1.3783x; 1.0308x over previous
//
#include <hip/hip_runtime.h>
#include <hip/hip_bf16.h>

#define DIN 49
#define HIN 32
#define WIN 64
#define CIN 32
#define DOUT 193
#define HOUT 256
#define WOUT 512
#define NPIX (HOUT * WOUT)      // 131072
#define NUPS (DOUT * NPIX)      // 25296896
#define NCONV (DIN * HIN * WIN) // 100352
#define NZ 1
#define CGRP 8 // conv channel groups (4 ci each)

// LGA LDS geometry: bf16-packed, d-contiguous per pixel, dot2-consumed
// (R13 measured win). CHUNK=16 (R14): PIXW=10 words/pixel, double-buffered
// 2 x 25.8 KB. Single barrier per chunk, 13 chunks.
#define ROWSTRIDE 33 // pixel-row stride in pixels
#define PIXW 10      // words per pixel
#define SUWORDS (20 * ROWSTRIDE * PIXW) // 6600 words per buffer
#define CHUNK 16
#define NPL 18   // CHUNK + 2 halo planes
// staging jobs: 20 rows x 4 segs x 18 planes = 1440; k<6 with tail 160
#define JGUARD(k, tid) ((k) < 5 || (tid) < 160)

typedef __attribute__((ext_vector_type(2))) float v2f;

// v_dot2_f32_bf16: d = a.lo*b.lo + a.hi*b.hi + c (packed bf16 operands).
__device__ __forceinline__ float dot2bf(unsigned a, unsigned b, float c) {
    float d;
    asm("v_dot2_f32_bf16 %0, %1, %2, %3"
        : "=v"(d)
        : "v"(a), "v"(b), "v"(c));
    return d;
}

// ---------------------------------------------------------------------------
// Kernel 1: 3x3x3 conv, 32 -> 1 ch, zero pad 1, split 8 ways over channels.
// 4-wide w-vectorized (R10 measured win).
// ---------------------------------------------------------------------------
__global__ void conv3d_kernel(const float* __restrict__ x,
                              const float* __restrict__ w,
                              float* __restrict__ partial) {
    __shared__ float ws[4 * 27];
    const int grp = blockIdx.y;
    for (int t = threadIdx.x; t < 4 * 27; t += blockDim.x)
        ws[t] = w[grp * (4 * 27) + t];
    __syncthreads();

    int idx4 = blockIdx.x * blockDim.x + threadIdx.x; // 25088 = 98*256 exact
    int w4 = idx4 & 15;  // WIN/4 = 16
    int t2 = idx4 >> 4;
    int hq = t2 & 31;    // HIN = 32
    int dq = t2 >> 5;    // dq in [0, 49)
    int wq0 = w4 * 4;

    float acc0 = 0.f, acc1 = 0.f, acc2 = 0.f, acc3 = 0.f;
    const float* xg = x + (size_t)grp * 4 * NCONV;
#pragma unroll
    for (int cl = 0; cl < 4; ++cl) {
        const float* xb = xg + cl * NCONV;
        const float* wb = ws + cl * 27;
#pragma unroll
        for (int kd = 0; kd < 3; ++kd) {
            int zd = dq + kd - 1;
            if (zd < 0 || zd >= DIN) continue;
#pragma unroll
            for (int kh = 0; kh < 3; ++kh) {
                int zh = hq + kh - 1;
                if (zh < 0 || zh >= HIN) continue;
                const float* row = xb + (zd * HIN + zh) * WIN;
                float4 v = *(const float4*)(row + wq0);
                float xl = (wq0 > 0) ? row[wq0 - 1] : 0.f;
                float xr = (wq0 < WIN - 4) ? row[wq0 + 4] : 0.f;
                float w0 = wb[(kd * 3 + kh) * 3 + 0];
                float w1 = wb[(kd * 3 + kh) * 3 + 1];
                float w2 = wb[(kd * 3 + kh) * 3 + 2];
                acc0 = fmaf(w0, xl, acc0);
                acc0 = fmaf(w1, v.x, acc0);
                acc0 = fmaf(w2, v.y, acc0);
                acc1 = fmaf(w0, v.x, acc1);
                acc1 = fmaf(w1, v.y, acc1);
                acc1 = fmaf(w2, v.z, acc1);
                acc2 = fmaf(w0, v.y, acc2);
                acc2 = fmaf(w1, v.z, acc2);
                acc2 = fmaf(w2, v.w, acc2);
                acc3 = fmaf(w0, v.z, acc3);
                acc3 = fmaf(w1, v.w, acc3);
                acc3 = fmaf(w2, xr, acc3);
            }
        }
    }
    float4 o4 = make_float4(acc0, acc1, acc2, acc3);
    *(float4*)(partial + (size_t)grp * NCONV + (size_t)idx4 * 4) = o4;
}

// ---------------------------------------------------------------------------
// Kernel 1b: fold 8 conv partials -> c. float4-vectorized (4x fewer insts
// for a launch/latency-bound kernel).
// ---------------------------------------------------------------------------
__global__ void convfold_kernel(const float* __restrict__ partial,
                                float* __restrict__ c) {
    int i4 = blockIdx.x * blockDim.x + threadIdx.x; // NCONV/4 = 25088
    float4 s = *(const float4*)(partial + (size_t)i4 * 4);
#pragma unroll
    for (int g = 1; g < CGRP; ++g) {
        float4 v = *(const float4*)(partial + (size_t)g * NCONV +
                                    (size_t)i4 * 4);
        s.x += v.x;
        s.y += v.y;
        s.z += v.z;
        s.w += v.w;
    }
    *(float4*)(c + (size_t)i4 * 4) = s;
}

__device__ __forceinline__ unsigned short bf16bits(float f) {
    __hip_bfloat16 h = __float2bfloat16(f);
    unsigned short b;
    __builtin_memcpy(&b, &h, 2);
    return b;
}

// Tap body for CHUNK=16: 9 LDS words (4x b64 + b32), 32 dot2, one set of
// packed weight words per tap (amortized over 16 outputs). gp[] holds bf16
// channel pairs; parity of t selects halves at compile time.
#define TAP16(sp, t)                                                 \
    do {                                                             \
        unsigned u0, u1, u2, u3, u4, u5, u6, u7, u8;                 \
        { uint2 q = *(const uint2*)(sp);       u0 = q.x; u1 = q.y; } \
        { uint2 q = *(const uint2*)((sp) + 2); u2 = q.x; u3 = q.y; } \
        { uint2 q = *(const uint2*)((sp) + 4); u4 = q.x; u5 = q.y; } \
        { uint2 q = *(const uint2*)((sp) + 6); u6 = q.x; u7 = q.y; } \
        u8 = (sp)[8];                                                \
        const unsigned g0w = gp[(t) >> 1];                           \
        const unsigned g1w = gp[(25 + (t)) >> 1];                    \
        const unsigned g2w = gp[(50 + (t)) >> 1];                    \
        unsigned W10, W2z, Wz1, W02;                                 \
        if ((t) & 1) {                                               \
            W10 = (g1w & 0xFFFFu) | (g0w & 0xFFFF0000u);             \
            W2z = g2w >> 16;                                         \
            Wz1 = g1w << 16;                                         \
            W02 = (g0w >> 16) | (g2w & 0xFFFF0000u);                 \
        } else {                                                     \
            W10 = (g1w >> 16) | (g0w << 16);                         \
            W2z = g2w & 0xFFFFu;                                     \
            Wz1 = g1w & 0xFFFF0000u;                                 \
            W02 = (g0w & 0xFFFFu) | (g2w << 16);                     \
        }                                                            \
        acc[0] = dot2bf(u0, W10, acc[0]);                            \
        acc[0] = dot2bf(u1, W2z, acc[0]);                            \
        acc[1] = dot2bf(u0, Wz1, acc[1]);                            \
        acc[1] = dot2bf(u1, W02, acc[1]);                            \
        acc[2] = dot2bf(u1, W10, acc[2]);                            \
        acc[2] = dot2bf(u2, W2z, acc[2]);                            \
        acc[3] = dot2bf(u1, Wz1, acc[3]);                            \
        acc[3] = dot2bf(u2, W02, acc[3]);                            \
        acc[4] = dot2bf(u2, W10, acc[4]);                            \
        acc[4] = dot2bf(u3, W2z, acc[4]);                            \
        acc[5] = dot2bf(u2, Wz1, acc[5]);                            \
        acc[5] = dot2bf(u3, W02, acc[5]);                            \
        acc[6] = dot2bf(u3, W10, acc[6]);                            \
        acc[6] = dot2bf(u4, W2z, acc[6]);                            \
        acc[7] = dot2bf(u3, Wz1, acc[7]);                            \
        acc[7] = dot2bf(u4, W02, acc[7]);                            \
        acc[8] = dot2bf(u4, W10, acc[8]);                            \
        acc[8] = dot2bf(u5, W2z, acc[8]);                            \
        acc[9] = dot2bf(u4, Wz1, acc[9]);                            \
        acc[9] = dot2bf(u5, W02, acc[9]);                            \
        acc[10] = dot2bf(u5, W10, acc[10]);                          \
        acc[10] = dot2bf(u6, W2z, acc[10]);                          \
        acc[11] = dot2bf(u5, Wz1, acc[11]);                          \
        acc[11] = dot2bf(u6, W02, acc[11]);                          \
        acc[12] = dot2bf(u6, W10, acc[12]);                          \
        acc[12] = dot2bf(u7, W2z, acc[12]);                          \
        acc[13] = dot2bf(u6, Wz1, acc[13]);                          \
        acc[13] = dot2bf(u7, W02, acc[13]);                          \
        acc[14] = dot2bf(u7, W10, acc[14]);                          \
        acc[14] = dot2bf(u8, W2z, acc[14]);                          \
        acc[15] = dot2bf(u7, Wz1, acc[15]);                          \
        acc[15] = dot2bf(u8, W02, acc[15]);                          \
    } while (0)

// job decode (1440 jobs): seg in [0,4), dl in [0,18), r in [0,20)
__device__ __forceinline__ void jdec(int j, int& seg, int& dl, int& r) {
    seg = j & 3;
    int rowjob = j >> 2; // [0, 360)
    dl = rowjob / 20;
    r = rowjob - dl * 20;
}

// ---------------------------------------------------------------------------
// lga1 staging phase A: trilinear d/h-lerp from c (L2-hot) into packed
// bf16 regs (9 regs for 6 jobs). Issued EARLY (T14).
// ---------------------------------------------------------------------------
__device__ __forceinline__ void stageA1(const float* __restrict__ cvol,
                                        int tid, int h0p, int w0p, int dstart,
                                        unsigned (&aq0)[6], unsigned (&aq2)[3]) {
    aq2[0] = 0u;
    aq2[1] = 0u;
    aq2[2] = 0u;
#pragma unroll
    for (int k = 0; k < 6; ++k) {
        const bool a = JGUARD(k, tid);
        int j = tid + k * 256;
        int seg, dl, r;
        jdec(j, seg, dl, r);
        int gh = h0p - 2 + r;
        int gwb = w0p - 8 + seg * 8;
        int gd = dstart - 1 + dl;
        if (a && gd >= 0 && gd < DOUT && gh >= 0 && gh < HOUT && gwb >= 0 &&
            (gwb + 8) <= WOUT) {
            float fd = (gd + 0.5f) * (49.0f / 193.0f) - 0.5f;
            fd = fminf(fmaxf(fd, 0.f), (float)(DIN - 1));
            int d0c = min((int)fd, DIN - 2);
            float ad = fd - (float)d0c;
            float fh = (gh + 0.5f) * 0.125f - 0.5f;
            fh = fminf(fmaxf(fh, 0.f), (float)(HIN - 1));
            int h0c = min((int)fh, HIN - 2);
            float ah = fh - (float)h0c;
            int g = gwb >> 3;
            int cm1 = max(g - 1, 0);
            int cp1 = min(g + 1, WIN - 1);
            const float* p00 = cvol + (d0c * HIN + h0c) * WIN;
            const float* p01 = p00 + WIN;
            const float* p10 = p00 + HIN * WIN;
            const float* p11 = p10 + WIN;
            float q00, q01, q10, q11, a0, a1, a2;
            q00 = p00[cm1]; q01 = p01[cm1];
            q10 = p10[cm1]; q11 = p11[cm1];
            a0 = (q00 + ah * (q01 - q00)) * (1.f - ad) +
                 (q10 + ah * (q11 - q10)) * ad;
            q00 = p00[g]; q01 = p01[g];
            q10 = p10[g]; q11 = p11[g];
            a1 = (q00 + ah * (q01 - q00)) * (1.f - ad) +
                 (q10 + ah * (q11 - q10)) * ad;
            q00 = p00[cp1]; q01 = p01[cp1];
            q10 = p10[cp1]; q11 = p11[cp1];
            a2 = (q00 + ah * (q01 - q00)) * (1.f - ad) +
                 (q10 + ah * (q11 - q10)) * ad;
            aq0[k] = (unsigned)bf16bits(a0) | ((unsigned)bf16bits(a1) << 16);
            aq2[k >> 1] |= ((unsigned)bf16bits(a2)) << ((k & 1) * 16);
        } else {
            aq0[k] = 0u;
        }
    }
}

// lga1 scatter phase B: w-lerp from regs, bf16 half-word stores into LDS.
// Plane dl of pixel p lives at half-index p*2*PIXW + dl.
__device__ __forceinline__ void scat1(unsigned short* __restrict__ su16,
                                      int tid, const unsigned (&aq0)[6],
                                      const unsigned (&aq2)[3]) {
#pragma unroll
    for (int k = 0; k < 6; ++k) {
        if (JGUARD(k, tid)) {
            int j = tid + k * 256;
            int seg, dl, r;
            jdec(j, seg, dl, r);
            int hb = (r * ROWSTRIDE + seg * 8) * (2 * PIXW) + dl;
            float a0 = __uint_as_float(aq0[k] << 16);
            float a1 = __uint_as_float(aq0[k] & 0xFFFF0000u);
            float a2 = __uint_as_float((k & 1) ? (aq2[k >> 1] & 0xFFFF0000u)
                                               : (aq2[k >> 1] << 16));
            float d01 = a1 - a0, d12 = a2 - a1;
            su16[hb + 0 * 2 * PIXW] = bf16bits(a0 + 0.5625f * d01);
            su16[hb + 1 * 2 * PIXW] = bf16bits(a0 + 0.6875f * d01);
            su16[hb + 2 * 2 * PIXW] = bf16bits(a0 + 0.8125f * d01);
            su16[hb + 3 * 2 * PIXW] = bf16bits(a0 + 0.9375f * d01);
            su16[hb + 4 * 2 * PIXW] = bf16bits(a1 + 0.0625f * d12);
            su16[hb + 5 * 2 * PIXW] = bf16bits(a1 + 0.1875f * d12);
            su16[hb + 6 * 2 * PIXW] = bf16bits(a1 + 0.3125f * d12);
            su16[hb + 7 * 2 * PIXW] = bf16bits(a1 + 0.4375f * d12);
        }
    }
}

// lga2 staging phase A: one uint4 (8 bf16) HBM load per job into regs.
__device__ __forceinline__ void stageA2(const unsigned short* __restrict__ xus,
                                        int tid, int h0p, int w0p, int dstart,
                                        uint4 (&dat)[6]) {
#pragma unroll
    for (int k = 0; k < 6; ++k) {
        const bool a = JGUARD(k, tid);
        int j = tid + k * 256;
        int seg, dl, r;
        jdec(j, seg, dl, r);
        int gh = h0p - 2 + r;
        int gwb = w0p - 8 + seg * 8;
        int gd = dstart - 1 + dl;
        uint4 v = make_uint4(0u, 0u, 0u, 0u);
        if (a && gd >= 0 && gd < DOUT && gh >= 0 && gh < HOUT && gwb >= 0 &&
            (gwb + 8) <= WOUT)
            v = *(const uint4*)(xus + (size_t)gd * NPIX + gh * WOUT + gwb);
        dat[k] = v;
    }
}

// lga2 scatter phase B: bf16 half-word stores straight from packed regs.
__device__ __forceinline__ void scat2(unsigned short* __restrict__ su16,
                                      int tid, const uint4 (&dat)[6]) {
#pragma unroll
    for (int k = 0; k < 6; ++k) {
        if (JGUARD(k, tid)) {
            int j = tid + k * 256;
            int seg, dl, r;
            jdec(j, seg, dl, r);
            int hb = (r * ROWSTRIDE + seg * 8) * (2 * PIXW) + dl;
            su16[hb + 0 * 2 * PIXW] = (unsigned short)(dat[k].x);
            su16[hb + 1 * 2 * PIXW] = (unsigned short)(dat[k].x >> 16);
            su16[hb + 2 * 2 * PIXW] = (unsigned short)(dat[k].y);
            su16[hb + 3 * 2 * PIXW] = (unsigned short)(dat[k].y >> 16);
            su16[hb + 4 * 2 * PIXW] = (unsigned short)(dat[k].z);
            su16[hb + 5 * 2 * PIXW] = (unsigned short)(dat[k].z >> 16);
            su16[hb + 6 * 2 * PIXW] = (unsigned short)(dat[k].w);
            su16[hb + 7 * 2 * PIXW] = (unsigned short)(dat[k].w >> 16);
        }
    }
}

// ---------------------------------------------------------------------------
// LGA pass 1. bf16 double-buffered su + dot2 taps, CHUNK=16 (13 barriers).
// s_setprio(1) around the tap loop (T5): the CU's 2 blocks drift out of
// phase, so compute-phase waves preempt staging-phase waves for issue
// slots. amdgpu_num_vgpr(128) pin.
// ---------------------------------------------------------------------------
__global__ __launch_bounds__(256)
__attribute__((amdgpu_num_vgpr(128))) void lga1_kernel(
    const float* __restrict__ cvol,
    const float* __restrict__ lg1,
    __hip_bfloat16* __restrict__ yout) {
    const int tid = threadIdx.x;
    const int tx = tid & 15;
    const int ty = tid >> 4;
    const int w0p = blockIdx.x * 16;
    const int h0p = blockIdx.y * 16;
    const int dend = DOUT;
    const int pix = (h0p + ty) * WOUT + (w0p + tx);

    __shared__ __align__(16) unsigned su[2 * SUWORDS];

    // prologue phase A (chunk 0): loads land under the guidance preamble
    unsigned aq0[6], aq2[3];
    stageA1(cvol, tid, h0p, w0p, 0, aq0, aq2);

    // ---- guidance: single pass, un-normalized, bf16 pairs (38 regs) ----
    float asum = 0.f;
    unsigned gp[38];
#pragma unroll
    for (int p = 0; p < 38; ++p) {
        int c0 = 2 * p, c1 = 2 * p + 1;
        float w0 = lg1[c0 * NPIX + pix];
        float w1 = (c1 < 75) ? lg1[c1 * NPIX + pix] : 0.f;
        unsigned b0 = bf16bits(w0), b1 = bf16bits(w1);
        asum += fabsf(__uint_as_float(b0 << 16)) +
                fabsf(__uint_as_float(b1 << 16));
        gp[p] = b0 | (b1 << 16);
    }
    const float inv = 1.f / fmaxf(asum, 1e-12f);

    const int pbase = (ty * ROWSTRIDE + tx + 6) * PIXW;
    __hip_bfloat16* ybase = yout + pix;

    scat1((unsigned short*)su, tid, aq0, aq2); // chunk 0 -> buf0
    int pb = 0;
    for (int d0 = 0; d0 < dend; d0 += CHUNK) {
        __syncthreads(); // buf[pb] writes visible; buf[pb^1] readers done
        const bool hn = (d0 + CHUNK < dend);
        if (hn) stageA1(cvol, tid, h0p, w0p, d0 + CHUNK, aq0, aq2);

        const unsigned* sw = su + pb * SUWORDS + pbase;
        float acc[16];
#pragma unroll
        for (int d = 0; d < 16; ++d) acc[d] = 0.f;
        __builtin_amdgcn_s_setprio(1);
#pragma unroll
        for (int i = 0; i < 5; ++i) {
#pragma unroll
            for (int j = 0; j < 5; ++j) {
                const int t = i * 5 + j;
                TAP16(sw + (i * ROWSTRIDE + j) * PIXW, t);
            }
        }
        __builtin_amdgcn_s_setprio(0);

        if (hn) scat1((unsigned short*)(su + (pb ^ 1) * SUWORDS), tid, aq0, aq2);

        if (d0 + CHUNK <= dend) {
#pragma unroll
            for (int dd = 0; dd < CHUNK; ++dd)
                ybase[(size_t)(d0 + dd) * NPIX] =
                    __float2bfloat16(acc[dd] * inv);
        } else {
#pragma unroll
            for (int dd = 0; dd < CHUNK; ++dd)
                if (d0 + dd < dend)
                    ybase[(size_t)(d0 + dd) * NPIX] =
                        __float2bfloat16(acc[dd] * inv);
        }
        pb ^= 1;
    }
}

// ---------------------------------------------------------------------------
// LGA pass 2: same structure; phase A is a pure uint4 HBM load; online
// softmin completes per pixel, S/L fused. Same setprio wrap.
// ---------------------------------------------------------------------------
__global__ __launch_bounds__(256)
__attribute__((amdgpu_num_vgpr(128))) void lga2_kernel(
    const __hip_bfloat16* __restrict__ xin,
    const float* __restrict__ lg1,
    float* __restrict__ out) {
    const int tid = threadIdx.x;
    const int tx = tid & 15;
    const int ty = tid >> 4;
    const int w0p = blockIdx.x * 16;
    const int h0p = blockIdx.y * 16;
    const int dend = DOUT;
    const int pix = (h0p + ty) * WOUT + (w0p + tx);
    const unsigned short* xus = (const unsigned short*)xin;

    __shared__ __align__(16) unsigned su[2 * SUWORDS];

    uint4 dat[6];
    stageA2(xus, tid, h0p, w0p, 0, dat);

    float asum = 0.f;
    unsigned gp[38];
#pragma unroll
    for (int p = 0; p < 38; ++p) {
        int c0 = 2 * p, c1 = 2 * p + 1;
        float w0 = lg1[c0 * NPIX + pix];
        float w1 = (c1 < 75) ? lg1[c1 * NPIX + pix] : 0.f;
        unsigned b0 = bf16bits(w0), b1 = bf16bits(w1);
        asum += fabsf(__uint_as_float(b0 << 16)) +
                fabsf(__uint_as_float(b1 << 16));
        gp[p] = b0 | (b1 << 16);
    }
    const float inv = 1.f / fmaxf(asum, 1e-12f);

    const int pbase = (ty * ROWSTRIDE + tx + 6) * PIXW;

    float m = -1e30f, l = 0.f, s_acc = 0.f;

    scat2((unsigned short*)su, tid, dat); // chunk 0 -> buf0
    int pb = 0;
    for (int d0 = 0; d0 < dend; d0 += CHUNK) {
        __syncthreads();
        const bool hn = (d0 + CHUNK < dend);
        if (hn) stageA2(xus, tid, h0p, w0p, d0 + CHUNK, dat);

        const unsigned* sw = su + pb * SUWORDS + pbase;
        float acc[16];
#pragma unroll
        for (int d = 0; d < 16; ++d) acc[d] = 0.f;
        __builtin_amdgcn_s_setprio(1);
#pragma unroll
        for (int i = 0; i < 5; ++i) {
#pragma unroll
            for (int j = 0; j < 5; ++j) {
                const int t = i * 5 + j;
                TAP16(sw + (i * ROWSTRIDE + j) * PIXW, t);
            }
        }
        __builtin_amdgcn_s_setprio(0);

        if (hn) scat2((unsigned short*)(su + (pb ^ 1) * SUWORDS), tid, dat);

        if (d0 + CHUNK <= dend) {
            float v[16];
            float mx = m;
#pragma unroll
            for (int d = 0; d < 16; ++d) {
                v[d] = -acc[d] * inv;
                mx = fmaxf(mx, v[d]);
            }
            float sc = __expf(m - mx);
            float sum = 0.f, ssum = 0.f;
#pragma unroll
            for (int d = 0; d < 16; ++d) {
                float e = __expf(v[d] - mx);
                sum += e;
                ssum += e * (float)(d0 + d);
            }
            l = l * sc + sum;
            s_acc = s_acc * sc + ssum;
            m = mx;
        } else {
#pragma unroll
            for (int dd = 0; dd < CHUNK; ++dd) {
                int d = d0 + dd;
                if (d < dend) {
                    float vv = -acc[dd] * inv;
                    float mx = fmaxf(m, vv);
                    float sc = __expf(m - mx);
                    float e = __expf(vv - mx);
                    l = l * sc + e;
                    s_acc = s_acc * sc + e * (float)d;
                    m = mx;
                }
            }
        }
        pb ^= 1;
    }

    out[pix] = s_acc / l;
}

// ---------------------------------------------------------------------------
extern "C" void kernel_launch(void* const* d_in, const int* in_sizes, int n_in,
                              void* d_out, int out_size, void* d_ws,
                              size_t ws_size, hipStream_t stream) {
    const float* x = (const float*)d_in[0];
    const float* lg1 = (const float*)d_in[1];
    const float* cw = (const float*)d_in[2];
    float* out = (float*)d_out;

    // ws: c fp32 [100352] | region A bf16 [NUPS] | region B bf16 [NUPS].
    // conv partials [8][NCONV] overlay region B; lga1 writes y1 to region B.
    float* c = (float*)d_ws;
    __hip_bfloat16* regA = (__hip_bfloat16*)((char*)d_ws + (size_t)NCONV * 4);
    __hip_bfloat16* y1 = regA + (size_t)NUPS;
    float* cpart = (float*)y1;

    dim3 cgrid(NCONV / 1024, CGRP); // 98 x 8; each thread does 4 w-outputs
    conv3d_kernel<<<cgrid, 256, 0, stream>>>(x, cw, cpart);
    convfold_kernel<<<NCONV / 1024, 256, 0, stream>>>(cpart, c);

    dim3 grid(WOUT / 16, HOUT / 16, NZ); // 32 x 16 x 1 = 512 blocks
    lga1_kernel<<<grid, 256, 0, stream>>>(c, lg1, y1);
    lga2_kernel<<<grid, 256, 0, stream>>>(y1, lg1, out);
}

// Round 16
// 282.296 us; speedup vs baseline: 1.4082x; 1.0217x over previous
//
#include <hip/hip_runtime.h>
#include <hip/hip_bf16.h>

#define DIN 49
#define HIN 32
#define WIN 64
#define CIN 32
#define DOUT 193
#define HOUT 256
#define WOUT 512
#define NPIX (HOUT * WOUT)      // 131072
#define NUPS (DOUT * NPIX)      // 25296896
#define NCONV (DIN * HIN * WIN) // 100352
#define NZ 1
#define CGRP 8 // conv channel groups (4 ci each)

// LGA LDS geometry: bf16-packed, d-contiguous per pixel, dot2-consumed
// (R13). CHUNK=16 (R14): PIXW=10 words/pixel, double-buffered 2 x 25.8 KB.
// 12 full chunks + 1-plane epilogue (d=192): the tail chunk needs only
// 25 dot2 (one per tap), not 800 — removes 7.7% wasted tap work (R16).
#define ROWSTRIDE 33 // pixel-row stride in pixels
#define PIXW 10      // words per pixel
#define SUWORDS (20 * ROWSTRIDE * PIXW) // 6600 words per buffer
#define CHUNK 16
#define NPL 18   // CHUNK + 2 halo planes
// staging jobs: 20 rows x 4 segs x 18 planes = 1440; k<6 with tail 160
#define JGUARD(k, tid) ((k) < 5 || (tid) < 160)

typedef __attribute__((ext_vector_type(2))) float v2f;

// v_dot2_f32_bf16: d = a.lo*b.lo + a.hi*b.hi + c (packed bf16 operands).
__device__ __forceinline__ float dot2bf(unsigned a, unsigned b, float c) {
    float d;
    asm("v_dot2_f32_bf16 %0, %1, %2, %3"
        : "=v"(d)
        : "v"(a), "v"(b), "v"(c));
    return d;
}

// ---------------------------------------------------------------------------
// Kernel 1: 3x3x3 conv, 32 -> 1 ch, zero pad 1, split 8 ways over channels.
// 4-wide w-vectorized (R10 measured win).
// ---------------------------------------------------------------------------
__global__ void conv3d_kernel(const float* __restrict__ x,
                              const float* __restrict__ w,
                              float* __restrict__ partial) {
    __shared__ float ws[4 * 27];
    const int grp = blockIdx.y;
    for (int t = threadIdx.x; t < 4 * 27; t += blockDim.x)
        ws[t] = w[grp * (4 * 27) + t];
    __syncthreads();

    int idx4 = blockIdx.x * blockDim.x + threadIdx.x; // 25088 = 98*256 exact
    int w4 = idx4 & 15;  // WIN/4 = 16
    int t2 = idx4 >> 4;
    int hq = t2 & 31;    // HIN = 32
    int dq = t2 >> 5;    // dq in [0, 49)
    int wq0 = w4 * 4;

    float acc0 = 0.f, acc1 = 0.f, acc2 = 0.f, acc3 = 0.f;
    const float* xg = x + (size_t)grp * 4 * NCONV;
#pragma unroll
    for (int cl = 0; cl < 4; ++cl) {
        const float* xb = xg + cl * NCONV;
        const float* wb = ws + cl * 27;
#pragma unroll
        for (int kd = 0; kd < 3; ++kd) {
            int zd = dq + kd - 1;
            if (zd < 0 || zd >= DIN) continue;
#pragma unroll
            for (int kh = 0; kh < 3; ++kh) {
                int zh = hq + kh - 1;
                if (zh < 0 || zh >= HIN) continue;
                const float* row = xb + (zd * HIN + zh) * WIN;
                float4 v = *(const float4*)(row + wq0);
                float xl = (wq0 > 0) ? row[wq0 - 1] : 0.f;
                float xr = (wq0 < WIN - 4) ? row[wq0 + 4] : 0.f;
                float w0 = wb[(kd * 3 + kh) * 3 + 0];
                float w1 = wb[(kd * 3 + kh) * 3 + 1];
                float w2 = wb[(kd * 3 + kh) * 3 + 2];
                acc0 = fmaf(w0, xl, acc0);
                acc0 = fmaf(w1, v.x, acc0);
                acc0 = fmaf(w2, v.y, acc0);
                acc1 = fmaf(w0, v.x, acc1);
                acc1 = fmaf(w1, v.y, acc1);
                acc1 = fmaf(w2, v.z, acc1);
                acc2 = fmaf(w0, v.y, acc2);
                acc2 = fmaf(w1, v.z, acc2);
                acc2 = fmaf(w2, v.w, acc2);
                acc3 = fmaf(w0, v.z, acc3);
                acc3 = fmaf(w1, v.w, acc3);
                acc3 = fmaf(w2, xr, acc3);
            }
        }
    }
    float4 o4 = make_float4(acc0, acc1, acc2, acc3);
    *(float4*)(partial + (size_t)grp * NCONV + (size_t)idx4 * 4) = o4;
}

// ---------------------------------------------------------------------------
// Kernel 1b: fold 8 conv partials -> c. float4-vectorized.
// ---------------------------------------------------------------------------
__global__ void convfold_kernel(const float* __restrict__ partial,
                                float* __restrict__ c) {
    int i4 = blockIdx.x * blockDim.x + threadIdx.x; // NCONV/4 = 25088
    float4 s = *(const float4*)(partial + (size_t)i4 * 4);
#pragma unroll
    for (int g = 1; g < CGRP; ++g) {
        float4 v = *(const float4*)(partial + (size_t)g * NCONV +
                                    (size_t)i4 * 4);
        s.x += v.x;
        s.y += v.y;
        s.z += v.z;
        s.w += v.w;
    }
    *(float4*)(c + (size_t)i4 * 4) = s;
}

__device__ __forceinline__ unsigned short bf16bits(float f) {
    __hip_bfloat16 h = __float2bfloat16(f);
    unsigned short b;
    __builtin_memcpy(&b, &h, 2);
    return b;
}

// Tap body for CHUNK=16: 9 LDS words (4x b64 + b32), 32 dot2, one set of
// packed weight words per tap (amortized over 16 outputs). gp[] holds bf16
// channel pairs; parity of t selects halves at compile time.
#define TAP16(sp, t)                                                 \
    do {                                                             \
        unsigned u0, u1, u2, u3, u4, u5, u6, u7, u8;                 \
        { uint2 q = *(const uint2*)(sp);       u0 = q.x; u1 = q.y; } \
        { uint2 q = *(const uint2*)((sp) + 2); u2 = q.x; u3 = q.y; } \
        { uint2 q = *(const uint2*)((sp) + 4); u4 = q.x; u5 = q.y; } \
        { uint2 q = *(const uint2*)((sp) + 6); u6 = q.x; u7 = q.y; } \
        u8 = (sp)[8];                                                \
        const unsigned g0w = gp[(t) >> 1];                           \
        const unsigned g1w = gp[(25 + (t)) >> 1];                    \
        const unsigned g2w = gp[(50 + (t)) >> 1];                    \
        unsigned W10, W2z, Wz1, W02;                                 \
        if ((t) & 1) {                                               \
            W10 = (g1w & 0xFFFFu) | (g0w & 0xFFFF0000u);             \
            W2z = g2w >> 16;                                         \
            Wz1 = g1w << 16;                                         \
            W02 = (g0w >> 16) | (g2w & 0xFFFF0000u);                 \
        } else {                                                     \
            W10 = (g1w >> 16) | (g0w << 16);                         \
            W2z = g2w & 0xFFFFu;                                     \
            Wz1 = g1w & 0xFFFF0000u;                                 \
            W02 = (g0w & 0xFFFFu) | (g2w << 16);                     \
        }                                                            \
        acc[0] = dot2bf(u0, W10, acc[0]);                            \
        acc[0] = dot2bf(u1, W2z, acc[0]);                            \
        acc[1] = dot2bf(u0, Wz1, acc[1]);                            \
        acc[1] = dot2bf(u1, W02, acc[1]);                            \
        acc[2] = dot2bf(u1, W10, acc[2]);                            \
        acc[2] = dot2bf(u2, W2z, acc[2]);                            \
        acc[3] = dot2bf(u1, Wz1, acc[3]);                            \
        acc[3] = dot2bf(u2, W02, acc[3]);                            \
        acc[4] = dot2bf(u2, W10, acc[4]);                            \
        acc[4] = dot2bf(u3, W2z, acc[4]);                            \
        acc[5] = dot2bf(u2, Wz1, acc[5]);                            \
        acc[5] = dot2bf(u3, W02, acc[5]);                            \
        acc[6] = dot2bf(u3, W10, acc[6]);                            \
        acc[6] = dot2bf(u4, W2z, acc[6]);                            \
        acc[7] = dot2bf(u3, Wz1, acc[7]);                            \
        acc[7] = dot2bf(u4, W02, acc[7]);                            \
        acc[8] = dot2bf(u4, W10, acc[8]);                            \
        acc[8] = dot2bf(u5, W2z, acc[8]);                            \
        acc[9] = dot2bf(u4, Wz1, acc[9]);                            \
        acc[9] = dot2bf(u5, W02, acc[9]);                            \
        acc[10] = dot2bf(u5, W10, acc[10]);                          \
        acc[10] = dot2bf(u6, W2z, acc[10]);                          \
        acc[11] = dot2bf(u5, Wz1, acc[11]);                          \
        acc[11] = dot2bf(u6, W02, acc[11]);                          \
        acc[12] = dot2bf(u6, W10, acc[12]);                          \
        acc[12] = dot2bf(u7, W2z, acc[12]);                          \
        acc[13] = dot2bf(u6, Wz1, acc[13]);                          \
        acc[13] = dot2bf(u7, W02, acc[13]);                          \
        acc[14] = dot2bf(u7, W10, acc[14]);                          \
        acc[14] = dot2bf(u8, W2z, acc[14]);                          \
        acc[15] = dot2bf(u7, Wz1, acc[15]);                          \
        acc[15] = dot2bf(u8, W02, acc[15]);                          \
    } while (0)

// Tail tap (d = 192 only): out = g1*u[191] + g0*u[192] (+ g2*0 — u[193]
// is zero-padded). One dot2 per tap on word 0.
#define TAPTAIL(sp, t)                                               \
    do {                                                             \
        unsigned u0 = (sp)[0];                                       \
        const unsigned g0w = gp[(t) >> 1];                           \
        const unsigned g1w = gp[(25 + (t)) >> 1];                    \
        unsigned W10;                                                \
        if ((t) & 1)                                                 \
            W10 = (g1w & 0xFFFFu) | (g0w & 0xFFFF0000u);             \
        else                                                         \
            W10 = (g1w >> 16) | (g0w << 16);                         \
        acc0 = dot2bf(u0, W10, acc0);                                \
    } while (0)

// job decode (1440 jobs): seg in [0,4), dl in [0,18), r in [0,20)
__device__ __forceinline__ void jdec(int j, int& seg, int& dl, int& r) {
    seg = j & 3;
    int rowjob = j >> 2; // [0, 360)
    dl = rowjob / 20;
    r = rowjob - dl * 20;
}

// ---------------------------------------------------------------------------
// lga1 staging phase A: trilinear d/h-lerp from c (L2-hot) into packed
// bf16 regs (9 regs for 6 jobs). Issued EARLY (T14).
// ---------------------------------------------------------------------------
__device__ __forceinline__ void stageA1(const float* __restrict__ cvol,
                                        int tid, int h0p, int w0p, int dstart,
                                        unsigned (&aq0)[6], unsigned (&aq2)[3]) {
    aq2[0] = 0u;
    aq2[1] = 0u;
    aq2[2] = 0u;
#pragma unroll
    for (int k = 0; k < 6; ++k) {
        const bool a = JGUARD(k, tid);
        int j = tid + k * 256;
        int seg, dl, r;
        jdec(j, seg, dl, r);
        int gh = h0p - 2 + r;
        int gwb = w0p - 8 + seg * 8;
        int gd = dstart - 1 + dl;
        if (a && gd >= 0 && gd < DOUT && gh >= 0 && gh < HOUT && gwb >= 0 &&
            (gwb + 8) <= WOUT) {
            float fd = (gd + 0.5f) * (49.0f / 193.0f) - 0.5f;
            fd = fminf(fmaxf(fd, 0.f), (float)(DIN - 1));
            int d0c = min((int)fd, DIN - 2);
            float ad = fd - (float)d0c;
            float fh = (gh + 0.5f) * 0.125f - 0.5f;
            fh = fminf(fmaxf(fh, 0.f), (float)(HIN - 1));
            int h0c = min((int)fh, HIN - 2);
            float ah = fh - (float)h0c;
            int g = gwb >> 3;
            int cm1 = max(g - 1, 0);
            int cp1 = min(g + 1, WIN - 1);
            const float* p00 = cvol + (d0c * HIN + h0c) * WIN;
            const float* p01 = p00 + WIN;
            const float* p10 = p00 + HIN * WIN;
            const float* p11 = p10 + WIN;
            float q00, q01, q10, q11, a0, a1, a2;
            q00 = p00[cm1]; q01 = p01[cm1];
            q10 = p10[cm1]; q11 = p11[cm1];
            a0 = (q00 + ah * (q01 - q00)) * (1.f - ad) +
                 (q10 + ah * (q11 - q10)) * ad;
            q00 = p00[g]; q01 = p01[g];
            q10 = p10[g]; q11 = p11[g];
            a1 = (q00 + ah * (q01 - q00)) * (1.f - ad) +
                 (q10 + ah * (q11 - q10)) * ad;
            q00 = p00[cp1]; q01 = p01[cp1];
            q10 = p10[cp1]; q11 = p11[cp1];
            a2 = (q00 + ah * (q01 - q00)) * (1.f - ad) +
                 (q10 + ah * (q11 - q10)) * ad;
            aq0[k] = (unsigned)bf16bits(a0) | ((unsigned)bf16bits(a1) << 16);
            aq2[k >> 1] |= ((unsigned)bf16bits(a2)) << ((k & 1) * 16);
        } else {
            aq0[k] = 0u;
        }
    }
}

// lga1 scatter phase B: w-lerp from regs, bf16 half-word stores into LDS.
__device__ __forceinline__ void scat1(unsigned short* __restrict__ su16,
                                      int tid, const unsigned (&aq0)[6],
                                      const unsigned (&aq2)[3]) {
#pragma unroll
    for (int k = 0; k < 6; ++k) {
        if (JGUARD(k, tid)) {
            int j = tid + k * 256;
            int seg, dl, r;
            jdec(j, seg, dl, r);
            int hb = (r * ROWSTRIDE + seg * 8) * (2 * PIXW) + dl;
            float a0 = __uint_as_float(aq0[k] << 16);
            float a1 = __uint_as_float(aq0[k] & 0xFFFF0000u);
            float a2 = __uint_as_float((k & 1) ? (aq2[k >> 1] & 0xFFFF0000u)
                                               : (aq2[k >> 1] << 16));
            float d01 = a1 - a0, d12 = a2 - a1;
            su16[hb + 0 * 2 * PIXW] = bf16bits(a0 + 0.5625f * d01);
            su16[hb + 1 * 2 * PIXW] = bf16bits(a0 + 0.6875f * d01);
            su16[hb + 2 * 2 * PIXW] = bf16bits(a0 + 0.8125f * d01);
            su16[hb + 3 * 2 * PIXW] = bf16bits(a0 + 0.9375f * d01);
            su16[hb + 4 * 2 * PIXW] = bf16bits(a1 + 0.0625f * d12);
            su16[hb + 5 * 2 * PIXW] = bf16bits(a1 + 0.1875f * d12);
            su16[hb + 6 * 2 * PIXW] = bf16bits(a1 + 0.3125f * d12);
            su16[hb + 7 * 2 * PIXW] = bf16bits(a1 + 0.4375f * d12);
        }
    }
}

// lga2 staging phase A: one uint4 (8 bf16) HBM load per job into regs.
__device__ __forceinline__ void stageA2(const unsigned short* __restrict__ xus,
                                        int tid, int h0p, int w0p, int dstart,
                                        uint4 (&dat)[6]) {
#pragma unroll
    for (int k = 0; k < 6; ++k) {
        const bool a = JGUARD(k, tid);
        int j = tid + k * 256;
        int seg, dl, r;
        jdec(j, seg, dl, r);
        int gh = h0p - 2 + r;
        int gwb = w0p - 8 + seg * 8;
        int gd = dstart - 1 + dl;
        uint4 v = make_uint4(0u, 0u, 0u, 0u);
        if (a && gd >= 0 && gd < DOUT && gh >= 0 && gh < HOUT && gwb >= 0 &&
            (gwb + 8) <= WOUT)
            v = *(const uint4*)(xus + (size_t)gd * NPIX + gh * WOUT + gwb);
        dat[k] = v;
    }
}

// lga2 scatter phase B: bf16 half-word stores straight from packed regs.
__device__ __forceinline__ void scat2(unsigned short* __restrict__ su16,
                                      int tid, const uint4 (&dat)[6]) {
#pragma unroll
    for (int k = 0; k < 6; ++k) {
        if (JGUARD(k, tid)) {
            int j = tid + k * 256;
            int seg, dl, r;
            jdec(j, seg, dl, r);
            int hb = (r * ROWSTRIDE + seg * 8) * (2 * PIXW) + dl;
            su16[hb + 0 * 2 * PIXW] = (unsigned short)(dat[k].x);
            su16[hb + 1 * 2 * PIXW] = (unsigned short)(dat[k].x >> 16);
            su16[hb + 2 * 2 * PIXW] = (unsigned short)(dat[k].y);
            su16[hb + 3 * 2 * PIXW] = (unsigned short)(dat[k].y >> 16);
            su16[hb + 4 * 2 * PIXW] = (unsigned short)(dat[k].z);
            su16[hb + 5 * 2 * PIXW] = (unsigned short)(dat[k].z >> 16);
            su16[hb + 6 * 2 * PIXW] = (unsigned short)(dat[k].w);
            su16[hb + 7 * 2 * PIXW] = (unsigned short)(dat[k].w >> 16);
        }
    }
}

// ---------------------------------------------------------------------------
// LGA pass 1. bf16 double-buffered su + dot2 taps; 12 full chunks + light
// 1-plane epilogue. s_setprio(1) around the tap loop (T5, R15 measured win).
// amdgpu_num_vgpr(128) pin.
// ---------------------------------------------------------------------------
__global__ __launch_bounds__(256)
__attribute__((amdgpu_num_vgpr(128))) void lga1_kernel(
    const float* __restrict__ cvol,
    const float* __restrict__ lg1,
    __hip_bfloat16* __restrict__ yout) {
    const int tid = threadIdx.x;
    const int tx = tid & 15;
    const int ty = tid >> 4;
    const int w0p = blockIdx.x * 16;
    const int h0p = blockIdx.y * 16;
    const int pix = (h0p + ty) * WOUT + (w0p + tx);

    __shared__ __align__(16) unsigned su[2 * SUWORDS];

    // prologue phase A (chunk 0): loads land under the guidance preamble
    unsigned aq0[6], aq2[3];
    stageA1(cvol, tid, h0p, w0p, 0, aq0, aq2);

    // ---- guidance: single pass, un-normalized, bf16 pairs (38 regs) ----
    float asum = 0.f;
    unsigned gp[38];
#pragma unroll
    for (int p = 0; p < 38; ++p) {
        int c0 = 2 * p, c1 = 2 * p + 1;
        float w0 = lg1[c0 * NPIX + pix];
        float w1 = (c1 < 75) ? lg1[c1 * NPIX + pix] : 0.f;
        unsigned b0 = bf16bits(w0), b1 = bf16bits(w1);
        asum += fabsf(__uint_as_float(b0 << 16)) +
                fabsf(__uint_as_float(b1 << 16));
        gp[p] = b0 | (b1 << 16);
    }
    const float inv = 1.f / fmaxf(asum, 1e-12f);

    const int pbase = (ty * ROWSTRIDE + tx + 6) * PIXW;
    __hip_bfloat16* ybase = yout + pix;

    scat1((unsigned short*)su, tid, aq0, aq2); // chunk 0 -> buf0
    int pb = 0;
    for (int d0 = 0; d0 + CHUNK < DOUT; d0 += CHUNK) { // 12 full chunks
        __syncthreads(); // buf[pb] writes visible; buf[pb^1] readers done
        stageA1(cvol, tid, h0p, w0p, d0 + CHUNK, aq0, aq2);

        const unsigned* sw = su + pb * SUWORDS + pbase;
        float acc[16];
#pragma unroll
        for (int d = 0; d < 16; ++d) acc[d] = 0.f;
        __builtin_amdgcn_s_setprio(1);
#pragma unroll
        for (int i = 0; i < 5; ++i) {
#pragma unroll
            for (int j = 0; j < 5; ++j) {
                const int t = i * 5 + j;
                TAP16(sw + (i * ROWSTRIDE + j) * PIXW, t);
            }
        }
        __builtin_amdgcn_s_setprio(0);

        scat1((unsigned short*)(su + (pb ^ 1) * SUWORDS), tid, aq0, aq2);

#pragma unroll
        for (int dd = 0; dd < CHUNK; ++dd)
            ybase[(size_t)(d0 + dd) * NPIX] = __float2bfloat16(acc[dd] * inv);
        pb ^= 1;
    }

    // epilogue: d = 192 only — one dot2 per tap
    __syncthreads();
    {
        const unsigned* sw = su + pb * SUWORDS + pbase;
        float acc0 = 0.f;
#pragma unroll
        for (int i = 0; i < 5; ++i) {
#pragma unroll
            for (int j = 0; j < 5; ++j) {
                const int t = i * 5 + j;
                TAPTAIL(sw + (i * ROWSTRIDE + j) * PIXW, t);
            }
        }
        ybase[(size_t)192 * NPIX] = __float2bfloat16(acc0 * inv);
    }
}

// ---------------------------------------------------------------------------
// LGA pass 2: same structure; phase A is a pure uint4 HBM load; online
// softmin completes per pixel, S/L fused. Light 1-plane epilogue.
// ---------------------------------------------------------------------------
__global__ __launch_bounds__(256)
__attribute__((amdgpu_num_vgpr(128))) void lga2_kernel(
    const __hip_bfloat16* __restrict__ xin,
    const float* __restrict__ lg1,
    float* __restrict__ out) {
    const int tid = threadIdx.x;
    const int tx = tid & 15;
    const int ty = tid >> 4;
    const int w0p = blockIdx.x * 16;
    const int h0p = blockIdx.y * 16;
    const int pix = (h0p + ty) * WOUT + (w0p + tx);
    const unsigned short* xus = (const unsigned short*)xin;

    __shared__ __align__(16) unsigned su[2 * SUWORDS];

    uint4 dat[6];
    stageA2(xus, tid, h0p, w0p, 0, dat);

    float asum = 0.f;
    unsigned gp[38];
#pragma unroll
    for (int p = 0; p < 38; ++p) {
        int c0 = 2 * p, c1 = 2 * p + 1;
        float w0 = lg1[c0 * NPIX + pix];
        float w1 = (c1 < 75) ? lg1[c1 * NPIX + pix] : 0.f;
        unsigned b0 = bf16bits(w0), b1 = bf16bits(w1);
        asum += fabsf(__uint_as_float(b0 << 16)) +
                fabsf(__uint_as_float(b1 << 16));
        gp[p] = b0 | (b1 << 16);
    }
    const float inv = 1.f / fmaxf(asum, 1e-12f);

    const int pbase = (ty * ROWSTRIDE + tx + 6) * PIXW;

    float m = -1e30f, l = 0.f, s_acc = 0.f;

    scat2((unsigned short*)su, tid, dat); // chunk 0 -> buf0
    int pb = 0;
    for (int d0 = 0; d0 + CHUNK < DOUT; d0 += CHUNK) { // 12 full chunks
        __syncthreads();
        stageA2(xus, tid, h0p, w0p, d0 + CHUNK, dat);

        const unsigned* sw = su + pb * SUWORDS + pbase;
        float acc[16];
#pragma unroll
        for (int d = 0; d < 16; ++d) acc[d] = 0.f;
        __builtin_amdgcn_s_setprio(1);
#pragma unroll
        for (int i = 0; i < 5; ++i) {
#pragma unroll
            for (int j = 0; j < 5; ++j) {
                const int t = i * 5 + j;
                TAP16(sw + (i * ROWSTRIDE + j) * PIXW, t);
            }
        }
        __builtin_amdgcn_s_setprio(0);

        scat2((unsigned short*)(su + (pb ^ 1) * SUWORDS), tid, dat);

        {
            float v[16];
            float mx = m;
#pragma unroll
            for (int d = 0; d < 16; ++d) {
                v[d] = -acc[d] * inv;
                mx = fmaxf(mx, v[d]);
            }
            float sc = __expf(m - mx);
            float sum = 0.f, ssum = 0.f;
#pragma unroll
            for (int d = 0; d < 16; ++d) {
                float e = __expf(v[d] - mx);
                sum += e;
                ssum += e * (float)(d0 + d);
            }
            l = l * sc + sum;
            s_acc = s_acc * sc + ssum;
            m = mx;
        }
        pb ^= 1;
    }

    // epilogue: d = 192 only
    __syncthreads();
    {
        const unsigned* sw = su + pb * SUWORDS + pbase;
        float acc0 = 0.f;
#pragma unroll
        for (int i = 0; i < 5; ++i) {
#pragma unroll
            for (int j = 0; j < 5; ++j) {
                const int t = i * 5 + j;
                TAPTAIL(sw + (i * ROWSTRIDE + j) * PIXW, t);
            }
        }
        float vv = -acc0 * inv;
        float mx = fmaxf(m, vv);
        float sc = __expf(m - mx);
        float e = __expf(vv - mx);
        l = l * sc + e;
        s_acc = s_acc * sc + e * 192.f;
    }

    out[pix] = s_acc / l;
}

// ---------------------------------------------------------------------------
extern "C" void kernel_launch(void* const* d_in, const int* in_sizes, int n_in,
                              void* d_out, int out_size, void* d_ws,
                              size_t ws_size, hipStream_t stream) {
    const float* x = (const float*)d_in[0];
    const float* lg1 = (const float*)d_in[1];
    const float* cw = (const float*)d_in[2];
    float* out = (float*)d_out;

    // ws: c fp32 [100352] | region A bf16 [NUPS] | region B bf16 [NUPS].
    // conv partials [8][NCONV] overlay region B; lga1 writes y1 to region B.
    float* c = (float*)d_ws;
    __hip_bfloat16* regA = (__hip_bfloat16*)((char*)d_ws + (size_t)NCONV * 4);
    __hip_bfloat16* y1 = regA + (size_t)NUPS;
    float* cpart = (float*)y1;

    dim3 cgrid(NCONV / 1024, CGRP); // 98 x 8; each thread does 4 w-outputs
    conv3d_kernel<<<cgrid, 256, 0, stream>>>(x, cw, cpart);
    convfold_kernel<<<NCONV / 1024, 256, 0, stream>>>(cpart, c);

    dim3 grid(WOUT / 16, HOUT / 16, NZ); // 32 x 16 x 1 = 512 blocks
    lga1_kernel<<<grid, 256, 0, stream>>>(c, lg1, y1);
    lga2_kernel<<<grid, 256, 0, stream>>>(y1, lg1, out);
}